// Round 1
// baseline (2860.241 us; speedup 1.0000x reference)
//
#include <hip/hip_runtime.h>
#include <cstdint>
#include <cstddef>

// Problem constants
#define TB_B 4
#define TB_S 1024
#define TB_E 1024
#define TB_H 16
#define TB_D 64
#define TB_MLP 4096
#define TB_ROWS (TB_B * TB_S)   // 4096

static __device__ __forceinline__ void atomicMaxF(float* addr, float v) {
  // valid for non-negative floats: IEEE bit pattern is monotonic
  atomicMax(reinterpret_cast<unsigned int*>(addr), __float_as_uint(v));
}

// ---------------------------------------------------------------------------
// absmax (or max(relu(x))) reduction -> atomicMax into *out (init to 0 first)
// ---------------------------------------------------------------------------
__global__ __launch_bounds__(256) void absmax_kernel(const float* __restrict__ x, long n,
                                                     float* __restrict__ out, int relu_mode) {
  float m = 0.f;
  long stride = (long)gridDim.x * 256;
  for (long i = (long)blockIdx.x * 256 + threadIdx.x; i < n; i += stride) {
    float v = x[i];
    m = fmaxf(m, relu_mode ? fmaxf(v, 0.f) : fabsf(v));
  }
#pragma unroll
  for (int o = 32; o; o >>= 1) m = fmaxf(m, __shfl_down(m, o, 64));
  __shared__ float sm[4];
  if (!(threadIdx.x & 63)) sm[threadIdx.x >> 6] = m;
  __syncthreads();
  if (threadIdx.x == 0) {
    m = fmaxf(fmaxf(sm[0], sm[1]), fmaxf(sm[2], sm[3]));
    atomicMaxF(out, m);
  }
}

// ---------------------------------------------------------------------------
// fake-quant elementwise (float4), out = clip(round(x*pre/scale),qmin,qmax)*scale
// scale = max(amax*pre/qmax, 1e-8)
// ---------------------------------------------------------------------------
__global__ __launch_bounds__(256) void quant4_kernel(const float* __restrict__ in,
                                                     float* __restrict__ outp, long n4,
                                                     const float* __restrict__ amax_p,
                                                     float pre, float qmax, float qmin) {
  float scale = fmaxf(amax_p[0] * pre / qmax, 1e-8f);
  long stride = (long)gridDim.x * 256;
  for (long i = (long)blockIdx.x * 256 + threadIdx.x; i < n4; i += stride) {
    float4 v = ((const float4*)in)[i];
    float4 o;
    o.x = fminf(fmaxf(rintf(v.x * pre / scale), qmin), qmax) * scale;
    o.y = fminf(fmaxf(rintf(v.y * pre / scale), qmin), qmax) * scale;
    o.z = fminf(fmaxf(rintf(v.z * pre / scale), qmin), qmax) * scale;
    o.w = fminf(fmaxf(rintf(v.w * pre / scale), qmin), qmax) * scale;
    ((float4*)outp)[i] = o;
  }
}

// relu + unsigned 8-bit fake-quant, in place
__global__ __launch_bounds__(256) void reluquant4_kernel(float* __restrict__ buf, long n4,
                                                         const float* __restrict__ amax_p) {
  float scale = fmaxf(amax_p[0] / 255.f, 1e-8f);
  long stride = (long)gridDim.x * 256;
  for (long i = (long)blockIdx.x * 256 + threadIdx.x; i < n4; i += stride) {
    float4 v = ((const float4*)buf)[i];
    float4 o;
    o.x = fminf(fmaxf(rintf(fmaxf(v.x, 0.f) / scale), 0.f), 255.f) * scale;
    o.y = fminf(fmaxf(rintf(fmaxf(v.y, 0.f) / scale), 0.f), 255.f) * scale;
    o.z = fminf(fmaxf(rintf(fmaxf(v.z, 0.f) / scale), 0.f), 255.f) * scale;
    o.w = fminf(fmaxf(rintf(fmaxf(v.w, 0.f) / scale), 0.f), 255.f) * scale;
    ((float4*)buf)[i] = o;
  }
}

// ---------------------------------------------------------------------------
// fp32 NT GEMM: C[M,N] = A[M,K] @ B[N,K]^T + bias[N]
// 128x128 macro-tile, K-tile 16, 256 threads, 8x8 per thread.
// M,N,K all multiples of 128/16 here -> no bounds checks.
// ---------------------------------------------------------------------------
__global__ __launch_bounds__(256) void gemm_nt_kernel(const float* __restrict__ A,
                                                      const float* __restrict__ Bw,
                                                      const float* __restrict__ bias,
                                                      float* __restrict__ C,
                                                      int M, int N, int K) {
  __shared__ float As[16][128];
  __shared__ float Bs[16][128];
  const int t = threadIdx.x;
  const int m0 = blockIdx.y * 128, n0 = blockIdx.x * 128;
  const int ty = t >> 4, tx = t & 15;
  float acc[8][8];
#pragma unroll
  for (int i = 0; i < 8; i++)
#pragma unroll
    for (int j = 0; j < 8; j++) acc[i][j] = 0.f;

  for (int k0 = 0; k0 < K; k0 += 16) {
#pragma unroll
    for (int l = 0; l < 2; l++) {
      int f = t + l * 256;          // 0..511 float4 slots (2048 floats per tile)
      int row = f >> 2;             // 0..127
      int c4 = (f & 3) * 4;         // 0,4,8,12
      float4 a = *(const float4*)(A + (long)(m0 + row) * K + k0 + c4);
      As[c4 + 0][row] = a.x; As[c4 + 1][row] = a.y; As[c4 + 2][row] = a.z; As[c4 + 3][row] = a.w;
      float4 b = *(const float4*)(Bw + (long)(n0 + row) * K + k0 + c4);
      Bs[c4 + 0][row] = b.x; Bs[c4 + 1][row] = b.y; Bs[c4 + 2][row] = b.z; Bs[c4 + 3][row] = b.w;
    }
    __syncthreads();
#pragma unroll
    for (int k = 0; k < 16; k++) {
      float4 a0 = *(const float4*)&As[k][ty * 8];
      float4 a1 = *(const float4*)&As[k][ty * 8 + 4];
      float4 b0 = *(const float4*)&Bs[k][tx * 8];
      float4 b1 = *(const float4*)&Bs[k][tx * 8 + 4];
      float av[8] = {a0.x, a0.y, a0.z, a0.w, a1.x, a1.y, a1.z, a1.w};
      float bv[8] = {b0.x, b0.y, b0.z, b0.w, b1.x, b1.y, b1.z, b1.w};
#pragma unroll
      for (int i = 0; i < 8; i++)
#pragma unroll
        for (int j = 0; j < 8; j++) acc[i][j] += av[i] * bv[j];
    }
    __syncthreads();
  }
#pragma unroll
  for (int i = 0; i < 8; i++) {
    long row = m0 + ty * 8 + i;
#pragma unroll
    for (int jq = 0; jq < 2; jq++) {
      int col = n0 + tx * 8 + jq * 4;
      float4 bi = *(const float4*)(bias + col);
      float4 o;
      o.x = acc[i][jq * 4 + 0] + bi.x;
      o.y = acc[i][jq * 4 + 1] + bi.y;
      o.z = acc[i][jq * 4 + 2] + bi.z;
      o.w = acc[i][jq * 4 + 3] + bi.w;
      *(float4*)(C + row * N + col) = o;
    }
  }
}

// ---------------------------------------------------------------------------
// Attention pass A: absmax over scores = qs @ kq^T  (per (b,h), 16 q-rows/block)
// q,k layout: [B,S,H,D]
// ---------------------------------------------------------------------------
__global__ __launch_bounds__(256) void attn_scores_amax_kernel(const float* __restrict__ q,
                                                               const float* __restrict__ k,
                                                               float* __restrict__ amax_out) {
  const int bh = blockIdx.x, it = blockIdx.y;
  const int b = bh >> 4, h = bh & 15;
  const int i0 = it * 16;
  __shared__ float qs[16][64];
  __shared__ float ks[64][68];
  const int t = threadIdx.x;
  {
    int row = t >> 4, c4 = (t & 15) * 4;
    *(float4*)&qs[row][c4] =
        *(const float4*)(q + (((long)(b * TB_S + i0 + row)) * TB_H + h) * TB_D + c4);
  }
  __syncthreads();
  const int i = t & 15, jq = t >> 4;
  float4 qreg[16];
#pragma unroll
  for (int d4 = 0; d4 < 16; d4++) qreg[d4] = *(const float4*)&qs[i][d4 * 4];
  float amax = 0.f;
  for (int j0 = 0; j0 < TB_S; j0 += 64) {
    __syncthreads();
#pragma unroll
    for (int l = 0; l < 4; l++) {
      int f = t + l * 256;
      int row = f >> 4, c4 = (f & 15) * 4;
      *(float4*)&ks[row][c4] =
          *(const float4*)(k + (((long)(b * TB_S + j0 + row)) * TB_H + h) * TB_D + c4);
    }
    __syncthreads();
#pragma unroll
    for (int jj = 0; jj < 4; jj++) {
      int j = jq * 4 + jj;
      float s = 0.f;
#pragma unroll
      for (int d4 = 0; d4 < 16; d4++) {
        float4 kf = *(const float4*)&ks[j][d4 * 4];
        float4 qf = qreg[d4];
        s += qf.x * kf.x + qf.y * kf.y + qf.z * kf.z + qf.w * kf.w;
      }
      amax = fmaxf(amax, fabsf(s));
    }
  }
#pragma unroll
  for (int o = 32; o; o >>= 1) amax = fmaxf(amax, __shfl_down(amax, o, 64));
  __shared__ float sm[4];
  if (!(t & 63)) sm[t >> 6] = amax;
  __syncthreads();
  if (t == 0) atomicMaxF(amax_out, fmaxf(fmaxf(sm[0], sm[1]), fmaxf(sm[2], sm[3])));
}

// ---------------------------------------------------------------------------
// Attention pass B: recompute scores, quantize -> int8 codes, online softmax
// row stats (m,l) -> rowm/rowl, and attn absmax = max(1/l).
// ---------------------------------------------------------------------------
__global__ __launch_bounds__(256) void attn_scores_qsm_kernel(const float* __restrict__ q,
                                                              const float* __restrict__ k,
                                                              const float* __restrict__ amax_sc,
                                                              signed char* __restrict__ g,
                                                              float* __restrict__ rowm,
                                                              float* __restrict__ rowl,
                                                              float* __restrict__ amax_attn) {
  const int bh = blockIdx.x, it = blockIdx.y;
  const int b = bh >> 4, h = bh & 15;
  const int i0 = it * 16;
  __shared__ float qs[16][64];
  __shared__ float ks[64][68];
  __shared__ float smm[16][16];
  __shared__ float sll[16][16];
  const int t = threadIdx.x;
  const float s_sc = fmaxf(amax_sc[0] / 127.f, 1e-8f);
  {
    int row = t >> 4, c4 = (t & 15) * 4;
    *(float4*)&qs[row][c4] =
        *(const float4*)(q + (((long)(b * TB_S + i0 + row)) * TB_H + h) * TB_D + c4);
  }
  __syncthreads();
  const int i = t & 15, jq = t >> 4;
  float4 qreg[16];
#pragma unroll
  for (int d4 = 0; d4 < 16; d4++) qreg[d4] = *(const float4*)&qs[i][d4 * 4];
  float m_t = -INFINITY, l_t = 0.f;
  for (int j0 = 0; j0 < TB_S; j0 += 64) {
    __syncthreads();
#pragma unroll
    for (int l = 0; l < 4; l++) {
      int f = t + l * 256;
      int row = f >> 4, c4 = (f & 15) * 4;
      *(float4*)&ks[row][c4] =
          *(const float4*)(k + (((long)(b * TB_S + j0 + row)) * TB_H + h) * TB_D + c4);
    }
    __syncthreads();
    char4 pack;
#pragma unroll
    for (int jj = 0; jj < 4; jj++) {
      int j = jq * 4 + jj;
      float s = 0.f;
#pragma unroll
      for (int d4 = 0; d4 < 16; d4++) {
        float4 kf = *(const float4*)&ks[j][d4 * 4];
        float4 qf = qreg[d4];
        s += qf.x * kf.x + qf.y * kf.y + qf.z * kf.z + qf.w * kf.w;
      }
      float qv = fminf(fmaxf(rintf(s / s_sc), -128.f), 127.f);
      ((signed char*)&pack)[jj] = (signed char)(int)qv;
      float val = qv * s_sc;
      float mn = fmaxf(m_t, val);
      l_t = l_t * expf(m_t - mn) + expf(val - mn);
      m_t = mn;
    }
    *(char4*)(g + ((long)(bh * TB_S + i0 + i)) * TB_S + j0 + jq * 4) = pack;
  }
  __syncthreads();
  smm[i][jq] = m_t;
  sll[i][jq] = l_t;
  __syncthreads();
  if (t < 16) {
    float m = smm[t][0];
#pragma unroll
    for (int c = 1; c < 16; c++) m = fmaxf(m, smm[t][c]);
    float l = 0.f;
#pragma unroll
    for (int c = 0; c < 16; c++) l += sll[t][c] * expf(smm[t][c] - m);
    rowm[(long)bh * TB_S + i0 + t] = m;
    rowl[(long)bh * TB_S + i0 + t] = l;
    atomicMaxF(amax_attn, 1.f / l);   // row max of softmax = exp(0)/l
  }
}

// ---------------------------------------------------------------------------
// Attention pass C: attn = quant(softmax from int8 codes + row stats); ctx = attn @ v
// ctx written in [B,S,H,D] layout (== [B,S,E]).
// ---------------------------------------------------------------------------
__global__ __launch_bounds__(256) void attn_pv_kernel(const signed char* __restrict__ g,
                                                      const float* __restrict__ rowm,
                                                      const float* __restrict__ rowl,
                                                      const float* __restrict__ v,
                                                      const float* __restrict__ amax_sc,
                                                      const float* __restrict__ amax_attn,
                                                      float* __restrict__ ctx) {
  const int bh = blockIdx.x, it = blockIdx.y;
  const int b = bh >> 4, h = bh & 15;
  const int i0 = it * 16;
  __shared__ float vs[64][68];
  __shared__ float patt[16][68];
  __shared__ float srm[16], srl[16];
  const int t = threadIdx.x;
  if (t < 16) {
    srm[t] = rowm[(long)bh * TB_S + i0 + t];
    srl[t] = rowl[(long)bh * TB_S + i0 + t];
  }
  const float s_sc = fmaxf(amax_sc[0] / 127.f, 1e-8f);
  const float s_at = fmaxf(amax_attn[0] / 127.f, 1e-8f);
  const int i = t & 15, dq = t >> 4;
  const int ip = t >> 4, jp4 = (t & 15) * 4;
  float4 acc = make_float4(0.f, 0.f, 0.f, 0.f);
  __syncthreads();
  for (int j0 = 0; j0 < TB_S; j0 += 64) {
#pragma unroll
    for (int l = 0; l < 4; l++) {
      int f = t + l * 256;
      int row = f >> 4, c4 = (f & 15) * 4;
      *(float4*)&vs[row][c4] =
          *(const float4*)(v + (((long)(b * TB_S + j0 + row)) * TB_H + h) * TB_D + c4);
    }
    {
      char4 cc = *(const char4*)(g + ((long)(bh * TB_S + i0 + ip)) * TB_S + j0 + jp4);
      float m = srm[ip], l = srl[ip];
      float pv[4];
      signed char cs[4] = {cc.x, cc.y, cc.z, cc.w};
#pragma unroll
      for (int c = 0; c < 4; c++) {
        float a = expf((float)cs[c] * s_sc - m) / l;
        pv[c] = fminf(fmaxf(rintf(a / s_at), -128.f), 127.f) * s_at;
      }
      *(float4*)&patt[ip][jp4] = make_float4(pv[0], pv[1], pv[2], pv[3]);
    }
    __syncthreads();
#pragma unroll 8
    for (int j = 0; j < 64; j++) {
      float p = patt[i][j];
      float4 vf = *(const float4*)&vs[j][dq * 4];
      acc.x += p * vf.x; acc.y += p * vf.y; acc.z += p * vf.z; acc.w += p * vf.w;
    }
    __syncthreads();   // before overwriting vs/patt next iteration
  }
  *(float4*)(ctx + (((long)(b * TB_S + i0 + i)) * TB_H + h) * TB_D + dq * 4) = acc;
}

// ---------------------------------------------------------------------------
// h = LayerNorm(aq + fakequant(braw)); aq already quantized. One block per row.
// ---------------------------------------------------------------------------
__global__ __launch_bounds__(256) void resid_ln_kernel(const float* __restrict__ aq,
                                                       const float* __restrict__ braw,
                                                       const float* __restrict__ amax_p,
                                                       float* __restrict__ outp) {
  __shared__ float red[4];
  const int row = blockIdx.x, t = threadIdx.x;
  const float scale = fmaxf(amax_p[0] / 127.f, 1e-8f);
  const long base = (long)row * TB_E + t * 4;
  float4 a = *(const float4*)(aq + base);
  float4 bv = *(const float4*)(braw + base);
  float v0 = a.x + fminf(fmaxf(rintf(bv.x / scale), -128.f), 127.f) * scale;
  float v1 = a.y + fminf(fmaxf(rintf(bv.y / scale), -128.f), 127.f) * scale;
  float v2 = a.z + fminf(fmaxf(rintf(bv.z / scale), -128.f), 127.f) * scale;
  float v3 = a.w + fminf(fmaxf(rintf(bv.w / scale), -128.f), 127.f) * scale;
  float s = v0 + v1 + v2 + v3;
#pragma unroll
  for (int o = 32; o; o >>= 1) s += __shfl_down(s, o, 64);
  if (!(t & 63)) red[t >> 6] = s;
  __syncthreads();
  float mu = ((red[0] + red[1]) + (red[2] + red[3])) * (1.f / TB_E);
  float d0 = v0 - mu, d1 = v1 - mu, d2 = v2 - mu, d3 = v3 - mu;
  float sq = d0 * d0 + d1 * d1 + d2 * d2 + d3 * d3;
#pragma unroll
  for (int o = 32; o; o >>= 1) sq += __shfl_down(sq, o, 64);
  __syncthreads();               // everyone done reading red for mu
  if (!(t & 63)) red[t >> 6] = sq;
  __syncthreads();
  float var = ((red[0] + red[1]) + (red[2] + red[3])) * (1.f / TB_E);
  float rs = 1.f / sqrtf(var + 1e-5f);
  float4 o4;
  o4.x = d0 * rs; o4.y = d1 * rs; o4.z = d2 * rs; o4.w = d3 * rs;
  *(float4*)(outp + base) = o4;
}

// ---------------------------------------------------------------------------
// Host side
// ---------------------------------------------------------------------------
// scalar slots (floats at ws[0..])
#define SL_X 0
#define SL_WQ 1
#define SL_WK 2
#define SL_WV 3
#define SL_WO 4
#define SL_W1 5
#define SL_W2 6
#define SL_BQ 7
#define SL_BK 8
#define SL_BV 9
#define SL_BO 10
#define SL_B1 11
#define SL_B2 12
#define SL_Q 13
#define SL_K 14
#define SL_V 15
#define SL_SC 16
#define SL_ATTN 17
#define SL_CTX 18
#define SL_AO 19
#define SL_H 20
#define SL_RELU 21
#define SL_M2 22

static inline int nblocks(long n) {
  long b = (n + 255) / 256;
  return (int)(b > 2048 ? 2048 : b);
}

extern "C" void kernel_launch(void* const* d_in, const int* in_sizes, int n_in,
                              void* d_out, int out_size, void* d_ws, size_t ws_size,
                              hipStream_t stream) {
  const float* x  = (const float*)d_in[0];
  const float* Wq = (const float*)d_in[1];
  const float* bq = (const float*)d_in[2];
  const float* Wk = (const float*)d_in[3];
  const float* bk = (const float*)d_in[4];
  const float* Wv = (const float*)d_in[5];
  const float* bv = (const float*)d_in[6];
  const float* Wo = (const float*)d_in[7];
  const float* bo = (const float*)d_in[8];
  const float* W1 = (const float*)d_in[9];
  const float* b1 = (const float*)d_in[10];
  const float* W2 = (const float*)d_in[11];
  const float* b2 = (const float*)d_in[12];
  float* ws = (float*)d_ws;
  float* out = (float*)d_out;

  // workspace layout (float offsets); header 64K floats = 256KB
  const long SZ_XE = (long)TB_ROWS * TB_E;      // 4,194,304
  const long SZ_W  = (long)TB_E * TB_E;         // 1,048,576
  const long OFF_QBQ = 1024, OFF_QBK = 2048, OFF_QBV = 3072, OFF_QBO = 4096;
  const long OFF_QB1 = 5120, OFF_QB2 = 9216;    // qb1 has 4096 floats
  const long OFF_QX = 65536;
  const long OFF_WQ = OFF_QX + SZ_XE;
  const long OFF_WK = OFF_WQ + SZ_W;
  const long OFF_WV = OFF_WK + SZ_W;
  const long OFF_WO = OFF_WV + SZ_W;
  const long OFF_W1 = OFF_WO + SZ_W;            // [4096,1024]
  const long OFF_W2 = OFF_W1 + SZ_XE;           // [1024,4096]
  const long OFF_Q  = OFF_W2 + SZ_XE;           // later reused as ctx
  const long OFF_K  = OFF_Q + SZ_XE;            // later reused as attn_out
  const long OFF_V  = OFF_K + SZ_XE;            // later reused as h
  const long OFF_ROWM = OFF_V + SZ_XE;          // 65536
  const long OFF_ROWL = OFF_ROWM + 65536;
  const long OFF_M0 = OFF_ROWL + 65536;
  const long OFF_M2 = OFF_M0 + SZ_XE;
  const long OFF_SC = OFF_M2 + SZ_XE;           // int8 scores 64MB; later m1 (fp32 16M floats)

  float* qx  = ws + OFF_QX;
  float* qwq = ws + OFF_WQ; float* qwk = ws + OFF_WK;
  float* qwv = ws + OFF_WV; float* qwo = ws + OFF_WO;
  float* qw1 = ws + OFF_W1; float* qw2 = ws + OFF_W2;
  float* qbuf = ws + OFF_Q;  float* kbuf = ws + OFF_K;  float* vbuf = ws + OFF_V;
  float* rowm = ws + OFF_ROWM; float* rowl = ws + OFF_ROWL;
  float* m0 = ws + OFF_M0; float* m2 = ws + OFF_M2;
  signed char* gsc = (signed char*)(ws + OFF_SC);
  float* m1 = ws + OFF_SC;
  float* ctx = qbuf;        // reuse q
  float* attn_out = kbuf;   // reuse k
  float* hbuf = vbuf;       // reuse v
  float* qbq_ = ws + OFF_QBQ; float* qbk_ = ws + OFF_QBK;
  float* qbv_ = ws + OFF_QBV; float* qbo_ = ws + OFF_QBO;
  float* qb1_ = ws + OFF_QB1; float* qb2_ = ws + OFF_QB2;

  hipMemsetAsync(ws, 0, 4096, stream);  // zero scalar slots

  // --- absmax of inputs ---
  absmax_kernel<<<nblocks(SZ_XE), 256, 0, stream>>>(x,  SZ_XE, ws + SL_X, 0);
  absmax_kernel<<<nblocks(SZ_W),  256, 0, stream>>>(Wq, SZ_W,  ws + SL_WQ, 0);
  absmax_kernel<<<nblocks(SZ_W),  256, 0, stream>>>(Wk, SZ_W,  ws + SL_WK, 0);
  absmax_kernel<<<nblocks(SZ_W),  256, 0, stream>>>(Wv, SZ_W,  ws + SL_WV, 0);
  absmax_kernel<<<nblocks(SZ_W),  256, 0, stream>>>(Wo, SZ_W,  ws + SL_WO, 0);
  absmax_kernel<<<nblocks(SZ_XE), 256, 0, stream>>>(W1, SZ_XE, ws + SL_W1, 0);
  absmax_kernel<<<nblocks(SZ_XE), 256, 0, stream>>>(W2, SZ_XE, ws + SL_W2, 0);
  absmax_kernel<<<nblocks(1024), 256, 0, stream>>>(bq, 1024, ws + SL_BQ, 0);
  absmax_kernel<<<nblocks(1024), 256, 0, stream>>>(bk, 1024, ws + SL_BK, 0);
  absmax_kernel<<<nblocks(1024), 256, 0, stream>>>(bv, 1024, ws + SL_BV, 0);
  absmax_kernel<<<nblocks(1024), 256, 0, stream>>>(bo, 1024, ws + SL_BO, 0);
  absmax_kernel<<<nblocks(4096), 256, 0, stream>>>(b1, 4096, ws + SL_B1, 0);
  absmax_kernel<<<nblocks(1024), 256, 0, stream>>>(b2, 1024, ws + SL_B2, 0);

  // --- quantize inputs ---
  // activations: qmax=127,qmin=-128 ; weights (narrow): qmin=-127 ; biases: -128
  quant4_kernel<<<nblocks(SZ_XE/4), 256, 0, stream>>>(x,  qx,  SZ_XE/4, ws + SL_X, 1.f, 127.f, -128.f);
  quant4_kernel<<<nblocks(SZ_W/4),  256, 0, stream>>>(Wq, qwq, SZ_W/4,  ws + SL_WQ, 1.f, 127.f, -127.f);
  quant4_kernel<<<nblocks(SZ_W/4),  256, 0, stream>>>(Wk, qwk, SZ_W/4,  ws + SL_WK, 1.f, 127.f, -127.f);
  quant4_kernel<<<nblocks(SZ_W/4),  256, 0, stream>>>(Wv, qwv, SZ_W/4,  ws + SL_WV, 1.f, 127.f, -127.f);
  quant4_kernel<<<nblocks(SZ_W/4),  256, 0, stream>>>(Wo, qwo, SZ_W/4,  ws + SL_WO, 1.f, 127.f, -127.f);
  quant4_kernel<<<nblocks(SZ_XE/4), 256, 0, stream>>>(W1, qw1, SZ_XE/4, ws + SL_W1, 1.f, 127.f, -127.f);
  quant4_kernel<<<nblocks(SZ_XE/4), 256, 0, stream>>>(W2, qw2, SZ_XE/4, ws + SL_W2, 1.f, 127.f, -127.f);
  quant4_kernel<<<1, 256, 0, stream>>>(bq, qbq_, 256, ws + SL_BQ, 1.f, 127.f, -128.f);
  quant4_kernel<<<1, 256, 0, stream>>>(bk, qbk_, 256, ws + SL_BK, 1.f, 127.f, -128.f);
  quant4_kernel<<<1, 256, 0, stream>>>(bv, qbv_, 256, ws + SL_BV, 1.f, 127.f, -128.f);
  quant4_kernel<<<1, 256, 0, stream>>>(bo, qbo_, 256, ws + SL_BO, 1.f, 127.f, -128.f);
  quant4_kernel<<<4, 256, 0, stream>>>(b1, qb1_, 1024, ws + SL_B1, 1.f, 127.f, -128.f);
  quant4_kernel<<<1, 256, 0, stream>>>(b2, qb2_, 256, ws + SL_B2, 1.f, 127.f, -128.f);

  // --- in-projections ---
  gemm_nt_kernel<<<dim3(TB_E/128, TB_ROWS/128), 256, 0, stream>>>(qx, qwq, qbq_, qbuf, TB_ROWS, TB_E, TB_E);
  gemm_nt_kernel<<<dim3(TB_E/128, TB_ROWS/128), 256, 0, stream>>>(qx, qwk, qbk_, kbuf, TB_ROWS, TB_E, TB_E);
  gemm_nt_kernel<<<dim3(TB_E/128, TB_ROWS/128), 256, 0, stream>>>(qx, qwv, qbv_, vbuf, TB_ROWS, TB_E, TB_E);

  // --- quantize q (scaled by 1/8), k, v in place ---
  absmax_kernel<<<nblocks(SZ_XE), 256, 0, stream>>>(qbuf, SZ_XE, ws + SL_Q, 0);
  absmax_kernel<<<nblocks(SZ_XE), 256, 0, stream>>>(kbuf, SZ_XE, ws + SL_K, 0);
  absmax_kernel<<<nblocks(SZ_XE), 256, 0, stream>>>(vbuf, SZ_XE, ws + SL_V, 0);
  quant4_kernel<<<nblocks(SZ_XE/4), 256, 0, stream>>>(qbuf, qbuf, SZ_XE/4, ws + SL_Q, 0.125f, 127.f, -128.f);
  quant4_kernel<<<nblocks(SZ_XE/4), 256, 0, stream>>>(kbuf, kbuf, SZ_XE/4, ws + SL_K, 1.f, 127.f, -128.f);
  quant4_kernel<<<nblocks(SZ_XE/4), 256, 0, stream>>>(vbuf, vbuf, SZ_XE/4, ws + SL_V, 1.f, 127.f, -128.f);

  // --- attention ---
  attn_scores_amax_kernel<<<dim3(TB_B*TB_H, TB_S/16), 256, 0, stream>>>(qbuf, kbuf, ws + SL_SC);
  attn_scores_qsm_kernel<<<dim3(TB_B*TB_H, TB_S/16), 256, 0, stream>>>(qbuf, kbuf, ws + SL_SC,
                                                                       gsc, rowm, rowl, ws + SL_ATTN);
  attn_pv_kernel<<<dim3(TB_B*TB_H, TB_S/16), 256, 0, stream>>>(gsc, rowm, rowl, vbuf,
                                                               ws + SL_SC, ws + SL_ATTN, ctx);

  // --- out projection ---
  absmax_kernel<<<nblocks(SZ_XE), 256, 0, stream>>>(ctx, SZ_XE, ws + SL_CTX, 0);
  quant4_kernel<<<nblocks(SZ_XE/4), 256, 0, stream>>>(ctx, ctx, SZ_XE/4, ws + SL_CTX, 1.f, 127.f, -128.f);
  gemm_nt_kernel<<<dim3(TB_E/128, TB_ROWS/128), 256, 0, stream>>>(ctx, qwo, qbo_, attn_out, TB_ROWS, TB_E, TB_E);

  // --- residual + LN ---
  absmax_kernel<<<nblocks(SZ_XE), 256, 0, stream>>>(attn_out, SZ_XE, ws + SL_AO, 0);
  resid_ln_kernel<<<TB_ROWS, 256, 0, stream>>>(qx, attn_out, ws + SL_AO, hbuf);

  // --- MLP ---
  absmax_kernel<<<nblocks(SZ_XE), 256, 0, stream>>>(hbuf, SZ_XE, ws + SL_H, 0);
  quant4_kernel<<<nblocks(SZ_XE/4), 256, 0, stream>>>(hbuf, m0, SZ_XE/4, ws + SL_H, 1.f, 127.f, -128.f);
  gemm_nt_kernel<<<dim3(TB_MLP/128, TB_ROWS/128), 256, 0, stream>>>(m0, qw1, qb1_, m1, TB_ROWS, TB_MLP, TB_E);
  const long SZ_M1 = (long)TB_ROWS * TB_MLP;
  absmax_kernel<<<nblocks(SZ_M1), 256, 0, stream>>>(m1, SZ_M1, ws + SL_RELU, 1);   // max(relu)
  reluquant4_kernel<<<nblocks(SZ_M1/4), 256, 0, stream>>>(m1, SZ_M1/4, ws + SL_RELU);
  gemm_nt_kernel<<<dim3(TB_E/128, TB_ROWS/128), 256, 0, stream>>>(m1, qw2, qb2_, m2, TB_ROWS, TB_E, TB_MLP);

  // --- final residual + LN ---
  absmax_kernel<<<nblocks(SZ_XE), 256, 0, stream>>>(m2, SZ_XE, ws + SL_M2, 0);
  resid_ln_kernel<<<TB_ROWS, 256, 0, stream>>>(m0, m2, ws + SL_M2, out);
}

// Round 2
// 1535.386 us; speedup vs baseline: 1.8629x; 1.8629x over previous
//
#include <hip/hip_runtime.h>
#include <cstdint>
#include <cstddef>

// Problem constants
#define TB_B 4
#define TB_S 1024
#define TB_E 1024
#define TB_H 16
#define TB_D 64
#define TB_MLP 4096
#define TB_ROWS (TB_B * TB_S)   // 4096

typedef int int4v __attribute__((ext_vector_type(4)));

static __device__ __forceinline__ void atomicMaxF(float* addr, float v) {
  // valid for non-negative floats: IEEE bit pattern is monotonic
  atomicMax(reinterpret_cast<unsigned int*>(addr), __float_as_uint(v));
}

// async global->LDS, 16 bytes per lane. LDS dest must be wave-uniform base + lane*16.
static __device__ __forceinline__ void gl2lds16(const void* g, void* l) {
  __builtin_amdgcn_global_load_lds(
      (const __attribute__((address_space(1))) void*)g,
      (__attribute__((address_space(3))) void*)l, 16, 0, 0);
}

// ---------------------------------------------------------------------------
// absmax (or max(relu(x))) reduction -> atomicMax into *out (init to 0 first)
// ---------------------------------------------------------------------------
__global__ __launch_bounds__(256) void absmax_kernel(const float* __restrict__ x, long n,
                                                     float* __restrict__ out, int relu_mode) {
  float m = 0.f;
  long stride = (long)gridDim.x * 256;
  for (long i = (long)blockIdx.x * 256 + threadIdx.x; i < n; i += stride) {
    float v = x[i];
    m = fmaxf(m, relu_mode ? fmaxf(v, 0.f) : fabsf(v));
  }
#pragma unroll
  for (int o = 32; o; o >>= 1) m = fmaxf(m, __shfl_down(m, o, 64));
  __shared__ float sm[4];
  if (!(threadIdx.x & 63)) sm[threadIdx.x >> 6] = m;
  __syncthreads();
  if (threadIdx.x == 0) {
    m = fmaxf(fmaxf(sm[0], sm[1]), fmaxf(sm[2], sm[3]));
    atomicMaxF(out, m);
  }
}

// ---------------------------------------------------------------------------
// fake-quant elementwise -> fp32 (float4). out = clip(round(x*pre/scale),qmin,qmax)*scale
// ---------------------------------------------------------------------------
__global__ __launch_bounds__(256) void quant4_kernel(const float* __restrict__ in,
                                                     float* __restrict__ outp, long n4,
                                                     const float* __restrict__ amax_p,
                                                     float pre, float qmax, float qmin) {
  float scale = fmaxf(amax_p[0] * pre / qmax, 1e-8f);
  long stride = (long)gridDim.x * 256;
  for (long i = (long)blockIdx.x * 256 + threadIdx.x; i < n4; i += stride) {
    float4 v = ((const float4*)in)[i];
    float4 o;
    o.x = fminf(fmaxf(rintf(v.x * pre / scale), qmin), qmax) * scale;
    o.y = fminf(fmaxf(rintf(v.y * pre / scale), qmin), qmax) * scale;
    o.z = fminf(fmaxf(rintf(v.z * pre / scale), qmin), qmax) * scale;
    o.w = fminf(fmaxf(rintf(v.w * pre / scale), qmin), qmax) * scale;
    ((float4*)outp)[i] = o;
  }
}

// fake-quant elementwise -> int8 codes
__global__ __launch_bounds__(256) void quant8_kernel(const float* __restrict__ in,
                                                     signed char* __restrict__ out8, long n4,
                                                     const float* __restrict__ amax_p,
                                                     float qmax, float qmin) {
  float scale = fmaxf(amax_p[0] / qmax, 1e-8f);
  long stride = (long)gridDim.x * 256;
  for (long i = (long)blockIdx.x * 256 + threadIdx.x; i < n4; i += stride) {
    float4 v = ((const float4*)in)[i];
    char4 o;
    o.x = (signed char)(int)fminf(fmaxf(rintf(v.x / scale), qmin), qmax);
    o.y = (signed char)(int)fminf(fmaxf(rintf(v.y / scale), qmin), qmax);
    o.z = (signed char)(int)fminf(fmaxf(rintf(v.z / scale), qmin), qmax);
    o.w = (signed char)(int)fminf(fmaxf(rintf(v.w / scale), qmin), qmax);
    ((char4*)out8)[i] = o;
  }
}

// relu + unsigned 8-bit quant -> codes stored as (c - 128) in signed i8
__global__ __launch_bounds__(256) void relu_quant8_kernel(const float* __restrict__ in,
                                                          signed char* __restrict__ out8, long n4,
                                                          const float* __restrict__ amax_p) {
  float scale = fmaxf(amax_p[0] / 255.f, 1e-8f);
  long stride = (long)gridDim.x * 256;
  for (long i = (long)blockIdx.x * 256 + threadIdx.x; i < n4; i += stride) {
    float4 v = ((const float4*)in)[i];
    char4 o;
    o.x = (signed char)((int)fminf(fmaxf(rintf(fmaxf(v.x, 0.f) / scale), 0.f), 255.f) - 128);
    o.y = (signed char)((int)fminf(fmaxf(rintf(fmaxf(v.y, 0.f) / scale), 0.f), 255.f) - 128);
    o.z = (signed char)((int)fminf(fmaxf(rintf(fmaxf(v.z, 0.f) / scale), 0.f), 255.f) - 128);
    o.w = (signed char)((int)fminf(fmaxf(rintf(fmaxf(v.w, 0.f) / scale), 0.f), 255.f) - 128);
    ((char4*)out8)[i] = o;
  }
}

// per-row sum of int8 codes (for unsigned-offset correction); one block per row
__global__ __launch_bounds__(256) void rowsum_i8_kernel(const signed char* __restrict__ w8,
                                                        int* __restrict__ out, int Kdim) {
  const int row = blockIdx.x, t = threadIdx.x;
  const signed char* p = w8 + (long)row * Kdim;
  int s = 0;
  for (int i = t * 16; i < Kdim; i += 4096) {
    int4v v = *(const int4v*)(p + i);
    const signed char* b = (const signed char*)&v;
#pragma unroll
    for (int j = 0; j < 16; j++) s += b[j];
  }
#pragma unroll
  for (int o = 32; o; o >>= 1) s += __shfl_down(s, o, 64);
  __shared__ int sm[4];
  if (!(t & 63)) sm[t >> 6] = s;
  __syncthreads();
  if (t == 0) out[row] = sm[0] + sm[1] + sm[2] + sm[3];
}

// ---------------------------------------------------------------------------
// int8 MFMA NT GEMM (exact): C[M,N] = (sum_k A8[m,k]*B8[n,k] + corr) * s_a*s_b + bias[n]
// 128x128 macro-tile, BK=64 bytes, 256 threads (4 waves), mfma_i32_16x16x64_i8.
// Wave w computes rows [w*32, w*32+32) x all 128 cols: 2x8 tiles of 16x16.
// Fragment layout (verified family, m89/m91): A: m=lane&15, k=quad*16+j;
// B: n=lane&15, k=quad*16+j; D: col=lane&15, row=quad*4+reg.
// ---------------------------------------------------------------------------
__global__ __launch_bounds__(256) void gemm_i8_kernel(
    const signed char* __restrict__ A, const signed char* __restrict__ Bw,
    const float* __restrict__ biasq,
    const float* __restrict__ amax_a, float div_a,
    const float* __restrict__ amax_b,
    const int* __restrict__ rowsum,           // nullable: adds 128*rowsum[n]
    float* __restrict__ C, int M, int N, int K) {
  __shared__ signed char As[8192];  // 128 rows x 64 bytes, K-contiguous
  __shared__ signed char Bs[8192];
  const int t = threadIdx.x;
  const int m0 = blockIdx.y * 128, n0 = blockIdx.x * 128;
  const int w = t >> 6, lane = t & 63;
  const int fr = lane & 15, quad = lane >> 4;
  const int r0 = t >> 2;            // staging row 0..63
  const int c0 = (t & 3) * 16;      // staging byte col
  const int a_off0 = (w * 32 + fr) * 64 + quad * 16;
  const int b_off0 = fr * 64 + quad * 16;

  int4v acc[2][8];
#pragma unroll
  for (int r = 0; r < 2; r++)
#pragma unroll
    for (int c = 0; c < 8; c++) acc[r][c] = (int4v){0, 0, 0, 0};

  for (int k0 = 0; k0 < K; k0 += 64) {
    __syncthreads();   // previous tile's ds_reads done before overwrite
    gl2lds16(A + (long)(m0 + r0) * K + k0 + c0, As + t * 16);
    gl2lds16(A + (long)(m0 + r0 + 64) * K + k0 + c0, As + t * 16 + 4096);
    gl2lds16(Bw + (long)(n0 + r0) * K + k0 + c0, Bs + t * 16);
    gl2lds16(Bw + (long)(n0 + r0 + 64) * K + k0 + c0, Bs + t * 16 + 4096);
    __syncthreads();   // compiler drains vmcnt(0) before s_barrier
    int4v af[2], bf[8];
#pragma unroll
    for (int r = 0; r < 2; r++) af[r] = *(const int4v*)(As + a_off0 + r * 1024);
#pragma unroll
    for (int c = 0; c < 8; c++) bf[c] = *(const int4v*)(Bs + b_off0 + c * 1024);
#pragma unroll
    for (int r = 0; r < 2; r++)
#pragma unroll
      for (int c = 0; c < 8; c++)
        acc[r][c] = __builtin_amdgcn_mfma_i32_16x16x64_i8(af[r], bf[c], acc[r][c], 0, 0, 0);
  }

  const float s_a = fmaxf(amax_a[0] / div_a, 1e-8f);
  const float s_b = fmaxf(amax_b[0] / 127.f, 1e-8f);
  const float s = s_a * s_b;
#pragma unroll
  for (int r = 0; r < 2; r++) {
    int rbase = m0 + w * 32 + r * 16 + quad * 4;
#pragma unroll
    for (int c = 0; c < 8; c++) {
      int col = n0 + c * 16 + fr;
      int corr = rowsum ? (rowsum[col] << 7) : 0;
      float bi = biasq[col];
#pragma unroll
      for (int g = 0; g < 4; g++)
        C[(long)(rbase + g) * N + col] = (float)(acc[r][c][g] + corr) * s + bi;
    }
  }
}

// ---------------------------------------------------------------------------
// Attention pass A: absmax over scores = qs @ kq^T  (per (b,h), 16 q-rows/block)
// q,k layout: [B,S,H,D]
// ---------------------------------------------------------------------------
__global__ __launch_bounds__(256) void attn_scores_amax_kernel(const float* __restrict__ q,
                                                               const float* __restrict__ k,
                                                               float* __restrict__ amax_out) {
  const int bh = blockIdx.x, it = blockIdx.y;
  const int b = bh >> 4, h = bh & 15;
  const int i0 = it * 16;
  __shared__ float qs[16][64];
  __shared__ float ks[64][68];
  const int t = threadIdx.x;
  {
    int row = t >> 4, c4 = (t & 15) * 4;
    *(float4*)&qs[row][c4] =
        *(const float4*)(q + (((long)(b * TB_S + i0 + row)) * TB_H + h) * TB_D + c4);
  }
  __syncthreads();
  const int i = t & 15, jq = t >> 4;
  float4 qreg[16];
#pragma unroll
  for (int d4 = 0; d4 < 16; d4++) qreg[d4] = *(const float4*)&qs[i][d4 * 4];
  float amax = 0.f;
  for (int j0 = 0; j0 < TB_S; j0 += 64) {
    __syncthreads();
#pragma unroll
    for (int l = 0; l < 4; l++) {
      int f = t + l * 256;
      int row = f >> 4, c4 = (f & 15) * 4;
      *(float4*)&ks[row][c4] =
          *(const float4*)(k + (((long)(b * TB_S + j0 + row)) * TB_H + h) * TB_D + c4);
    }
    __syncthreads();
#pragma unroll
    for (int jj = 0; jj < 4; jj++) {
      int j = jq * 4 + jj;
      float s = 0.f;
#pragma unroll
      for (int d4 = 0; d4 < 16; d4++) {
        float4 kf = *(const float4*)&ks[j][d4 * 4];
        float4 qf = qreg[d4];
        s += qf.x * kf.x + qf.y * kf.y + qf.z * kf.z + qf.w * kf.w;
      }
      amax = fmaxf(amax, fabsf(s));
    }
  }
#pragma unroll
  for (int o = 32; o; o >>= 1) amax = fmaxf(amax, __shfl_down(amax, o, 64));
  __shared__ float sm[4];
  if (!(t & 63)) sm[t >> 6] = amax;
  __syncthreads();
  if (t == 0) atomicMaxF(amax_out, fmaxf(fmaxf(sm[0], sm[1]), fmaxf(sm[2], sm[3])));
}

// ---------------------------------------------------------------------------
// Attention pass B: recompute scores, quantize -> int8 codes, online softmax
// row stats (m,l) -> rowm/rowl, and attn absmax = max(1/l).
// ---------------------------------------------------------------------------
__global__ __launch_bounds__(256) void attn_scores_qsm_kernel(const float* __restrict__ q,
                                                              const float* __restrict__ k,
                                                              const float* __restrict__ amax_sc,
                                                              signed char* __restrict__ g,
                                                              float* __restrict__ rowm,
                                                              float* __restrict__ rowl,
                                                              float* __restrict__ amax_attn) {
  const int bh = blockIdx.x, it = blockIdx.y;
  const int b = bh >> 4, h = bh & 15;
  const int i0 = it * 16;
  __shared__ float qs[16][64];
  __shared__ float ks[64][68];
  __shared__ float smm[16][16];
  __shared__ float sll[16][16];
  const int t = threadIdx.x;
  const float s_sc = fmaxf(amax_sc[0] / 127.f, 1e-8f);
  {
    int row = t >> 4, c4 = (t & 15) * 4;
    *(float4*)&qs[row][c4] =
        *(const float4*)(q + (((long)(b * TB_S + i0 + row)) * TB_H + h) * TB_D + c4);
  }
  __syncthreads();
  const int i = t & 15, jq = t >> 4;
  float4 qreg[16];
#pragma unroll
  for (int d4 = 0; d4 < 16; d4++) qreg[d4] = *(const float4*)&qs[i][d4 * 4];
  float m_t = -INFINITY, l_t = 0.f;
  for (int j0 = 0; j0 < TB_S; j0 += 64) {
    __syncthreads();
#pragma unroll
    for (int l = 0; l < 4; l++) {
      int f = t + l * 256;
      int row = f >> 4, c4 = (f & 15) * 4;
      *(float4*)&ks[row][c4] =
          *(const float4*)(k + (((long)(b * TB_S + j0 + row)) * TB_H + h) * TB_D + c4);
    }
    __syncthreads();
    char4 pack;
#pragma unroll
    for (int jj = 0; jj < 4; jj++) {
      int j = jq * 4 + jj;
      float s = 0.f;
#pragma unroll
      for (int d4 = 0; d4 < 16; d4++) {
        float4 kf = *(const float4*)&ks[j][d4 * 4];
        float4 qf = qreg[d4];
        s += qf.x * kf.x + qf.y * kf.y + qf.z * kf.z + qf.w * kf.w;
      }
      float qv = fminf(fmaxf(rintf(s / s_sc), -128.f), 127.f);
      ((signed char*)&pack)[jj] = (signed char)(int)qv;
      float val = qv * s_sc;
      float mn = fmaxf(m_t, val);
      l_t = l_t * expf(m_t - mn) + expf(val - mn);
      m_t = mn;
    }
    *(char4*)(g + ((long)(bh * TB_S + i0 + i)) * TB_S + j0 + jq * 4) = pack;
  }
  __syncthreads();
  smm[i][jq] = m_t;
  sll[i][jq] = l_t;
  __syncthreads();
  if (t < 16) {
    float m = smm[t][0];
#pragma unroll
    for (int c = 1; c < 16; c++) m = fmaxf(m, smm[t][c]);
    float l = 0.f;
#pragma unroll
    for (int c = 0; c < 16; c++) l += sll[t][c] * expf(smm[t][c] - m);
    rowm[(long)bh * TB_S + i0 + t] = m;
    rowl[(long)bh * TB_S + i0 + t] = l;
    atomicMaxF(amax_attn, 1.f / l);   // row max of softmax = exp(0)/l
  }
}

// ---------------------------------------------------------------------------
// Attention pass C: attn = quant(softmax from int8 codes + row stats); ctx = attn @ v
// ctx written in [B,S,H,D] layout (== [B,S,E]).
// ---------------------------------------------------------------------------
__global__ __launch_bounds__(256) void attn_pv_kernel(const signed char* __restrict__ g,
                                                      const float* __restrict__ rowm,
                                                      const float* __restrict__ rowl,
                                                      const float* __restrict__ v,
                                                      const float* __restrict__ amax_sc,
                                                      const float* __restrict__ amax_attn,
                                                      float* __restrict__ ctx) {
  const int bh = blockIdx.x, it = blockIdx.y;
  const int b = bh >> 4, h = bh & 15;
  const int i0 = it * 16;
  __shared__ float vs[64][68];
  __shared__ float patt[16][68];
  __shared__ float srm[16], srl[16];
  const int t = threadIdx.x;
  if (t < 16) {
    srm[t] = rowm[(long)bh * TB_S + i0 + t];
    srl[t] = rowl[(long)bh * TB_S + i0 + t];
  }
  const float s_sc = fmaxf(amax_sc[0] / 127.f, 1e-8f);
  const float s_at = fmaxf(amax_attn[0] / 127.f, 1e-8f);
  const int i = t & 15, dq = t >> 4;
  const int ip = t >> 4, jp4 = (t & 15) * 4;
  float4 acc = make_float4(0.f, 0.f, 0.f, 0.f);
  __syncthreads();
  for (int j0 = 0; j0 < TB_S; j0 += 64) {
#pragma unroll
    for (int l = 0; l < 4; l++) {
      int f = t + l * 256;
      int row = f >> 4, c4 = (f & 15) * 4;
      *(float4*)&vs[row][c4] =
          *(const float4*)(v + (((long)(b * TB_S + j0 + row)) * TB_H + h) * TB_D + c4);
    }
    {
      char4 cc = *(const char4*)(g + ((long)(bh * TB_S + i0 + ip)) * TB_S + j0 + jp4);
      float m = srm[ip], l = srl[ip];
      float pv[4];
      signed char cs[4] = {cc.x, cc.y, cc.z, cc.w};
#pragma unroll
      for (int c = 0; c < 4; c++) {
        float a = expf((float)cs[c] * s_sc - m) / l;
        pv[c] = fminf(fmaxf(rintf(a / s_at), -128.f), 127.f) * s_at;
      }
      *(float4*)&patt[ip][jp4] = make_float4(pv[0], pv[1], pv[2], pv[3]);
    }
    __syncthreads();
#pragma unroll 8
    for (int j = 0; j < 64; j++) {
      float p = patt[i][j];
      float4 vf = *(const float4*)&vs[j][dq * 4];
      acc.x += p * vf.x; acc.y += p * vf.y; acc.z += p * vf.z; acc.w += p * vf.w;
    }
    __syncthreads();   // before overwriting vs/patt next iteration
  }
  *(float4*)(ctx + (((long)(b * TB_S + i0 + i)) * TB_H + h) * TB_D + dq * 4) = acc;
}

// ---------------------------------------------------------------------------
// h = LayerNorm(dequant(a8) + fakequant(braw)); a8 are i8 codes with scale amax_a/127.
// One block per row.
// ---------------------------------------------------------------------------
__global__ __launch_bounds__(256) void resid_ln_kernel(const signed char* __restrict__ a8,
                                                       const float* __restrict__ amax_a,
                                                       const float* __restrict__ braw,
                                                       const float* __restrict__ amax_b,
                                                       float* __restrict__ outp) {
  __shared__ float red[4];
  const int row = blockIdx.x, t = threadIdx.x;
  const float sa = fmaxf(amax_a[0] / 127.f, 1e-8f);
  const float sb = fmaxf(amax_b[0] / 127.f, 1e-8f);
  const long base = (long)row * TB_E + t * 4;
  char4 a = ((const char4*)a8)[(long)row * 256 + t];
  float4 bv = *(const float4*)(braw + base);
  float v0 = (float)a.x * sa + fminf(fmaxf(rintf(bv.x / sb), -128.f), 127.f) * sb;
  float v1 = (float)a.y * sa + fminf(fmaxf(rintf(bv.y / sb), -128.f), 127.f) * sb;
  float v2 = (float)a.z * sa + fminf(fmaxf(rintf(bv.z / sb), -128.f), 127.f) * sb;
  float v3 = (float)a.w * sa + fminf(fmaxf(rintf(bv.w / sb), -128.f), 127.f) * sb;
  float s = v0 + v1 + v2 + v3;
#pragma unroll
  for (int o = 32; o; o >>= 1) s += __shfl_down(s, o, 64);
  if (!(t & 63)) red[t >> 6] = s;
  __syncthreads();
  float mu = ((red[0] + red[1]) + (red[2] + red[3])) * (1.f / TB_E);
  float d0 = v0 - mu, d1 = v1 - mu, d2 = v2 - mu, d3 = v3 - mu;
  float sq = d0 * d0 + d1 * d1 + d2 * d2 + d3 * d3;
#pragma unroll
  for (int o = 32; o; o >>= 1) sq += __shfl_down(sq, o, 64);
  __syncthreads();               // everyone done reading red for mu
  if (!(t & 63)) red[t >> 6] = sq;
  __syncthreads();
  float var = ((red[0] + red[1]) + (red[2] + red[3])) * (1.f / TB_E);
  float rs = 1.f / sqrtf(var + 1e-5f);
  float4 o4;
  o4.x = d0 * rs; o4.y = d1 * rs; o4.z = d2 * rs; o4.w = d3 * rs;
  *(float4*)(outp + base) = o4;
}

// ---------------------------------------------------------------------------
// Host side
// ---------------------------------------------------------------------------
#define SL_X 0
#define SL_WQ 1
#define SL_WK 2
#define SL_WV 3
#define SL_WO 4
#define SL_W1 5
#define SL_W2 6
#define SL_BQ 7
#define SL_BK 8
#define SL_BV 9
#define SL_BO 10
#define SL_B1 11
#define SL_B2 12
#define SL_Q 13
#define SL_K 14
#define SL_V 15
#define SL_SC 16
#define SL_ATTN 17
#define SL_CTX 18
#define SL_AO 19
#define SL_H 20
#define SL_RELU 21
#define SL_M2 22

static inline int nblocks(long n) {
  long b = (n + 255) / 256;
  return (int)(b > 2048 ? 2048 : b);
}

extern "C" void kernel_launch(void* const* d_in, const int* in_sizes, int n_in,
                              void* d_out, int out_size, void* d_ws, size_t ws_size,
                              hipStream_t stream) {
  const float* x  = (const float*)d_in[0];
  const float* Wq = (const float*)d_in[1];
  const float* bq = (const float*)d_in[2];
  const float* Wk = (const float*)d_in[3];
  const float* bk = (const float*)d_in[4];
  const float* Wv = (const float*)d_in[5];
  const float* bv = (const float*)d_in[6];
  const float* Wo = (const float*)d_in[7];
  const float* bo = (const float*)d_in[8];
  const float* W1 = (const float*)d_in[9];
  const float* b1 = (const float*)d_in[10];
  const float* W2 = (const float*)d_in[11];
  const float* b2 = (const float*)d_in[12];
  float* ws = (float*)d_ws;
  float* out = (float*)d_out;

  const long SZ_XE = (long)TB_ROWS * TB_E;      // 4,194,304
  const long SZ_W  = (long)TB_E * TB_E;         // 1,048,576
  const long SZ_M1 = (long)TB_ROWS * TB_MLP;    // 16,777,216

  // float-offset layout
  const long OFF_QBQ = 1024, OFF_QBK = 2048, OFF_QBV = 3072, OFF_QBO = 4096;
  const long OFF_QB1 = 5120, OFF_QB2 = 9216;
  const long OFF_RSUM = 10240;                  // int32[1024]
  const long OFF_Q  = 65536;                    // fp32 q, later ctx (fp32)
  const long OFF_K  = OFF_Q + SZ_XE;            // fp32 k, later attn_out
  const long OFF_V  = OFF_K + SZ_XE;            // fp32 v, later h
  const long OFF_M2 = OFF_V + SZ_XE;            // fp32 m2
  const long OFF_ROWM = OFF_M2 + SZ_XE;
  const long OFF_ROWL = OFF_ROWM + 65536;
  const long OFF_SHARED = OFF_ROWL + 65536;     // gsc (i8, 64MB) then m1 fp32 (64MB)
  const long OFF_I8 = OFF_SHARED + SZ_M1;       // i8 region start (float offset)

  float* qbuf = ws + OFF_Q;  float* kbuf = ws + OFF_K;  float* vbuf = ws + OFF_V;
  float* m2   = ws + OFF_M2;
  float* rowm = ws + OFF_ROWM; float* rowl = ws + OFF_ROWL;
  signed char* gsc = (signed char*)(ws + OFF_SHARED);
  float* m1 = ws + OFF_SHARED;
  float* ctx = qbuf;        // reuse q (after attention)
  float* attn_out = kbuf;   // reuse k
  float* hbuf = vbuf;       // reuse v
  float* qbq_ = ws + OFF_QBQ; float* qbk_ = ws + OFF_QBK;
  float* qbv_ = ws + OFF_QBV; float* qbo_ = ws + OFF_QBO;
  float* qb1_ = ws + OFF_QB1; float* qb2_ = ws + OFF_QB2;
  int* rsum = (int*)(ws + OFF_RSUM);

  // i8 code buffers (byte pointers)
  signed char* i8base = (signed char*)(ws + OFF_I8);
  signed char* qx8  = i8base;                   // 4096x1024
  signed char* wq8  = qx8 + SZ_XE;              // 1024x1024
  signed char* wk8  = wq8 + SZ_W;
  signed char* wv8  = wk8 + SZ_W;
  signed char* wo8  = wv8 + SZ_W;
  signed char* w18  = wo8 + SZ_W;               // 4096x1024
  signed char* w28  = w18 + SZ_XE;              // 1024x4096
  signed char* ctx8 = w28 + SZ_XE;              // 4096x1024
  signed char* m08  = ctx8 + SZ_XE;             // 4096x1024
  signed char* m18  = m08 + SZ_XE;              // 4096x4096 (relu codes - 128)

  hipMemsetAsync(ws, 0, 4096, stream);  // zero scalar slots

  // --- absmax of inputs ---
  absmax_kernel<<<nblocks(SZ_XE), 256, 0, stream>>>(x,  SZ_XE, ws + SL_X, 0);
  absmax_kernel<<<nblocks(SZ_W),  256, 0, stream>>>(Wq, SZ_W,  ws + SL_WQ, 0);
  absmax_kernel<<<nblocks(SZ_W),  256, 0, stream>>>(Wk, SZ_W,  ws + SL_WK, 0);
  absmax_kernel<<<nblocks(SZ_W),  256, 0, stream>>>(Wv, SZ_W,  ws + SL_WV, 0);
  absmax_kernel<<<nblocks(SZ_W),  256, 0, stream>>>(Wo, SZ_W,  ws + SL_WO, 0);
  absmax_kernel<<<nblocks(SZ_XE), 256, 0, stream>>>(W1, SZ_XE, ws + SL_W1, 0);
  absmax_kernel<<<nblocks(SZ_XE), 256, 0, stream>>>(W2, SZ_XE, ws + SL_W2, 0);
  absmax_kernel<<<nblocks(1024), 256, 0, stream>>>(bq, 1024, ws + SL_BQ, 0);
  absmax_kernel<<<nblocks(1024), 256, 0, stream>>>(bk, 1024, ws + SL_BK, 0);
  absmax_kernel<<<nblocks(1024), 256, 0, stream>>>(bv, 1024, ws + SL_BV, 0);
  absmax_kernel<<<nblocks(1024), 256, 0, stream>>>(bo, 1024, ws + SL_BO, 0);
  absmax_kernel<<<nblocks(4096), 256, 0, stream>>>(b1, 4096, ws + SL_B1, 0);
  absmax_kernel<<<nblocks(1024), 256, 0, stream>>>(b2, 1024, ws + SL_B2, 0);

  // --- quantize to int8 codes (GEMM inputs); biases to fp32 ---
  quant8_kernel<<<nblocks(SZ_XE/4), 256, 0, stream>>>(x,  qx8, SZ_XE/4, ws + SL_X, 127.f, -128.f);
  quant8_kernel<<<nblocks(SZ_W/4),  256, 0, stream>>>(Wq, wq8, SZ_W/4,  ws + SL_WQ, 127.f, -127.f);
  quant8_kernel<<<nblocks(SZ_W/4),  256, 0, stream>>>(Wk, wk8, SZ_W/4,  ws + SL_WK, 127.f, -127.f);
  quant8_kernel<<<nblocks(SZ_W/4),  256, 0, stream>>>(Wv, wv8, SZ_W/4,  ws + SL_WV, 127.f, -127.f);
  quant8_kernel<<<nblocks(SZ_W/4),  256, 0, stream>>>(Wo, wo8, SZ_W/4,  ws + SL_WO, 127.f, -127.f);
  quant8_kernel<<<nblocks(SZ_XE/4), 256, 0, stream>>>(W1, w18, SZ_XE/4, ws + SL_W1, 127.f, -127.f);
  quant8_kernel<<<nblocks(SZ_XE/4), 256, 0, stream>>>(W2, w28, SZ_XE/4, ws + SL_W2, 127.f, -127.f);
  rowsum_i8_kernel<<<TB_E, 256, 0, stream>>>(w28, rsum, TB_MLP);
  quant4_kernel<<<1, 256, 0, stream>>>(bq, qbq_, 256, ws + SL_BQ, 1.f, 127.f, -128.f);
  quant4_kernel<<<1, 256, 0, stream>>>(bk, qbk_, 256, ws + SL_BK, 1.f, 127.f, -128.f);
  quant4_kernel<<<1, 256, 0, stream>>>(bv, qbv_, 256, ws + SL_BV, 1.f, 127.f, -128.f);
  quant4_kernel<<<1, 256, 0, stream>>>(bo, qbo_, 256, ws + SL_BO, 1.f, 127.f, -128.f);
  quant4_kernel<<<4, 256, 0, stream>>>(b1, qb1_, 1024, ws + SL_B1, 1.f, 127.f, -128.f);
  quant4_kernel<<<1, 256, 0, stream>>>(b2, qb2_, 256, ws + SL_B2, 1.f, 127.f, -128.f);

  // --- in-projections (int8 MFMA, exact) ---
  gemm_i8_kernel<<<dim3(TB_E/128, TB_ROWS/128), 256, 0, stream>>>(
      qx8, wq8, qbq_, ws + SL_X, 127.f, ws + SL_WQ, nullptr, qbuf, TB_ROWS, TB_E, TB_E);
  gemm_i8_kernel<<<dim3(TB_E/128, TB_ROWS/128), 256, 0, stream>>>(
      qx8, wk8, qbk_, ws + SL_X, 127.f, ws + SL_WK, nullptr, kbuf, TB_ROWS, TB_E, TB_E);
  gemm_i8_kernel<<<dim3(TB_E/128, TB_ROWS/128), 256, 0, stream>>>(
      qx8, wv8, qbv_, ws + SL_X, 127.f, ws + SL_WV, nullptr, vbuf, TB_ROWS, TB_E, TB_E);

  // --- quantize q (scaled by 1/8), k, v in place (fp32 for attention) ---
  absmax_kernel<<<nblocks(SZ_XE), 256, 0, stream>>>(qbuf, SZ_XE, ws + SL_Q, 0);
  absmax_kernel<<<nblocks(SZ_XE), 256, 0, stream>>>(kbuf, SZ_XE, ws + SL_K, 0);
  absmax_kernel<<<nblocks(SZ_XE), 256, 0, stream>>>(vbuf, SZ_XE, ws + SL_V, 0);
  quant4_kernel<<<nblocks(SZ_XE/4), 256, 0, stream>>>(qbuf, qbuf, SZ_XE/4, ws + SL_Q, 0.125f, 127.f, -128.f);
  quant4_kernel<<<nblocks(SZ_XE/4), 256, 0, stream>>>(kbuf, kbuf, SZ_XE/4, ws + SL_K, 1.f, 127.f, -128.f);
  quant4_kernel<<<nblocks(SZ_XE/4), 256, 0, stream>>>(vbuf, vbuf, SZ_XE/4, ws + SL_V, 1.f, 127.f, -128.f);

  // --- attention ---
  attn_scores_amax_kernel<<<dim3(TB_B*TB_H, TB_S/16), 256, 0, stream>>>(qbuf, kbuf, ws + SL_SC);
  attn_scores_qsm_kernel<<<dim3(TB_B*TB_H, TB_S/16), 256, 0, stream>>>(qbuf, kbuf, ws + SL_SC,
                                                                       gsc, rowm, rowl, ws + SL_ATTN);
  attn_pv_kernel<<<dim3(TB_B*TB_H, TB_S/16), 256, 0, stream>>>(gsc, rowm, rowl, vbuf,
                                                               ws + SL_SC, ws + SL_ATTN, ctx);

  // --- out projection ---
  absmax_kernel<<<nblocks(SZ_XE), 256, 0, stream>>>(ctx, SZ_XE, ws + SL_CTX, 0);
  quant8_kernel<<<nblocks(SZ_XE/4), 256, 0, stream>>>(ctx, ctx8, SZ_XE/4, ws + SL_CTX, 127.f, -128.f);
  gemm_i8_kernel<<<dim3(TB_E/128, TB_ROWS/128), 256, 0, stream>>>(
      ctx8, wo8, qbo_, ws + SL_CTX, 127.f, ws + SL_WO, nullptr, attn_out, TB_ROWS, TB_E, TB_E);

  // --- residual + LN ---
  absmax_kernel<<<nblocks(SZ_XE), 256, 0, stream>>>(attn_out, SZ_XE, ws + SL_AO, 0);
  resid_ln_kernel<<<TB_ROWS, 256, 0, stream>>>(qx8, ws + SL_X, attn_out, ws + SL_AO, hbuf);

  // --- MLP ---
  absmax_kernel<<<nblocks(SZ_XE), 256, 0, stream>>>(hbuf, SZ_XE, ws + SL_H, 0);
  quant8_kernel<<<nblocks(SZ_XE/4), 256, 0, stream>>>(hbuf, m08, SZ_XE/4, ws + SL_H, 127.f, -128.f);
  gemm_i8_kernel<<<dim3(TB_MLP/128, TB_ROWS/128), 256, 0, stream>>>(
      m08, w18, qb1_, ws + SL_H, 127.f, ws + SL_W1, nullptr, m1, TB_ROWS, TB_MLP, TB_E);
  absmax_kernel<<<nblocks(SZ_M1), 256, 0, stream>>>(m1, SZ_M1, ws + SL_RELU, 1);   // max(relu)
  relu_quant8_kernel<<<nblocks(SZ_M1/4), 256, 0, stream>>>(m1, m18, SZ_M1/4, ws + SL_RELU);
  gemm_i8_kernel<<<dim3(TB_E/128, TB_ROWS/128), 256, 0, stream>>>(
      m18, w28, qb2_, ws + SL_RELU, 255.f, ws + SL_W2, rsum, m2, TB_ROWS, TB_E, TB_MLP);

  // --- final residual + LN ---
  absmax_kernel<<<nblocks(SZ_XE), 256, 0, stream>>>(m2, SZ_XE, ws + SL_M2, 0);
  resid_ln_kernel<<<TB_ROWS, 256, 0, stream>>>(m08, ws + SL_H, m2, ws + SL_M2, out);
}

// Round 3
// 919.928 us; speedup vs baseline: 3.1092x; 1.6690x over previous
//
#include <hip/hip_runtime.h>
#include <cstdint>
#include <cstddef>

// Problem constants
#define TB_B 4
#define TB_S 1024
#define TB_E 1024
#define TB_H 16
#define TB_D 64
#define TB_MLP 4096
#define TB_ROWS (TB_B * TB_S)   // 4096

typedef int int4v __attribute__((ext_vector_type(4)));

static __device__ __forceinline__ void atomicMaxF(float* addr, float v) {
  // valid for non-negative floats: IEEE bit pattern is monotonic
  atomicMax(reinterpret_cast<unsigned int*>(addr), __float_as_uint(v));
}

// async global->LDS, 16 bytes per lane. LDS dest must be wave-uniform base + lane*16.
static __device__ __forceinline__ void gl2lds16(const void* g, void* l) {
  __builtin_amdgcn_global_load_lds(
      (const __attribute__((address_space(1))) void*)g,
      (__attribute__((address_space(3))) void*)l, 16, 0, 0);
}

// ---------------------------------------------------------------------------
// absmax reduction -> atomicMax into *out (init to 0 first)
// ---------------------------------------------------------------------------
__global__ __launch_bounds__(256) void absmax_kernel(const float* __restrict__ x, long n,
                                                     float* __restrict__ out) {
  float m = 0.f;
  long stride = (long)gridDim.x * 256;
  for (long i = (long)blockIdx.x * 256 + threadIdx.x; i < n; i += stride)
    m = fmaxf(m, fabsf(x[i]));
#pragma unroll
  for (int o = 32; o; o >>= 1) m = fmaxf(m, __shfl_down(m, o, 64));
  __shared__ float sm[4];
  if (!(threadIdx.x & 63)) sm[threadIdx.x >> 6] = m;
  __syncthreads();
  if (threadIdx.x == 0) {
    m = fmaxf(fmaxf(sm[0], sm[1]), fmaxf(sm[2], sm[3]));
    atomicMaxF(out, m);
  }
}

// ---------------------------------------------------------------------------
// fake-quant elementwise -> fp32 (float4): out = clip(round(x*pre/scale))*scale
// ---------------------------------------------------------------------------
__global__ __launch_bounds__(256) void quant4_kernel(const float* __restrict__ in,
                                                     float* __restrict__ outp, long n4,
                                                     const float* __restrict__ amax_p,
                                                     float pre, float qmax, float qmin) {
  float scale = fmaxf(amax_p[0] * pre / qmax, 1e-8f);
  long stride = (long)gridDim.x * 256;
  for (long i = (long)blockIdx.x * 256 + threadIdx.x; i < n4; i += stride) {
    float4 v = ((const float4*)in)[i];
    float4 o;
    o.x = fminf(fmaxf(rintf(v.x * pre / scale), qmin), qmax) * scale;
    o.y = fminf(fmaxf(rintf(v.y * pre / scale), qmin), qmax) * scale;
    o.z = fminf(fmaxf(rintf(v.z * pre / scale), qmin), qmax) * scale;
    o.w = fminf(fmaxf(rintf(v.w * pre / scale), qmin), qmax) * scale;
    ((float4*)outp)[i] = o;
  }
}

// fake-quant elementwise -> int8 codes (scale = amax*pre/qmax)
__global__ __launch_bounds__(256) void quant8_kernel(const float* __restrict__ in,
                                                     signed char* __restrict__ out8, long n4,
                                                     const float* __restrict__ amax_p,
                                                     float pre, float qmax, float qmin) {
  float scale = fmaxf(amax_p[0] * pre / qmax, 1e-8f);
  long stride = (long)gridDim.x * 256;
  for (long i = (long)blockIdx.x * 256 + threadIdx.x; i < n4; i += stride) {
    float4 v = ((const float4*)in)[i];
    char4 o;
    o.x = (signed char)(int)fminf(fmaxf(rintf(v.x * pre / scale), qmin), qmax);
    o.y = (signed char)(int)fminf(fmaxf(rintf(v.y * pre / scale), qmin), qmax);
    o.z = (signed char)(int)fminf(fmaxf(rintf(v.z * pre / scale), qmin), qmax);
    o.w = (signed char)(int)fminf(fmaxf(rintf(v.w * pre / scale), qmin), qmax);
    ((char4*)out8)[i] = o;
  }
}

// relu + unsigned 8-bit quant -> codes stored as (c - 128) in signed i8
__global__ __launch_bounds__(256) void relu_quant8_kernel(const float* __restrict__ in,
                                                          signed char* __restrict__ out8, long n4,
                                                          const float* __restrict__ amax_p) {
  float scale = fmaxf(amax_p[0] / 255.f, 1e-8f);
  long stride = (long)gridDim.x * 256;
  for (long i = (long)blockIdx.x * 256 + threadIdx.x; i < n4; i += stride) {
    float4 v = ((const float4*)in)[i];
    char4 o;
    o.x = (signed char)((int)fminf(fmaxf(rintf(fmaxf(v.x, 0.f) / scale), 0.f), 255.f) - 128);
    o.y = (signed char)((int)fminf(fmaxf(rintf(fmaxf(v.y, 0.f) / scale), 0.f), 255.f) - 128);
    o.z = (signed char)((int)fminf(fmaxf(rintf(fmaxf(v.z, 0.f) / scale), 0.f), 255.f) - 128);
    o.w = (signed char)((int)fminf(fmaxf(rintf(fmaxf(v.w, 0.f) / scale), 0.f), 255.f) - 128);
    ((char4*)out8)[i] = o;
  }
}

// per-row sum of int8 codes (for unsigned-offset correction); one block per row
__global__ __launch_bounds__(256) void rowsum_i8_kernel(const signed char* __restrict__ w8,
                                                        int* __restrict__ out, int Kdim) {
  const int row = blockIdx.x, t = threadIdx.x;
  const signed char* p = w8 + (long)row * Kdim;
  int s = 0;
  for (int i = t * 16; i < Kdim; i += 4096) {
    int4v v = *(const int4v*)(p + i);
    const signed char* b = (const signed char*)&v;
#pragma unroll
    for (int j = 0; j < 16; j++) s += b[j];
  }
#pragma unroll
  for (int o = 32; o; o >>= 1) s += __shfl_down(s, o, 64);
  __shared__ int sm[4];
  if (!(t & 63)) sm[t >> 6] = s;
  __syncthreads();
  if (t == 0) out[row] = sm[0] + sm[1] + sm[2] + sm[3];
}

// ---------------------------------------------------------------------------
// int8 MFMA NT GEMM (exact): C[M,N] = (sum_k A8[m,k]*B8[n,k] + corr) * s_a*s_b + bias[n]
// Fused output absmax (or relu-max) -> atomicMaxF(amax_out).
// ---------------------------------------------------------------------------
__global__ __launch_bounds__(256) void gemm_i8_kernel(
    const signed char* __restrict__ A, const signed char* __restrict__ Bw,
    const float* __restrict__ biasq,
    const float* __restrict__ amax_a, float div_a,
    const float* __restrict__ amax_b,
    const int* __restrict__ rowsum,           // nullable: adds 128*rowsum[n]
    float* __restrict__ C, int M, int N, int K,
    float* __restrict__ amax_out, int relu_amax) {
  __shared__ signed char As[8192];  // 128 rows x 64 bytes, K-contiguous
  __shared__ signed char Bs[8192];
  const int t = threadIdx.x;
  const int m0 = blockIdx.y * 128, n0 = blockIdx.x * 128;
  const int w = t >> 6, lane = t & 63;
  const int fr = lane & 15, quad = lane >> 4;
  const int r0 = t >> 2;            // staging row 0..63
  const int c0 = (t & 3) * 16;      // staging byte col
  const int a_off0 = (w * 32 + fr) * 64 + quad * 16;
  const int b_off0 = fr * 64 + quad * 16;

  int4v acc[2][8];
#pragma unroll
  for (int r = 0; r < 2; r++)
#pragma unroll
    for (int c = 0; c < 8; c++) acc[r][c] = (int4v){0, 0, 0, 0};

  for (int k0 = 0; k0 < K; k0 += 64) {
    __syncthreads();
    gl2lds16(A + (long)(m0 + r0) * K + k0 + c0, As + t * 16);
    gl2lds16(A + (long)(m0 + r0 + 64) * K + k0 + c0, As + t * 16 + 4096);
    gl2lds16(Bw + (long)(n0 + r0) * K + k0 + c0, Bs + t * 16);
    gl2lds16(Bw + (long)(n0 + r0 + 64) * K + k0 + c0, Bs + t * 16 + 4096);
    __syncthreads();
    int4v af[2], bf[8];
#pragma unroll
    for (int r = 0; r < 2; r++) af[r] = *(const int4v*)(As + a_off0 + r * 1024);
#pragma unroll
    for (int c = 0; c < 8; c++) bf[c] = *(const int4v*)(Bs + b_off0 + c * 1024);
#pragma unroll
    for (int r = 0; r < 2; r++)
#pragma unroll
      for (int c = 0; c < 8; c++)
        acc[r][c] = __builtin_amdgcn_mfma_i32_16x16x64_i8(af[r], bf[c], acc[r][c], 0, 0, 0);
  }

  const float s_a = fmaxf(amax_a[0] / div_a, 1e-8f);
  const float s_b = fmaxf(amax_b[0] / 127.f, 1e-8f);
  const float s = s_a * s_b;
  float lmax = 0.f;
#pragma unroll
  for (int r = 0; r < 2; r++) {
    int rbase = m0 + w * 32 + r * 16 + quad * 4;
#pragma unroll
    for (int c = 0; c < 8; c++) {
      int col = n0 + c * 16 + fr;
      int corr = rowsum ? (rowsum[col] << 7) : 0;
      float bi = biasq[col];
#pragma unroll
      for (int g = 0; g < 4; g++) {
        float o = (float)(acc[r][c][g] + corr) * s + bi;
        lmax = fmaxf(lmax, relu_amax ? fmaxf(o, 0.f) : fabsf(o));
        C[(long)(rbase + g) * N + col] = o;
      }
    }
  }
#pragma unroll
  for (int o = 32; o; o >>= 1) lmax = fmaxf(lmax, __shfl_down(lmax, o, 64));
  __shared__ float redm[4];
  if (!lane) redm[w] = lmax;
  __syncthreads();
  if (t == 0) atomicMaxF(amax_out, fmaxf(fmaxf(redm[0], redm[1]), fmaxf(redm[2], redm[3])));
}

// ---------------------------------------------------------------------------
// Attention pass A: integer absmax of scores = q8 @ k8^T per (b,h).
// Orientation: mfma(A=k_frag, B=q_frag) -> D[m=j][n=i]; layout irrelevant here.
// grid (64 bh, 16 i-tiles of 64 rows), 256 threads = 4 waves x 16 q-rows.
// ---------------------------------------------------------------------------
__global__ __launch_bounds__(256) void attn_amax_kernel(const signed char* __restrict__ q8,
                                                        const signed char* __restrict__ k8,
                                                        int* __restrict__ imax_out) {
  const int bh = blockIdx.x, b = bh >> 4, h = bh & 15;
  const int t = threadIdx.x, w = t >> 6, lane = t & 63;
  const int fr = lane & 15, quad = lane >> 4;
  const int i0 = blockIdx.y * 64 + w * 16;
  int4v qf = *(const int4v*)(q8 + (((long)(b * TB_S + i0 + fr)) * TB_H + h) * TB_D + quad * 16);
  int im = 0;
  for (int j0 = 0; j0 < TB_S; j0 += 16) {
    int4v kf = *(const int4v*)(k8 + (((long)(b * TB_S + j0 + fr)) * TB_H + h) * TB_D + quad * 16);
    int4v sc = __builtin_amdgcn_mfma_i32_16x16x64_i8(kf, qf, (int4v){0, 0, 0, 0}, 0, 0, 0);
#pragma unroll
    for (int g = 0; g < 4; g++) {
      int a = sc[g] < 0 ? -sc[g] : sc[g];
      im = im > a ? im : a;
    }
  }
#pragma unroll
  for (int o = 32; o; o >>= 1) im = max(im, __shfl_down(im, o, 64));
  __shared__ int sm[4];
  if (!lane) sm[w] = im;
  __syncthreads();
  if (t == 0) atomicMax(imax_out, max(max(sm[0], sm[1]), max(sm[2], sm[3])));
}

// ---------------------------------------------------------------------------
// Attention pass B: recompute scores, quantize in-register, online softmax ->
// rowm/rowl per q-row, amax_attn = max(1/l).
// D[m=j][n=i]: lane holds i = i0+fr fixed, j = j0 + quad*4 + g.
// ---------------------------------------------------------------------------
__global__ __launch_bounds__(256) void attn_rowstats_kernel(
    const signed char* __restrict__ q8, const signed char* __restrict__ k8,
    const int* __restrict__ imax_p,
    const float* __restrict__ amax_q, const float* __restrict__ amax_k,
    float* __restrict__ rowm, float* __restrict__ rowl,
    float* __restrict__ amax_attn) {
  const int bh = blockIdx.x, b = bh >> 4, h = bh & 15;
  const int t = threadIdx.x, w = t >> 6, lane = t & 63;
  const int fr = lane & 15, quad = lane >> 4;
  const int i0 = blockIdx.y * 64 + w * 16;
  const float s_q = fmaxf(amax_q[0] * 0.125f / 127.f, 1e-8f);
  const float s_k = fmaxf(amax_k[0] / 127.f, 1e-8f);
  const float sqk = s_q * s_k;
  const float s_sc = fmaxf((float)imax_p[0] * sqk / 127.f, 1e-8f);
  int4v qf = *(const int4v*)(q8 + (((long)(b * TB_S + i0 + fr)) * TB_H + h) * TB_D + quad * 16);
  float m_t[4], l_t[4];
#pragma unroll
  for (int g = 0; g < 4; g++) { m_t[g] = -INFINITY; l_t[g] = 0.f; }
  for (int j0 = 0; j0 < TB_S; j0 += 16) {
    int4v kf = *(const int4v*)(k8 + (((long)(b * TB_S + j0 + fr)) * TB_H + h) * TB_D + quad * 16);
    int4v sc = __builtin_amdgcn_mfma_i32_16x16x64_i8(kf, qf, (int4v){0, 0, 0, 0}, 0, 0, 0);
#pragma unroll
    for (int g = 0; g < 4; g++) {
      float fsc = (float)sc[g] * sqk;
      float qv = fminf(fmaxf(rintf(fsc / s_sc), -128.f), 127.f);
      float val = qv * s_sc;
      float mn = fmaxf(m_t[g], val);
      l_t[g] = l_t[g] * expf(m_t[g] - mn) + expf(val - mn);
      m_t[g] = mn;
    }
  }
  // merge the 4 per-lane partials (all same row i)
  float m = m_t[0], l = l_t[0];
#pragma unroll
  for (int g = 1; g < 4; g++) {
    float mn = fmaxf(m, m_t[g]);
    l = l * expf(m - mn) + l_t[g] * expf(m_t[g] - mn);
    m = mn;
  }
  // merge across the 4 quads (lanes fr, fr+16, fr+32, fr+48)
#pragma unroll
  for (int off = 16; off <= 32; off <<= 1) {
    float mo = __shfl_xor(m, off, 64), lo = __shfl_xor(l, off, 64);
    float mn = fmaxf(m, mo);
    l = l * expf(m - mn) + lo * expf(mo - mn);
    m = mn;
  }
  if (quad == 0) {
    rowm[(long)bh * TB_S + i0 + fr] = m;
    rowl[(long)bh * TB_S + i0 + fr] = l;
  }
  float inv = (quad == 0) ? 1.f / l : 0.f;
#pragma unroll
  for (int o = 32; o; o >>= 1) inv = fmaxf(inv, __shfl_down(inv, o, 64));
  __shared__ float smf[4];
  if (!lane) smf[w] = inv;
  __syncthreads();
  if (t == 0) atomicMaxF(amax_attn, fmaxf(fmaxf(smf[0], smf[1]), fmaxf(smf[2], smf[3])));
}

// ---------------------------------------------------------------------------
// Attention pass C: recompute scores (identical expr -> identical codes),
// softmax via rowm/rowl, quantize attn -> i8, LDS transpose, PV i8 MFMA.
// ctx fp32 in [B,S,H,D] + fused ctx absmax.
// ---------------------------------------------------------------------------
__global__ __launch_bounds__(256) void attn_pv_kernel(
    const signed char* __restrict__ q8, const signed char* __restrict__ k8,
    const signed char* __restrict__ v8t,
    const int* __restrict__ imax_p,
    const float* __restrict__ amax_q, const float* __restrict__ amax_k,
    const float* __restrict__ amax_v, const float* __restrict__ amax_attn,
    const float* __restrict__ rowm, const float* __restrict__ rowl,
    float* __restrict__ ctx, float* __restrict__ amax_ctx) {
  __shared__ signed char latt[4][16][80];  // [wave][i-rel][j-chunk], stride 80 (16B-aligned rows, ~2-way banks)
  const int bh = blockIdx.x, b = bh >> 4, h = bh & 15;
  const int t = threadIdx.x, w = t >> 6, lane = t & 63;
  const int fr = lane & 15, quad = lane >> 4;
  const int i0 = blockIdx.y * 64 + w * 16;
  const float s_q = fmaxf(amax_q[0] * 0.125f / 127.f, 1e-8f);
  const float s_k = fmaxf(amax_k[0] / 127.f, 1e-8f);
  const float sqk = s_q * s_k;
  const float s_sc = fmaxf((float)imax_p[0] * sqk / 127.f, 1e-8f);
  const float s_v = fmaxf(amax_v[0] / 127.f, 1e-8f);
  const float s_at = fmaxf(amax_attn[0] / 127.f, 1e-8f);
  int4v qf = *(const int4v*)(q8 + (((long)(b * TB_S + i0 + fr)) * TB_H + h) * TB_D + quad * 16);
  const float mi = rowm[(long)bh * TB_S + i0 + fr];
  const float li = rowl[(long)bh * TB_S + i0 + fr];
  int4v accv[4];
#pragma unroll
  for (int dtile = 0; dtile < 4; dtile++) accv[dtile] = (int4v){0, 0, 0, 0};

  for (int j0 = 0; j0 < TB_S; j0 += 64) {
#pragma unroll
    for (int tt = 0; tt < 4; tt++) {
      int4v kf = *(const int4v*)(k8 + (((long)(b * TB_S + j0 + tt * 16 + fr)) * TB_H + h) * TB_D + quad * 16);
      int4v sc = __builtin_amdgcn_mfma_i32_16x16x64_i8(kf, qf, (int4v){0, 0, 0, 0}, 0, 0, 0);
      int packed = 0;
#pragma unroll
      for (int g = 0; g < 4; g++) {
        float fsc = (float)sc[g] * sqk;
        float qv = fminf(fmaxf(rintf(fsc / s_sc), -128.f), 127.f);
        float val = qv * s_sc;
        float p = expf(val - mi) / li;
        int code = (int)fminf(fmaxf(rintf(p / s_at), -128.f), 127.f);
        packed |= (code & 255) << (g * 8);
      }
      *(int*)&latt[w][fr][tt * 16 + quad * 4] = packed;
    }
    __syncthreads();
    int4v af = *(const int4v*)&latt[w][fr][quad * 16];
#pragma unroll
    for (int dtile = 0; dtile < 4; dtile++) {
      int4v vf = *(const int4v*)(v8t + ((long)(b * TB_H + h) * TB_D + dtile * 16 + fr) * TB_S + j0 + quad * 16);
      accv[dtile] = __builtin_amdgcn_mfma_i32_16x16x64_i8(af, vf, accv[dtile], 0, 0, 0);
    }
    __syncthreads();
  }
  const float sav = s_at * s_v;
  float cmax = 0.f;
#pragma unroll
  for (int dtile = 0; dtile < 4; dtile++) {
#pragma unroll
    for (int g = 0; g < 4; g++) {
      float val = (float)accv[dtile][g] * sav;
      cmax = fmaxf(cmax, fabsf(val));
      int irow = i0 + quad * 4 + g;
      ctx[(((long)(b * TB_S + irow)) * TB_H + h) * TB_D + dtile * 16 + fr] = val;
    }
  }
#pragma unroll
  for (int o = 32; o; o >>= 1) cmax = fmaxf(cmax, __shfl_down(cmax, o, 64));
  __shared__ float smf[4];
  if (!lane) smf[w] = cmax;
  __syncthreads();
  if (t == 0) atomicMaxF(amax_ctx, fmaxf(fmaxf(smf[0], smf[1]), fmaxf(smf[2], smf[3])));
}

// ---------------------------------------------------------------------------
// v quant + transpose: fp32 [B,S,H,D] -> i8 [B,H,D,S]
// grid (64 bh, 16 s-tiles), block 256
// ---------------------------------------------------------------------------
__global__ __launch_bounds__(256) void quant8_vT_kernel(const float* __restrict__ v,
                                                        const float* __restrict__ amax_p,
                                                        signed char* __restrict__ v8t) {
  __shared__ signed char tile[64][80];  // [d][s], stride 80
  const int bh = blockIdx.x, b = bh >> 4, h = bh & 15;
  const int s0 = blockIdx.y * 64;
  const int t = threadIdx.x;
  const float scale = fmaxf(amax_p[0] / 127.f, 1e-8f);
#pragma unroll
  for (int it = 0; it < 4; it++) {
    int idx = t + it * 256;           // 0..1023 float4 slots
    int r = idx >> 4, c4 = (idx & 15) * 4;
    float4 vv = *(const float4*)(v + (((long)(b * TB_S + s0 + r)) * TB_H + h) * TB_D + c4);
    tile[c4 + 0][r] = (signed char)(int)fminf(fmaxf(rintf(vv.x / scale), -128.f), 127.f);
    tile[c4 + 1][r] = (signed char)(int)fminf(fmaxf(rintf(vv.y / scale), -128.f), 127.f);
    tile[c4 + 2][r] = (signed char)(int)fminf(fmaxf(rintf(vv.z / scale), -128.f), 127.f);
    tile[c4 + 3][r] = (signed char)(int)fminf(fmaxf(rintf(vv.w / scale), -128.f), 127.f);
  }
  __syncthreads();
  int d = t >> 2, sb = (t & 3) * 16;
  int4v o = *(const int4v*)&tile[d][sb];
  *(int4v*)(v8t + ((long)(b * TB_H + h) * TB_D + d) * TB_S + s0 + sb) = o;
}

// ---------------------------------------------------------------------------
// h = LayerNorm(dequant(a8) + fakequant(braw)); fused output absmax.
// ---------------------------------------------------------------------------
__global__ __launch_bounds__(256) void resid_ln_kernel(const signed char* __restrict__ a8,
                                                       const float* __restrict__ amax_a,
                                                       const float* __restrict__ braw,
                                                       const float* __restrict__ amax_b,
                                                       float* __restrict__ outp,
                                                       float* __restrict__ amax_out) {
  __shared__ float red[4];
  __shared__ float redm[4];
  const int row = blockIdx.x, t = threadIdx.x;
  const float sa = fmaxf(amax_a[0] / 127.f, 1e-8f);
  const float sb = fmaxf(amax_b[0] / 127.f, 1e-8f);
  const long base = (long)row * TB_E + t * 4;
  char4 a = ((const char4*)a8)[(long)row * 256 + t];
  float4 bv = *(const float4*)(braw + base);
  float v0 = (float)a.x * sa + fminf(fmaxf(rintf(bv.x / sb), -128.f), 127.f) * sb;
  float v1 = (float)a.y * sa + fminf(fmaxf(rintf(bv.y / sb), -128.f), 127.f) * sb;
  float v2 = (float)a.z * sa + fminf(fmaxf(rintf(bv.z / sb), -128.f), 127.f) * sb;
  float v3 = (float)a.w * sa + fminf(fmaxf(rintf(bv.w / sb), -128.f), 127.f) * sb;
  float s = v0 + v1 + v2 + v3;
#pragma unroll
  for (int o = 32; o; o >>= 1) s += __shfl_down(s, o, 64);
  if (!(t & 63)) red[t >> 6] = s;
  __syncthreads();
  float mu = ((red[0] + red[1]) + (red[2] + red[3])) * (1.f / TB_E);
  float d0 = v0 - mu, d1 = v1 - mu, d2 = v2 - mu, d3 = v3 - mu;
  float sq = d0 * d0 + d1 * d1 + d2 * d2 + d3 * d3;
#pragma unroll
  for (int o = 32; o; o >>= 1) sq += __shfl_down(sq, o, 64);
  __syncthreads();
  if (!(t & 63)) red[t >> 6] = sq;
  __syncthreads();
  float var = ((red[0] + red[1]) + (red[2] + red[3])) * (1.f / TB_E);
  float rs = 1.f / sqrtf(var + 1e-5f);
  float4 o4;
  o4.x = d0 * rs; o4.y = d1 * rs; o4.z = d2 * rs; o4.w = d3 * rs;
  *(float4*)(outp + base) = o4;
  float lm = fmaxf(fmaxf(fabsf(o4.x), fabsf(o4.y)), fmaxf(fabsf(o4.z), fabsf(o4.w)));
#pragma unroll
  for (int o = 32; o; o >>= 1) lm = fmaxf(lm, __shfl_down(lm, o, 64));
  if (!(t & 63)) redm[t >> 6] = lm;
  __syncthreads();
  if (t == 0) atomicMaxF(amax_out, fmaxf(fmaxf(redm[0], redm[1]), fmaxf(redm[2], redm[3])));
}

// ---------------------------------------------------------------------------
// Host side
// ---------------------------------------------------------------------------
#define SL_X 0
#define SL_WQ 1
#define SL_WK 2
#define SL_WV 3
#define SL_WO 4
#define SL_W1 5
#define SL_W2 6
#define SL_BQ 7
#define SL_BK 8
#define SL_BV 9
#define SL_BO 10
#define SL_B1 11
#define SL_B2 12
#define SL_Q 13
#define SL_K 14
#define SL_V 15
#define SL_SCI 16     // int imax of scores
#define SL_ATTN 17
#define SL_CTX 18
#define SL_AO 19
#define SL_H 20
#define SL_RELU 21
#define SL_M2 22
#define SL_DUMMY 23

static inline int nblocks(long n) {
  long b = (n + 255) / 256;
  return (int)(b > 2048 ? 2048 : b);
}

extern "C" void kernel_launch(void* const* d_in, const int* in_sizes, int n_in,
                              void* d_out, int out_size, void* d_ws, size_t ws_size,
                              hipStream_t stream) {
  const float* x  = (const float*)d_in[0];
  const float* Wq = (const float*)d_in[1];
  const float* bq = (const float*)d_in[2];
  const float* Wk = (const float*)d_in[3];
  const float* bk = (const float*)d_in[4];
  const float* Wv = (const float*)d_in[5];
  const float* bv = (const float*)d_in[6];
  const float* Wo = (const float*)d_in[7];
  const float* bo = (const float*)d_in[8];
  const float* W1 = (const float*)d_in[9];
  const float* b1 = (const float*)d_in[10];
  const float* W2 = (const float*)d_in[11];
  const float* b2 = (const float*)d_in[12];
  float* ws = (float*)d_ws;
  float* out = (float*)d_out;

  const long SZ_XE = (long)TB_ROWS * TB_E;      // 4,194,304
  const long SZ_W  = (long)TB_E * TB_E;         // 1,048,576
  const long SZ_M1 = (long)TB_ROWS * TB_MLP;    // 16,777,216

  // float-offset layout
  const long OFF_QBQ = 1024, OFF_QBK = 2048, OFF_QBV = 3072, OFF_QBO = 4096;
  const long OFF_QB1 = 5120, OFF_QB2 = 9216;
  const long OFF_RSUM = 10240;                  // int32[1024]
  const long OFF_Q  = 65536;                    // fp32 q, later ctx
  const long OFF_K  = OFF_Q + SZ_XE;            // fp32 k, later attn_out
  const long OFF_V  = OFF_K + SZ_XE;            // fp32 v, later h
  const long OFF_M2 = OFF_V + SZ_XE;            // fp32 m2
  const long OFF_ROWM = OFF_M2 + SZ_XE;
  const long OFF_ROWL = OFF_ROWM + 65536;
  const long OFF_M1 = OFF_ROWL + 65536;         // fp32 m1 (64MB)
  const long OFF_I8 = OFF_M1 + SZ_M1;           // i8 region start (float offset)

  float* qbuf = ws + OFF_Q;  float* kbuf = ws + OFF_K;  float* vbuf = ws + OFF_V;
  float* m2   = ws + OFF_M2;
  float* rowm = ws + OFF_ROWM; float* rowl = ws + OFF_ROWL;
  float* m1 = ws + OFF_M1;
  float* ctx = qbuf;        // reuse q (q8 codes already extracted)
  float* attn_out = kbuf;   // reuse k
  float* hbuf = vbuf;       // reuse v
  float* qbq_ = ws + OFF_QBQ; float* qbk_ = ws + OFF_QBK;
  float* qbv_ = ws + OFF_QBV; float* qbo_ = ws + OFF_QBO;
  float* qb1_ = ws + OFF_QB1; float* qb2_ = ws + OFF_QB2;
  int* rsum = (int*)(ws + OFF_RSUM);
  int* imax = (int*)(ws + SL_SCI);

  // i8 code buffers (byte pointers)
  signed char* i8base = (signed char*)(ws + OFF_I8);
  signed char* qx8  = i8base;                   // 4096x1024
  signed char* wq8  = qx8 + SZ_XE;              // 1024x1024
  signed char* wk8  = wq8 + SZ_W;
  signed char* wv8  = wk8 + SZ_W;
  signed char* wo8  = wv8 + SZ_W;
  signed char* w18  = wo8 + SZ_W;               // 4096x1024
  signed char* w28  = w18 + SZ_XE;              // 1024x4096
  signed char* ctx8 = w28 + SZ_XE;              // 4096x1024
  signed char* m08  = ctx8 + SZ_XE;             // 4096x1024
  signed char* m18  = m08 + SZ_XE;              // 4096x4096 (relu codes - 128)
  signed char* q8   = m18 + SZ_M1;              // [B,S,H,D]
  signed char* k8   = q8 + SZ_XE;               // [B,S,H,D]
  signed char* v8t  = k8 + SZ_XE;               // [B,H,D,S]

  hipMemsetAsync(ws, 0, 4096, stream);  // zero scalar slots

  // --- absmax of inputs ---
  absmax_kernel<<<nblocks(SZ_XE), 256, 0, stream>>>(x,  SZ_XE, ws + SL_X);
  absmax_kernel<<<nblocks(SZ_W),  256, 0, stream>>>(Wq, SZ_W,  ws + SL_WQ);
  absmax_kernel<<<nblocks(SZ_W),  256, 0, stream>>>(Wk, SZ_W,  ws + SL_WK);
  absmax_kernel<<<nblocks(SZ_W),  256, 0, stream>>>(Wv, SZ_W,  ws + SL_WV);
  absmax_kernel<<<nblocks(SZ_W),  256, 0, stream>>>(Wo, SZ_W,  ws + SL_WO);
  absmax_kernel<<<nblocks(SZ_XE), 256, 0, stream>>>(W1, SZ_XE, ws + SL_W1);
  absmax_kernel<<<nblocks(SZ_XE), 256, 0, stream>>>(W2, SZ_XE, ws + SL_W2);
  absmax_kernel<<<nblocks(1024), 256, 0, stream>>>(bq, 1024, ws + SL_BQ);
  absmax_kernel<<<nblocks(1024), 256, 0, stream>>>(bk, 1024, ws + SL_BK);
  absmax_kernel<<<nblocks(1024), 256, 0, stream>>>(bv, 1024, ws + SL_BV);
  absmax_kernel<<<nblocks(1024), 256, 0, stream>>>(bo, 1024, ws + SL_BO);
  absmax_kernel<<<nblocks(4096), 256, 0, stream>>>(b1, 4096, ws + SL_B1);
  absmax_kernel<<<nblocks(1024), 256, 0, stream>>>(b2, 1024, ws + SL_B2);

  // --- quantize to int8 codes (GEMM inputs); biases to fp32 ---
  quant8_kernel<<<nblocks(SZ_XE/4), 256, 0, stream>>>(x,  qx8, SZ_XE/4, ws + SL_X, 1.f, 127.f, -128.f);
  quant8_kernel<<<nblocks(SZ_W/4),  256, 0, stream>>>(Wq, wq8, SZ_W/4,  ws + SL_WQ, 1.f, 127.f, -127.f);
  quant8_kernel<<<nblocks(SZ_W/4),  256, 0, stream>>>(Wk, wk8, SZ_W/4,  ws + SL_WK, 1.f, 127.f, -127.f);
  quant8_kernel<<<nblocks(SZ_W/4),  256, 0, stream>>>(Wv, wv8, SZ_W/4,  ws + SL_WV, 1.f, 127.f, -127.f);
  quant8_kernel<<<nblocks(SZ_W/4),  256, 0, stream>>>(Wo, wo8, SZ_W/4,  ws + SL_WO, 1.f, 127.f, -127.f);
  quant8_kernel<<<nblocks(SZ_XE/4), 256, 0, stream>>>(W1, w18, SZ_XE/4, ws + SL_W1, 1.f, 127.f, -127.f);
  quant8_kernel<<<nblocks(SZ_XE/4), 256, 0, stream>>>(W2, w28, SZ_XE/4, ws + SL_W2, 1.f, 127.f, -127.f);
  rowsum_i8_kernel<<<TB_E, 256, 0, stream>>>(w28, rsum, TB_MLP);
  quant4_kernel<<<1, 256, 0, stream>>>(bq, qbq_, 256, ws + SL_BQ, 1.f, 127.f, -128.f);
  quant4_kernel<<<1, 256, 0, stream>>>(bk, qbk_, 256, ws + SL_BK, 1.f, 127.f, -128.f);
  quant4_kernel<<<1, 256, 0, stream>>>(bv, qbv_, 256, ws + SL_BV, 1.f, 127.f, -128.f);
  quant4_kernel<<<1, 256, 0, stream>>>(bo, qbo_, 256, ws + SL_BO, 1.f, 127.f, -128.f);
  quant4_kernel<<<4, 256, 0, stream>>>(b1, qb1_, 1024, ws + SL_B1, 1.f, 127.f, -128.f);
  quant4_kernel<<<1, 256, 0, stream>>>(b2, qb2_, 256, ws + SL_B2, 1.f, 127.f, -128.f);

  // --- in-projections (int8 MFMA, exact) with fused output absmax ---
  gemm_i8_kernel<<<dim3(TB_E/128, TB_ROWS/128), 256, 0, stream>>>(
      qx8, wq8, qbq_, ws + SL_X, 127.f, ws + SL_WQ, nullptr, qbuf, TB_ROWS, TB_E, TB_E, ws + SL_Q, 0);
  gemm_i8_kernel<<<dim3(TB_E/128, TB_ROWS/128), 256, 0, stream>>>(
      qx8, wk8, qbk_, ws + SL_X, 127.f, ws + SL_WK, nullptr, kbuf, TB_ROWS, TB_E, TB_E, ws + SL_K, 0);
  gemm_i8_kernel<<<dim3(TB_E/128, TB_ROWS/128), 256, 0, stream>>>(
      qx8, wv8, qbv_, ws + SL_X, 127.f, ws + SL_WV, nullptr, vbuf, TB_ROWS, TB_E, TB_E, ws + SL_V, 0);

  // --- quantize q (pre=1/8), k to i8 codes; v transposed ---
  quant8_kernel<<<nblocks(SZ_XE/4), 256, 0, stream>>>(qbuf, q8, SZ_XE/4, ws + SL_Q, 0.125f, 127.f, -128.f);
  quant8_kernel<<<nblocks(SZ_XE/4), 256, 0, stream>>>(kbuf, k8, SZ_XE/4, ws + SL_K, 1.f, 127.f, -128.f);
  quant8_vT_kernel<<<dim3(TB_B*TB_H, TB_S/64), 256, 0, stream>>>(vbuf, ws + SL_V, v8t);

  // --- attention (i8 MFMA, 3 passes) ---
  attn_amax_kernel<<<dim3(TB_B*TB_H, TB_S/64), 256, 0, stream>>>(q8, k8, imax);
  attn_rowstats_kernel<<<dim3(TB_B*TB_H, TB_S/64), 256, 0, stream>>>(
      q8, k8, imax, ws + SL_Q, ws + SL_K, rowm, rowl, ws + SL_ATTN);
  attn_pv_kernel<<<dim3(TB_B*TB_H, TB_S/64), 256, 0, stream>>>(
      q8, k8, v8t, imax, ws + SL_Q, ws + SL_K, ws + SL_V, ws + SL_ATTN,
      rowm, rowl, ctx, ws + SL_CTX);

  // --- out projection ---
  quant8_kernel<<<nblocks(SZ_XE/4), 256, 0, stream>>>(ctx, ctx8, SZ_XE/4, ws + SL_CTX, 1.f, 127.f, -128.f);
  gemm_i8_kernel<<<dim3(TB_E/128, TB_ROWS/128), 256, 0, stream>>>(
      ctx8, wo8, qbo_, ws + SL_CTX, 127.f, ws + SL_WO, nullptr, attn_out, TB_ROWS, TB_E, TB_E, ws + SL_AO, 0);

  // --- residual + LN (fused h absmax) ---
  resid_ln_kernel<<<TB_ROWS, 256, 0, stream>>>(qx8, ws + SL_X, attn_out, ws + SL_AO, hbuf, ws + SL_H);

  // --- MLP ---
  quant8_kernel<<<nblocks(SZ_XE/4), 256, 0, stream>>>(hbuf, m08, SZ_XE/4, ws + SL_H, 1.f, 127.f, -128.f);
  gemm_i8_kernel<<<dim3(TB_MLP/128, TB_ROWS/128), 256, 0, stream>>>(
      m08, w18, qb1_, ws + SL_H, 127.f, ws + SL_W1, nullptr, m1, TB_ROWS, TB_MLP, TB_E, ws + SL_RELU, 1);
  relu_quant8_kernel<<<nblocks(SZ_M1/4), 256, 0, stream>>>(m1, m18, SZ_M1/4, ws + SL_RELU);
  gemm_i8_kernel<<<dim3(TB_E/128, TB_ROWS/128), 256, 0, stream>>>(
      m18, w28, qb2_, ws + SL_RELU, 255.f, ws + SL_W2, rsum, m2, TB_ROWS, TB_E, TB_MLP, ws + SL_M2, 0);

  // --- final residual + LN ---
  resid_ln_kernel<<<TB_ROWS, 256, 0, stream>>>(m08, ws + SL_H, m2, ws + SL_M2, out, ws + SL_DUMMY);
}

// Round 4
// 839.024 us; speedup vs baseline: 3.4090x; 1.0964x over previous
//
#include <hip/hip_runtime.h>
#include <cstdint>
#include <cstddef>

// Problem constants
#define TB_B 4
#define TB_S 1024
#define TB_E 1024
#define TB_H 16
#define TB_D 64
#define TB_MLP 4096
#define TB_ROWS (TB_B * TB_S)   // 4096

typedef int int4v __attribute__((ext_vector_type(4)));

static __device__ __forceinline__ void atomicMaxF(float* addr, float v) {
  // valid for non-negative floats: IEEE bit pattern is monotonic
  atomicMax(reinterpret_cast<unsigned int*>(addr), __float_as_uint(v));
}

static __device__ __forceinline__ float fast_exp2(float x) {
#if __has_builtin(__builtin_amdgcn_exp2f)
  return __builtin_amdgcn_exp2f(x);
#else
  return exp2f(x);
#endif
}

// async global->LDS, 16 bytes per lane. LDS dest must be wave-uniform base + lane*16.
static __device__ __forceinline__ void gl2lds16(const void* g, void* l) {
  __builtin_amdgcn_global_load_lds(
      (const __attribute__((address_space(1))) void*)g,
      (__attribute__((address_space(3))) void*)l, 16, 0, 0);
}

// ---------------------------------------------------------------------------
// absmax reduction -> atomicMax into *out (init to 0 first)
// ---------------------------------------------------------------------------
__global__ __launch_bounds__(256) void absmax_kernel(const float* __restrict__ x, long n,
                                                     float* __restrict__ out) {
  float m = 0.f;
  long stride = (long)gridDim.x * 256;
  for (long i = (long)blockIdx.x * 256 + threadIdx.x; i < n; i += stride)
    m = fmaxf(m, fabsf(x[i]));
#pragma unroll
  for (int o = 32; o; o >>= 1) m = fmaxf(m, __shfl_down(m, o, 64));
  __shared__ float sm[4];
  if (!(threadIdx.x & 63)) sm[threadIdx.x >> 6] = m;
  __syncthreads();
  if (threadIdx.x == 0) {
    m = fmaxf(fmaxf(sm[0], sm[1]), fmaxf(sm[2], sm[3]));
    atomicMaxF(out, m);
  }
}

// ---------------------------------------------------------------------------
// fake-quant elementwise -> fp32 (float4): out = clip(round(x*pre/scale))*scale
// ---------------------------------------------------------------------------
__global__ __launch_bounds__(256) void quant4_kernel(const float* __restrict__ in,
                                                     float* __restrict__ outp, long n4,
                                                     const float* __restrict__ amax_p,
                                                     float pre, float qmax, float qmin) {
  float scale = fmaxf(amax_p[0] * pre / qmax, 1e-8f);
  long stride = (long)gridDim.x * 256;
  for (long i = (long)blockIdx.x * 256 + threadIdx.x; i < n4; i += stride) {
    float4 v = ((const float4*)in)[i];
    float4 o;
    o.x = fminf(fmaxf(rintf(v.x * pre / scale), qmin), qmax) * scale;
    o.y = fminf(fmaxf(rintf(v.y * pre / scale), qmin), qmax) * scale;
    o.z = fminf(fmaxf(rintf(v.z * pre / scale), qmin), qmax) * scale;
    o.w = fminf(fmaxf(rintf(v.w * pre / scale), qmin), qmax) * scale;
    ((float4*)outp)[i] = o;
  }
}

// fake-quant elementwise -> int8 codes (scale = amax*pre/qmax)
__global__ __launch_bounds__(256) void quant8_kernel(const float* __restrict__ in,
                                                     signed char* __restrict__ out8, long n4,
                                                     const float* __restrict__ amax_p,
                                                     float pre, float qmax, float qmin) {
  float scale = fmaxf(amax_p[0] * pre / qmax, 1e-8f);
  long stride = (long)gridDim.x * 256;
  for (long i = (long)blockIdx.x * 256 + threadIdx.x; i < n4; i += stride) {
    float4 v = ((const float4*)in)[i];
    char4 o;
    o.x = (signed char)(int)fminf(fmaxf(rintf(v.x * pre / scale), qmin), qmax);
    o.y = (signed char)(int)fminf(fmaxf(rintf(v.y * pre / scale), qmin), qmax);
    o.z = (signed char)(int)fminf(fmaxf(rintf(v.z * pre / scale), qmin), qmax);
    o.w = (signed char)(int)fminf(fmaxf(rintf(v.w * pre / scale), qmin), qmax);
    ((char4*)out8)[i] = o;
  }
}

// relu + unsigned 8-bit quant -> codes stored as (c - 128) in signed i8
__global__ __launch_bounds__(256) void relu_quant8_kernel(const float* __restrict__ in,
                                                          signed char* __restrict__ out8, long n4,
                                                          const float* __restrict__ amax_p) {
  float scale = fmaxf(amax_p[0] / 255.f, 1e-8f);
  long stride = (long)gridDim.x * 256;
  for (long i = (long)blockIdx.x * 256 + threadIdx.x; i < n4; i += stride) {
    float4 v = ((const float4*)in)[i];
    char4 o;
    o.x = (signed char)((int)fminf(fmaxf(rintf(fmaxf(v.x, 0.f) / scale), 0.f), 255.f) - 128);
    o.y = (signed char)((int)fminf(fmaxf(rintf(fmaxf(v.y, 0.f) / scale), 0.f), 255.f) - 128);
    o.z = (signed char)((int)fminf(fmaxf(rintf(fmaxf(v.z, 0.f) / scale), 0.f), 255.f) - 128);
    o.w = (signed char)((int)fminf(fmaxf(rintf(fmaxf(v.w, 0.f) / scale), 0.f), 255.f) - 128);
    ((char4*)out8)[i] = o;
  }
}

// per-row sum of int8 codes (for unsigned-offset correction); one block per row
__global__ __launch_bounds__(256) void rowsum_i8_kernel(const signed char* __restrict__ w8,
                                                        int* __restrict__ out, int Kdim) {
  const int row = blockIdx.x, t = threadIdx.x;
  const signed char* p = w8 + (long)row * Kdim;
  int s = 0;
  for (int i = t * 16; i < Kdim; i += 4096) {
    int4v v = *(const int4v*)(p + i);
    const signed char* b = (const signed char*)&v;
#pragma unroll
    for (int j = 0; j < 16; j++) s += b[j];
  }
#pragma unroll
  for (int o = 32; o; o >>= 1) s += __shfl_down(s, o, 64);
  __shared__ int sm[4];
  if (!(t & 63)) sm[t >> 6] = s;
  __syncthreads();
  if (t == 0) out[row] = sm[0] + sm[1] + sm[2] + sm[3];
}

// ---------------------------------------------------------------------------
// int8 MFMA NT GEMM (exact): C[M,N] = (sum_k A8[m,k]*B8[n,k] + corr) * s_a*s_b + bias[n]
// Fused output absmax (or relu-max) -> atomicMaxF(amax_out).
// ---------------------------------------------------------------------------
__global__ __launch_bounds__(256) void gemm_i8_kernel(
    const signed char* __restrict__ A, const signed char* __restrict__ Bw,
    const float* __restrict__ biasq,
    const float* __restrict__ amax_a, float div_a,
    const float* __restrict__ amax_b,
    const int* __restrict__ rowsum,           // nullable: adds 128*rowsum[n]
    float* __restrict__ C, int M, int N, int K,
    float* __restrict__ amax_out, int relu_amax) {
  __shared__ signed char As[8192];  // 128 rows x 64 bytes, K-contiguous
  __shared__ signed char Bs[8192];
  const int t = threadIdx.x;
  const int m0 = blockIdx.y * 128, n0 = blockIdx.x * 128;
  const int w = t >> 6, lane = t & 63;
  const int fr = lane & 15, quad = lane >> 4;
  const int r0 = t >> 2;            // staging row 0..63
  const int c0 = (t & 3) * 16;      // staging byte col
  const int a_off0 = (w * 32 + fr) * 64 + quad * 16;
  const int b_off0 = fr * 64 + quad * 16;

  int4v acc[2][8];
#pragma unroll
  for (int r = 0; r < 2; r++)
#pragma unroll
    for (int c = 0; c < 8; c++) acc[r][c] = (int4v){0, 0, 0, 0};

  for (int k0 = 0; k0 < K; k0 += 64) {
    __syncthreads();
    gl2lds16(A + (long)(m0 + r0) * K + k0 + c0, As + t * 16);
    gl2lds16(A + (long)(m0 + r0 + 64) * K + k0 + c0, As + t * 16 + 4096);
    gl2lds16(Bw + (long)(n0 + r0) * K + k0 + c0, Bs + t * 16);
    gl2lds16(Bw + (long)(n0 + r0 + 64) * K + k0 + c0, Bs + t * 16 + 4096);
    __syncthreads();
    int4v af[2], bf[8];
#pragma unroll
    for (int r = 0; r < 2; r++) af[r] = *(const int4v*)(As + a_off0 + r * 1024);
#pragma unroll
    for (int c = 0; c < 8; c++) bf[c] = *(const int4v*)(Bs + b_off0 + c * 1024);
#pragma unroll
    for (int r = 0; r < 2; r++)
#pragma unroll
      for (int c = 0; c < 8; c++)
        acc[r][c] = __builtin_amdgcn_mfma_i32_16x16x64_i8(af[r], bf[c], acc[r][c], 0, 0, 0);
  }

  const float s_a = fmaxf(amax_a[0] / div_a, 1e-8f);
  const float s_b = fmaxf(amax_b[0] / 127.f, 1e-8f);
  const float s = s_a * s_b;
  float lmax = 0.f;
#pragma unroll
  for (int r = 0; r < 2; r++) {
    int rbase = m0 + w * 32 + r * 16 + quad * 4;
#pragma unroll
    for (int c = 0; c < 8; c++) {
      int col = n0 + c * 16 + fr;
      int corr = rowsum ? (rowsum[col] << 7) : 0;
      float bi = biasq[col];
#pragma unroll
      for (int g = 0; g < 4; g++) {
        float o = (float)(acc[r][c][g] + corr) * s + bi;
        lmax = fmaxf(lmax, relu_amax ? fmaxf(o, 0.f) : fabsf(o));
        C[(long)(rbase + g) * N + col] = o;
      }
    }
  }
#pragma unroll
  for (int o = 32; o; o >>= 1) lmax = fmaxf(lmax, __shfl_down(lmax, o, 64));
  __shared__ float redm[4];
  if (!lane) redm[w] = lmax;
  __syncthreads();
  if (t == 0) atomicMaxF(amax_out, fmaxf(fmaxf(redm[0], redm[1]), fmaxf(redm[2], redm[3])));
}

// ---------------------------------------------------------------------------
// Attention pass A: integer absmax of scores = q8 @ k8^T per (b,h).
// ---------------------------------------------------------------------------
__global__ __launch_bounds__(256) void attn_amax_kernel(const signed char* __restrict__ q8,
                                                        const signed char* __restrict__ k8,
                                                        int* __restrict__ imax_out) {
  const int bh = blockIdx.x, b = bh >> 4, h = bh & 15;
  const int t = threadIdx.x, w = t >> 6, lane = t & 63;
  const int fr = lane & 15, quad = lane >> 4;
  const int i0 = blockIdx.y * 64 + w * 16;
  int4v qf = *(const int4v*)(q8 + (((long)(b * TB_S + i0 + fr)) * TB_H + h) * TB_D + quad * 16);
  int im = 0;
  for (int j0 = 0; j0 < TB_S; j0 += 16) {
    int4v kf = *(const int4v*)(k8 + (((long)(b * TB_S + j0 + fr)) * TB_H + h) * TB_D + quad * 16);
    int4v sc = __builtin_amdgcn_mfma_i32_16x16x64_i8(kf, qf, (int4v){0, 0, 0, 0}, 0, 0, 0);
#pragma unroll
    for (int g = 0; g < 4; g++) {
      int a = sc[g] < 0 ? -sc[g] : sc[g];
      im = im > a ? im : a;
    }
  }
#pragma unroll
  for (int o = 32; o; o >>= 1) im = max(im, __shfl_down(im, o, 64));
  __shared__ int sm[4];
  if (!lane) sm[w] = im;
  __syncthreads();
  if (t == 0) atomicMax(imax_out, max(max(sm[0], sm[1]), max(sm[2], sm[3])));
}

// ---------------------------------------------------------------------------
// Attention pass B: integer row-max (quantization is monotonic in the int
// score), then l = sum exp2((qv - qmax)*a), a = s_sc*log2(e). No divides in
// the loops. rowm stores the max CODE (float), rowl the sum l.
// amax_attn = max(1/l).
// D[m=j][n=i]: lane holds i = i0+fr fixed, j = j0 + quad*4 + g.
// ---------------------------------------------------------------------------
__global__ __launch_bounds__(256) void attn_rowstats_kernel(
    const signed char* __restrict__ q8, const signed char* __restrict__ k8,
    const int* __restrict__ imax_p,
    const float* __restrict__ amax_q, const float* __restrict__ amax_k,
    float* __restrict__ rowm, float* __restrict__ rowl,
    float* __restrict__ amax_attn) {
  const int bh = blockIdx.x, b = bh >> 4, h = bh & 15;
  const int t = threadIdx.x, w = t >> 6, lane = t & 63;
  const int fr = lane & 15, quad = lane >> 4;
  const int i0 = blockIdx.y * 64 + w * 16;
  const float s_q = fmaxf(amax_q[0] * 0.125f / 127.f, 1e-8f);
  const float s_k = fmaxf(amax_k[0] / 127.f, 1e-8f);
  const float sqk = s_q * s_k;
  const float s_sc = fmaxf((float)imax_p[0] * sqk / 127.f, 1e-8f);
  const float c1 = sqk / s_sc;                       // int score -> code (pre-round)
  const float aa = s_sc * 1.44269504088896340736f;   // code -> log2-domain
  int4v qf = *(const int4v*)(q8 + (((long)(b * TB_S + i0 + fr)) * TB_H + h) * TB_D + quad * 16);

  // loop 1: integer row max
  int imr = -2147483647;
  for (int j0 = 0; j0 < TB_S; j0 += 16) {
    int4v kf = *(const int4v*)(k8 + (((long)(b * TB_S + j0 + fr)) * TB_H + h) * TB_D + quad * 16);
    int4v sc = __builtin_amdgcn_mfma_i32_16x16x64_i8(kf, qf, (int4v){0, 0, 0, 0}, 0, 0, 0);
    imr = max(imr, max(max(sc[0], sc[1]), max(sc[2], sc[3])));
  }
  imr = max(imr, __shfl_xor(imr, 16, 64));
  imr = max(imr, __shfl_xor(imr, 32, 64));
  const float qmax = fminf(fmaxf(rintf((float)imr * c1), -128.f), 127.f);
  const float qa = qmax * aa;

  // loop 2: l = sum exp2(qv*aa - qa)
  float l = 0.f;
  for (int j0 = 0; j0 < TB_S; j0 += 16) {
    int4v kf = *(const int4v*)(k8 + (((long)(b * TB_S + j0 + fr)) * TB_H + h) * TB_D + quad * 16);
    int4v sc = __builtin_amdgcn_mfma_i32_16x16x64_i8(kf, qf, (int4v){0, 0, 0, 0}, 0, 0, 0);
#pragma unroll
    for (int g = 0; g < 4; g++) {
      float qv = fminf(fmaxf(rintf((float)sc[g] * c1), -128.f), 127.f);
      l += fast_exp2(fmaf(qv, aa, -qa));
    }
  }
  l += __shfl_xor(l, 16, 64);
  l += __shfl_xor(l, 32, 64);
  if (quad == 0) {
    rowm[(long)bh * TB_S + i0 + fr] = qmax;   // max CODE, not value
    rowl[(long)bh * TB_S + i0 + fr] = l;
  }
  float inv = 1.f / l;                        // row max of softmax = 1/l
#pragma unroll
  for (int o = 32; o; o >>= 1) inv = fmaxf(inv, __shfl_down(inv, o, 64));
  __shared__ float smf[4];
  if (!lane) smf[w] = inv;
  __syncthreads();
  if (t == 0) atomicMaxF(amax_attn, fmaxf(fmaxf(smf[0], smf[1]), fmaxf(smf[2], smf[3])));
}

// ---------------------------------------------------------------------------
// Attention pass C: recompute scores (identical expr -> identical codes),
// attn code = rint(exp2(qv*aa - bexp) * invls) clamped; LDS transpose; PV MFMA.
// ctx fp32 in [B,S,H,D] + fused ctx absmax.
// ---------------------------------------------------------------------------
__global__ __launch_bounds__(256) void attn_pv_kernel(
    const signed char* __restrict__ q8, const signed char* __restrict__ k8,
    const signed char* __restrict__ v8t,
    const int* __restrict__ imax_p,
    const float* __restrict__ amax_q, const float* __restrict__ amax_k,
    const float* __restrict__ amax_v, const float* __restrict__ amax_attn,
    const float* __restrict__ rowm, const float* __restrict__ rowl,
    float* __restrict__ ctx, float* __restrict__ amax_ctx) {
  __shared__ signed char latt[4][16][80];  // [wave][i-rel][j-chunk], stride 80
  const int bh = blockIdx.x, b = bh >> 4, h = bh & 15;
  const int t = threadIdx.x, w = t >> 6, lane = t & 63;
  const int fr = lane & 15, quad = lane >> 4;
  const int i0 = blockIdx.y * 64 + w * 16;
  const float s_q = fmaxf(amax_q[0] * 0.125f / 127.f, 1e-8f);
  const float s_k = fmaxf(amax_k[0] / 127.f, 1e-8f);
  const float sqk = s_q * s_k;
  const float s_sc = fmaxf((float)imax_p[0] * sqk / 127.f, 1e-8f);
  const float c1 = sqk / s_sc;                       // identical to pass B
  const float aa = s_sc * 1.44269504088896340736f;   // identical to pass B
  const float s_v = fmaxf(amax_v[0] / 127.f, 1e-8f);
  const float s_at = fmaxf(amax_attn[0] / 127.f, 1e-8f);
  int4v qf = *(const int4v*)(q8 + (((long)(b * TB_S + i0 + fr)) * TB_H + h) * TB_D + quad * 16);
  const float qmaxrow = rowm[(long)bh * TB_S + i0 + fr];
  const float li = rowl[(long)bh * TB_S + i0 + fr];
  const float bexp = qmaxrow * aa;
  const float invls = 1.f / (li * s_at);             // one exact div per row
  int4v accv[4];
#pragma unroll
  for (int dtile = 0; dtile < 4; dtile++) accv[dtile] = (int4v){0, 0, 0, 0};

  for (int j0 = 0; j0 < TB_S; j0 += 64) {
#pragma unroll
    for (int tt = 0; tt < 4; tt++) {
      int4v kf = *(const int4v*)(k8 + (((long)(b * TB_S + j0 + tt * 16 + fr)) * TB_H + h) * TB_D + quad * 16);
      int4v sc = __builtin_amdgcn_mfma_i32_16x16x64_i8(kf, qf, (int4v){0, 0, 0, 0}, 0, 0, 0);
      int packed = 0;
#pragma unroll
      for (int g = 0; g < 4; g++) {
        float qv = fminf(fmaxf(rintf((float)sc[g] * c1), -128.f), 127.f);
        float e = fast_exp2(fmaf(qv, aa, -bexp));
        int code = (int)fminf(fmaxf(rintf(e * invls), -128.f), 127.f);
        packed |= (code & 255) << (g * 8);
      }
      *(int*)&latt[w][fr][tt * 16 + quad * 4] = packed;
    }
    __syncthreads();
    int4v af = *(const int4v*)&latt[w][fr][quad * 16];
#pragma unroll
    for (int dtile = 0; dtile < 4; dtile++) {
      int4v vf = *(const int4v*)(v8t + ((long)(b * TB_H + h) * TB_D + dtile * 16 + fr) * TB_S + j0 + quad * 16);
      accv[dtile] = __builtin_amdgcn_mfma_i32_16x16x64_i8(af, vf, accv[dtile], 0, 0, 0);
    }
    __syncthreads();
  }
  const float sav = s_at * s_v;
  float cmax = 0.f;
#pragma unroll
  for (int dtile = 0; dtile < 4; dtile++) {
#pragma unroll
    for (int g = 0; g < 4; g++) {
      float val = (float)accv[dtile][g] * sav;
      cmax = fmaxf(cmax, fabsf(val));
      int irow = i0 + quad * 4 + g;
      ctx[(((long)(b * TB_S + irow)) * TB_H + h) * TB_D + dtile * 16 + fr] = val;
    }
  }
#pragma unroll
  for (int o = 32; o; o >>= 1) cmax = fmaxf(cmax, __shfl_down(cmax, o, 64));
  __shared__ float smf[4];
  if (!lane) smf[w] = cmax;
  __syncthreads();
  if (t == 0) atomicMaxF(amax_ctx, fmaxf(fmaxf(smf[0], smf[1]), fmaxf(smf[2], smf[3])));
}

// ---------------------------------------------------------------------------
// v quant + transpose: fp32 [B,S,H,D] -> i8 [B,H,D,S]
// ---------------------------------------------------------------------------
__global__ __launch_bounds__(256) void quant8_vT_kernel(const float* __restrict__ v,
                                                        const float* __restrict__ amax_p,
                                                        signed char* __restrict__ v8t) {
  __shared__ signed char tile[64][80];  // [d][s], stride 80
  const int bh = blockIdx.x, b = bh >> 4, h = bh & 15;
  const int s0 = blockIdx.y * 64;
  const int t = threadIdx.x;
  const float scale = fmaxf(amax_p[0] / 127.f, 1e-8f);
#pragma unroll
  for (int it = 0; it < 4; it++) {
    int idx = t + it * 256;           // 0..1023 float4 slots
    int r = idx >> 4, c4 = (idx & 15) * 4;
    float4 vv = *(const float4*)(v + (((long)(b * TB_S + s0 + r)) * TB_H + h) * TB_D + c4);
    tile[c4 + 0][r] = (signed char)(int)fminf(fmaxf(rintf(vv.x / scale), -128.f), 127.f);
    tile[c4 + 1][r] = (signed char)(int)fminf(fmaxf(rintf(vv.y / scale), -128.f), 127.f);
    tile[c4 + 2][r] = (signed char)(int)fminf(fmaxf(rintf(vv.z / scale), -128.f), 127.f);
    tile[c4 + 3][r] = (signed char)(int)fminf(fmaxf(rintf(vv.w / scale), -128.f), 127.f);
  }
  __syncthreads();
  int d = t >> 2, sb = (t & 3) * 16;
  int4v o = *(const int4v*)&tile[d][sb];
  *(int4v*)(v8t + ((long)(b * TB_H + h) * TB_D + d) * TB_S + s0 + sb) = o;
}

// ---------------------------------------------------------------------------
// h = LayerNorm(dequant(a8) + fakequant(braw)); fused output absmax.
// ---------------------------------------------------------------------------
__global__ __launch_bounds__(256) void resid_ln_kernel(const signed char* __restrict__ a8,
                                                       const float* __restrict__ amax_a,
                                                       const float* __restrict__ braw,
                                                       const float* __restrict__ amax_b,
                                                       float* __restrict__ outp,
                                                       float* __restrict__ amax_out) {
  __shared__ float red[4];
  __shared__ float redm[4];
  const int row = blockIdx.x, t = threadIdx.x;
  const float sa = fmaxf(amax_a[0] / 127.f, 1e-8f);
  const float sb = fmaxf(amax_b[0] / 127.f, 1e-8f);
  const long base = (long)row * TB_E + t * 4;
  char4 a = ((const char4*)a8)[(long)row * 256 + t];
  float4 bv = *(const float4*)(braw + base);
  float v0 = (float)a.x * sa + fminf(fmaxf(rintf(bv.x / sb), -128.f), 127.f) * sb;
  float v1 = (float)a.y * sa + fminf(fmaxf(rintf(bv.y / sb), -128.f), 127.f) * sb;
  float v2 = (float)a.z * sa + fminf(fmaxf(rintf(bv.z / sb), -128.f), 127.f) * sb;
  float v3 = (float)a.w * sa + fminf(fmaxf(rintf(bv.w / sb), -128.f), 127.f) * sb;
  float s = v0 + v1 + v2 + v3;
#pragma unroll
  for (int o = 32; o; o >>= 1) s += __shfl_down(s, o, 64);
  if (!(t & 63)) red[t >> 6] = s;
  __syncthreads();
  float mu = ((red[0] + red[1]) + (red[2] + red[3])) * (1.f / TB_E);
  float d0 = v0 - mu, d1 = v1 - mu, d2 = v2 - mu, d3 = v3 - mu;
  float sq = d0 * d0 + d1 * d1 + d2 * d2 + d3 * d3;
#pragma unroll
  for (int o = 32; o; o >>= 1) sq += __shfl_down(sq, o, 64);
  __syncthreads();
  if (!(t & 63)) red[t >> 6] = sq;
  __syncthreads();
  float var = ((red[0] + red[1]) + (red[2] + red[3])) * (1.f / TB_E);
  float rs = 1.f / sqrtf(var + 1e-5f);
  float4 o4;
  o4.x = d0 * rs; o4.y = d1 * rs; o4.z = d2 * rs; o4.w = d3 * rs;
  *(float4*)(outp + base) = o4;
  float lm = fmaxf(fmaxf(fabsf(o4.x), fabsf(o4.y)), fmaxf(fabsf(o4.z), fabsf(o4.w)));
#pragma unroll
  for (int o = 32; o; o >>= 1) lm = fmaxf(lm, __shfl_down(lm, o, 64));
  if (!(t & 63)) redm[t >> 6] = lm;
  __syncthreads();
  if (t == 0) atomicMaxF(amax_out, fmaxf(fmaxf(redm[0], redm[1]), fmaxf(redm[2], redm[3])));
}

// ---------------------------------------------------------------------------
// Host side
// ---------------------------------------------------------------------------
#define SL_X 0
#define SL_WQ 1
#define SL_WK 2
#define SL_WV 3
#define SL_WO 4
#define SL_W1 5
#define SL_W2 6
#define SL_BQ 7
#define SL_BK 8
#define SL_BV 9
#define SL_BO 10
#define SL_B1 11
#define SL_B2 12
#define SL_Q 13
#define SL_K 14
#define SL_V 15
#define SL_SCI 16     // int imax of scores
#define SL_ATTN 17
#define SL_CTX 18
#define SL_AO 19
#define SL_H 20
#define SL_RELU 21
#define SL_M2 22
#define SL_DUMMY 23

static inline int nblocks(long n) {
  long b = (n + 255) / 256;
  return (int)(b > 2048 ? 2048 : b);
}

extern "C" void kernel_launch(void* const* d_in, const int* in_sizes, int n_in,
                              void* d_out, int out_size, void* d_ws, size_t ws_size,
                              hipStream_t stream) {
  const float* x  = (const float*)d_in[0];
  const float* Wq = (const float*)d_in[1];
  const float* bq = (const float*)d_in[2];
  const float* Wk = (const float*)d_in[3];
  const float* bk = (const float*)d_in[4];
  const float* Wv = (const float*)d_in[5];
  const float* bv = (const float*)d_in[6];
  const float* Wo = (const float*)d_in[7];
  const float* bo = (const float*)d_in[8];
  const float* W1 = (const float*)d_in[9];
  const float* b1 = (const float*)d_in[10];
  const float* W2 = (const float*)d_in[11];
  const float* b2 = (const float*)d_in[12];
  float* ws = (float*)d_ws;
  float* out = (float*)d_out;

  const long SZ_XE = (long)TB_ROWS * TB_E;      // 4,194,304
  const long SZ_W  = (long)TB_E * TB_E;         // 1,048,576
  const long SZ_M1 = (long)TB_ROWS * TB_MLP;    // 16,777,216

  // float-offset layout
  const long OFF_QBQ = 1024, OFF_QBK = 2048, OFF_QBV = 3072, OFF_QBO = 4096;
  const long OFF_QB1 = 5120, OFF_QB2 = 9216;
  const long OFF_RSUM = 10240;                  // int32[1024]
  const long OFF_Q  = 65536;                    // fp32 q, later ctx
  const long OFF_K  = OFF_Q + SZ_XE;            // fp32 k, later attn_out
  const long OFF_V  = OFF_K + SZ_XE;            // fp32 v, later h
  const long OFF_M2 = OFF_V + SZ_XE;            // fp32 m2
  const long OFF_ROWM = OFF_M2 + SZ_XE;
  const long OFF_ROWL = OFF_ROWM + 65536;
  const long OFF_M1 = OFF_ROWL + 65536;         // fp32 m1 (64MB)
  const long OFF_I8 = OFF_M1 + SZ_M1;           // i8 region start (float offset)

  float* qbuf = ws + OFF_Q;  float* kbuf = ws + OFF_K;  float* vbuf = ws + OFF_V;
  float* m2   = ws + OFF_M2;
  float* rowm = ws + OFF_ROWM; float* rowl = ws + OFF_ROWL;
  float* m1 = ws + OFF_M1;
  float* ctx = qbuf;        // reuse q (q8 codes already extracted)
  float* attn_out = kbuf;   // reuse k
  float* hbuf = vbuf;       // reuse v
  float* qbq_ = ws + OFF_QBQ; float* qbk_ = ws + OFF_QBK;
  float* qbv_ = ws + OFF_QBV; float* qbo_ = ws + OFF_QBO;
  float* qb1_ = ws + OFF_QB1; float* qb2_ = ws + OFF_QB2;
  int* rsum = (int*)(ws + OFF_RSUM);
  int* imax = (int*)(ws + SL_SCI);

  // i8 code buffers (byte pointers)
  signed char* i8base = (signed char*)(ws + OFF_I8);
  signed char* qx8  = i8base;                   // 4096x1024
  signed char* wq8  = qx8 + SZ_XE;              // 1024x1024
  signed char* wk8  = wq8 + SZ_W;
  signed char* wv8  = wk8 + SZ_W;
  signed char* wo8  = wv8 + SZ_W;
  signed char* w18  = wo8 + SZ_W;               // 4096x1024
  signed char* w28  = w18 + SZ_XE;              // 1024x4096
  signed char* ctx8 = w28 + SZ_XE;              // 4096x1024
  signed char* m08  = ctx8 + SZ_XE;             // 4096x1024
  signed char* m18  = m08 + SZ_XE;              // 4096x4096 (relu codes - 128)
  signed char* q8   = m18 + SZ_M1;              // [B,S,H,D]
  signed char* k8   = q8 + SZ_XE;               // [B,S,H,D]
  signed char* v8t  = k8 + SZ_XE;               // [B,H,D,S]

  hipMemsetAsync(ws, 0, 4096, stream);  // zero scalar slots

  // --- absmax of inputs ---
  absmax_kernel<<<nblocks(SZ_XE), 256, 0, stream>>>(x,  SZ_XE, ws + SL_X);
  absmax_kernel<<<nblocks(SZ_W),  256, 0, stream>>>(Wq, SZ_W,  ws + SL_WQ);
  absmax_kernel<<<nblocks(SZ_W),  256, 0, stream>>>(Wk, SZ_W,  ws + SL_WK);
  absmax_kernel<<<nblocks(SZ_W),  256, 0, stream>>>(Wv, SZ_W,  ws + SL_WV);
  absmax_kernel<<<nblocks(SZ_W),  256, 0, stream>>>(Wo, SZ_W,  ws + SL_WO);
  absmax_kernel<<<nblocks(SZ_XE), 256, 0, stream>>>(W1, SZ_XE, ws + SL_W1);
  absmax_kernel<<<nblocks(SZ_XE), 256, 0, stream>>>(W2, SZ_XE, ws + SL_W2);
  absmax_kernel<<<nblocks(1024), 256, 0, stream>>>(bq, 1024, ws + SL_BQ);
  absmax_kernel<<<nblocks(1024), 256, 0, stream>>>(bk, 1024, ws + SL_BK);
  absmax_kernel<<<nblocks(1024), 256, 0, stream>>>(bv, 1024, ws + SL_BV);
  absmax_kernel<<<nblocks(1024), 256, 0, stream>>>(bo, 1024, ws + SL_BO);
  absmax_kernel<<<nblocks(4096), 256, 0, stream>>>(b1, 4096, ws + SL_B1);
  absmax_kernel<<<nblocks(1024), 256, 0, stream>>>(b2, 1024, ws + SL_B2);

  // --- quantize to int8 codes (GEMM inputs); biases to fp32 ---
  quant8_kernel<<<nblocks(SZ_XE/4), 256, 0, stream>>>(x,  qx8, SZ_XE/4, ws + SL_X, 1.f, 127.f, -128.f);
  quant8_kernel<<<nblocks(SZ_W/4),  256, 0, stream>>>(Wq, wq8, SZ_W/4,  ws + SL_WQ, 1.f, 127.f, -127.f);
  quant8_kernel<<<nblocks(SZ_W/4),  256, 0, stream>>>(Wk, wk8, SZ_W/4,  ws + SL_WK, 1.f, 127.f, -127.f);
  quant8_kernel<<<nblocks(SZ_W/4),  256, 0, stream>>>(Wv, wv8, SZ_W/4,  ws + SL_WV, 1.f, 127.f, -127.f);
  quant8_kernel<<<nblocks(SZ_W/4),  256, 0, stream>>>(Wo, wo8, SZ_W/4,  ws + SL_WO, 1.f, 127.f, -127.f);
  quant8_kernel<<<nblocks(SZ_XE/4), 256, 0, stream>>>(W1, w18, SZ_XE/4, ws + SL_W1, 1.f, 127.f, -127.f);
  quant8_kernel<<<nblocks(SZ_XE/4), 256, 0, stream>>>(W2, w28, SZ_XE/4, ws + SL_W2, 1.f, 127.f, -127.f);
  rowsum_i8_kernel<<<TB_E, 256, 0, stream>>>(w28, rsum, TB_MLP);
  quant4_kernel<<<1, 256, 0, stream>>>(bq, qbq_, 256, ws + SL_BQ, 1.f, 127.f, -128.f);
  quant4_kernel<<<1, 256, 0, stream>>>(bk, qbk_, 256, ws + SL_BK, 1.f, 127.f, -128.f);
  quant4_kernel<<<1, 256, 0, stream>>>(bv, qbv_, 256, ws + SL_BV, 1.f, 127.f, -128.f);
  quant4_kernel<<<1, 256, 0, stream>>>(bo, qbo_, 256, ws + SL_BO, 1.f, 127.f, -128.f);
  quant4_kernel<<<4, 256, 0, stream>>>(b1, qb1_, 1024, ws + SL_B1, 1.f, 127.f, -128.f);
  quant4_kernel<<<1, 256, 0, stream>>>(b2, qb2_, 256, ws + SL_B2, 1.f, 127.f, -128.f);

  // --- in-projections (int8 MFMA, exact) with fused output absmax ---
  gemm_i8_kernel<<<dim3(TB_E/128, TB_ROWS/128), 256, 0, stream>>>(
      qx8, wq8, qbq_, ws + SL_X, 127.f, ws + SL_WQ, nullptr, qbuf, TB_ROWS, TB_E, TB_E, ws + SL_Q, 0);
  gemm_i8_kernel<<<dim3(TB_E/128, TB_ROWS/128), 256, 0, stream>>>(
      qx8, wk8, qbk_, ws + SL_X, 127.f, ws + SL_WK, nullptr, kbuf, TB_ROWS, TB_E, TB_E, ws + SL_K, 0);
  gemm_i8_kernel<<<dim3(TB_E/128, TB_ROWS/128), 256, 0, stream>>>(
      qx8, wv8, qbv_, ws + SL_X, 127.f, ws + SL_WV, nullptr, vbuf, TB_ROWS, TB_E, TB_E, ws + SL_V, 0);

  // --- quantize q (pre=1/8), k to i8 codes; v transposed ---
  quant8_kernel<<<nblocks(SZ_XE/4), 256, 0, stream>>>(qbuf, q8, SZ_XE/4, ws + SL_Q, 0.125f, 127.f, -128.f);
  quant8_kernel<<<nblocks(SZ_XE/4), 256, 0, stream>>>(kbuf, k8, SZ_XE/4, ws + SL_K, 1.f, 127.f, -128.f);
  quant8_vT_kernel<<<dim3(TB_B*TB_H, TB_S/64), 256, 0, stream>>>(vbuf, ws + SL_V, v8t);

  // --- attention (i8 MFMA, 3 passes) ---
  attn_amax_kernel<<<dim3(TB_B*TB_H, TB_S/64), 256, 0, stream>>>(q8, k8, imax);
  attn_rowstats_kernel<<<dim3(TB_B*TB_H, TB_S/64), 256, 0, stream>>>(
      q8, k8, imax, ws + SL_Q, ws + SL_K, rowm, rowl, ws + SL_ATTN);
  attn_pv_kernel<<<dim3(TB_B*TB_H, TB_S/64), 256, 0, stream>>>(
      q8, k8, v8t, imax, ws + SL_Q, ws + SL_K, ws + SL_V, ws + SL_ATTN,
      rowm, rowl, ctx, ws + SL_CTX);

  // --- out projection ---
  quant8_kernel<<<nblocks(SZ_XE/4), 256, 0, stream>>>(ctx, ctx8, SZ_XE/4, ws + SL_CTX, 1.f, 127.f, -128.f);
  gemm_i8_kernel<<<dim3(TB_E/128, TB_ROWS/128), 256, 0, stream>>>(
      ctx8, wo8, qbo_, ws + SL_CTX, 127.f, ws + SL_WO, nullptr, attn_out, TB_ROWS, TB_E, TB_E, ws + SL_AO, 0);

  // --- residual + LN (fused h absmax) ---
  resid_ln_kernel<<<TB_ROWS, 256, 0, stream>>>(qx8, ws + SL_X, attn_out, ws + SL_AO, hbuf, ws + SL_H);

  // --- MLP ---
  quant8_kernel<<<nblocks(SZ_XE/4), 256, 0, stream>>>(hbuf, m08, SZ_XE/4, ws + SL_H, 1.f, 127.f, -128.f);
  gemm_i8_kernel<<<dim3(TB_MLP/128, TB_ROWS/128), 256, 0, stream>>>(
      m08, w18, qb1_, ws + SL_H, 127.f, ws + SL_W1, nullptr, m1, TB_ROWS, TB_MLP, TB_E, ws + SL_RELU, 1);
  relu_quant8_kernel<<<nblocks(SZ_M1/4), 256, 0, stream>>>(m1, m18, SZ_M1/4, ws + SL_RELU);
  gemm_i8_kernel<<<dim3(TB_E/128, TB_ROWS/128), 256, 0, stream>>>(
      m18, w28, qb2_, ws + SL_RELU, 255.f, ws + SL_W2, rsum, m2, TB_ROWS, TB_E, TB_MLP, ws + SL_M2, 0);

  // --- final residual + LN ---
  resid_ln_kernel<<<TB_ROWS, 256, 0, stream>>>(m08, ws + SL_H, m2, ws + SL_M2, out, ws + SL_DUMMY);
}

// Round 5
// 579.977 us; speedup vs baseline: 4.9316x; 1.4466x over previous
//
#include <hip/hip_runtime.h>
#include <cstdint>
#include <cstddef>

// Problem constants
#define TB_B 4
#define TB_S 1024
#define TB_E 1024
#define TB_H 16
#define TB_D 64
#define TB_MLP 4096
#define TB_ROWS (TB_B * TB_S)   // 4096

typedef int int4v __attribute__((ext_vector_type(4)));

#define LGKM0() __asm__ volatile("s_waitcnt lgkmcnt(0)" ::: "memory")
#define CMEMBAR() __asm__ volatile("" ::: "memory")

static __device__ __forceinline__ void atomicMaxF(float* addr, float v) {
  // valid for non-negative floats: IEEE bit pattern is monotonic
  atomicMax(reinterpret_cast<unsigned int*>(addr), __float_as_uint(v));
}

static __device__ __forceinline__ float fast_exp2(float x) {
#if __has_builtin(__builtin_amdgcn_exp2f)
  return __builtin_amdgcn_exp2f(x);
#else
  return exp2f(x);
#endif
}

// async global->LDS, 16 bytes per lane. LDS dest must be wave-uniform base + lane*16.
static __device__ __forceinline__ void gl2lds16(const void* g, void* l) {
  __builtin_amdgcn_global_load_lds(
      (const __attribute__((address_space(1))) void*)g,
      (__attribute__((address_space(3))) void*)l, 16, 0, 0);
}

// ---------------------------------------------------------------------------
// multi-tensor absmax: one dispatch for all 13 input tensors
// ---------------------------------------------------------------------------
struct AMDesc { const float* p; long n4; int slot; };
struct AMBatch { AMDesc d[13]; };
__global__ __launch_bounds__(256) void absmax_multi_kernel(AMBatch bt, float* ws) {
  AMDesc d = bt.d[blockIdx.y];
  float m = 0.f;
  long stride = (long)gridDim.x * 256;
  for (long i = (long)blockIdx.x * 256 + threadIdx.x; i < d.n4; i += stride) {
    float4 v = ((const float4*)d.p)[i];
    m = fmaxf(m, fmaxf(fmaxf(fabsf(v.x), fabsf(v.y)), fmaxf(fabsf(v.z), fabsf(v.w))));
  }
#pragma unroll
  for (int o = 32; o; o >>= 1) m = fmaxf(m, __shfl_down(m, o, 64));
  __shared__ float sm[4];
  if (!(threadIdx.x & 63)) sm[threadIdx.x >> 6] = m;
  __syncthreads();
  if (threadIdx.x == 0)
    atomicMaxF(ws + d.slot, fmaxf(fmaxf(sm[0], sm[1]), fmaxf(sm[2], sm[3])));
}

// multi-tensor fake-quant -> i8 codes (x + 6 weights)
struct QMDesc { const float* in; signed char* out; long n4; int slot; float qmin; };
struct QMBatch { QMDesc d[7]; };
__global__ __launch_bounds__(256) void quant8_multi_kernel(QMBatch bt, const float* ws) {
  QMDesc d = bt.d[blockIdx.y];
  float scale = fmaxf(ws[d.slot] / 127.f, 1e-8f);
  long stride = (long)gridDim.x * 256;
  for (long i = (long)blockIdx.x * 256 + threadIdx.x; i < d.n4; i += stride) {
    float4 v = ((const float4*)d.in)[i];
    char4 o;
    o.x = (signed char)(int)fminf(fmaxf(rintf(v.x / scale), d.qmin), 127.f);
    o.y = (signed char)(int)fminf(fmaxf(rintf(v.y / scale), d.qmin), 127.f);
    o.z = (signed char)(int)fminf(fmaxf(rintf(v.z / scale), d.qmin), 127.f);
    o.w = (signed char)(int)fminf(fmaxf(rintf(v.w / scale), d.qmin), 127.f);
    ((char4*)d.out)[i] = o;
  }
}

// multi-tensor bias fake-quant -> fp32
struct BDesc { const float* in; float* out; int n4; int slot; };
struct BBatch { BDesc d[6]; };
__global__ __launch_bounds__(256) void bias_quant_multi_kernel(BBatch bt, const float* ws) {
  BDesc d = bt.d[blockIdx.y];
  float scale = fmaxf(ws[d.slot] / 127.f, 1e-8f);
  int i = blockIdx.x * 256 + threadIdx.x;
  if (i < d.n4) {
    float4 v = ((const float4*)d.in)[i];
    float4 o;
    o.x = fminf(fmaxf(rintf(v.x / scale), -128.f), 127.f) * scale;
    o.y = fminf(fmaxf(rintf(v.y / scale), -128.f), 127.f) * scale;
    o.z = fminf(fmaxf(rintf(v.z / scale), -128.f), 127.f) * scale;
    o.w = fminf(fmaxf(rintf(v.w / scale), -128.f), 127.f) * scale;
    ((float4*)d.out)[i] = o;
  }
}

// generic fake-quant -> i8 (same layout), used for ctx and h
__global__ __launch_bounds__(256) void quant8_kernel(const float* __restrict__ in,
                                                     signed char* __restrict__ out8, long n4,
                                                     const float* __restrict__ amax_p,
                                                     float pre, float qmin) {
  float scale = fmaxf(amax_p[0] * pre / 127.f, 1e-8f);
  long stride = (long)gridDim.x * 256;
  for (long i = (long)blockIdx.x * 256 + threadIdx.x; i < n4; i += stride) {
    float4 v = ((const float4*)in)[i];
    char4 o;
    o.x = (signed char)(int)fminf(fmaxf(rintf(v.x * pre / scale), qmin), 127.f);
    o.y = (signed char)(int)fminf(fmaxf(rintf(v.y * pre / scale), qmin), 127.f);
    o.z = (signed char)(int)fminf(fmaxf(rintf(v.z * pre / scale), qmin), 127.f);
    o.w = (signed char)(int)fminf(fmaxf(rintf(v.w * pre / scale), qmin), 127.f);
    ((char4*)out8)[i] = o;
  }
}

// relu + unsigned 8-bit quant -> codes stored as (c - 128) in signed i8
__global__ __launch_bounds__(256) void relu_quant8_kernel(const float* __restrict__ in,
                                                          signed char* __restrict__ out8, long n4,
                                                          const float* __restrict__ amax_p) {
  float scale = fmaxf(amax_p[0] / 255.f, 1e-8f);
  long stride = (long)gridDim.x * 256;
  for (long i = (long)blockIdx.x * 256 + threadIdx.x; i < n4; i += stride) {
    float4 v = ((const float4*)in)[i];
    char4 o;
    o.x = (signed char)((int)fminf(fmaxf(rintf(fmaxf(v.x, 0.f) / scale), 0.f), 255.f) - 128);
    o.y = (signed char)((int)fminf(fmaxf(rintf(fmaxf(v.y, 0.f) / scale), 0.f), 255.f) - 128);
    o.z = (signed char)((int)fminf(fmaxf(rintf(fmaxf(v.z, 0.f) / scale), 0.f), 255.f) - 128);
    o.w = (signed char)((int)fminf(fmaxf(rintf(fmaxf(v.w, 0.f) / scale), 0.f), 255.f) - 128);
    ((char4*)out8)[i] = o;
  }
}

// per-row sum of int8 codes (for unsigned-offset correction); one block per row
__global__ __launch_bounds__(256) void rowsum_i8_kernel(const signed char* __restrict__ w8,
                                                        int* __restrict__ out, int Kdim) {
  const int row = blockIdx.x, t = threadIdx.x;
  const signed char* p = w8 + (long)row * Kdim;
  int s = 0;
  for (int i = t * 16; i < Kdim; i += 4096) {
    int4v v = *(const int4v*)(p + i);
    const signed char* b = (const signed char*)&v;
#pragma unroll
    for (int j = 0; j < 16; j++) s += b[j];
  }
#pragma unroll
  for (int o = 32; o; o >>= 1) s += __shfl_down(s, o, 64);
  __shared__ int sm[4];
  if (!(t & 63)) sm[t >> 6] = s;
  __syncthreads();
  if (t == 0) out[row] = sm[0] + sm[1] + sm[2] + sm[3];
}

// ---------------------------------------------------------------------------
// int8 MFMA NT GEMM (exact): C[M,N] = (sum_k A8[m,k]*B8[n,k] + corr) * s_a*s_b + bias[n]
// Fused output absmax (or relu-max) -> atomicMaxF(amax_out).
// ---------------------------------------------------------------------------
__global__ __launch_bounds__(256) void gemm_i8_kernel(
    const signed char* __restrict__ A, const signed char* __restrict__ Bw,
    const float* __restrict__ biasq,
    const float* __restrict__ amax_a, float div_a,
    const float* __restrict__ amax_b,
    const int* __restrict__ rowsum,           // nullable: adds 128*rowsum[n]
    float* __restrict__ C, int M, int N, int K,
    float* __restrict__ amax_out, int relu_amax) {
  __shared__ signed char As[8192];  // 128 rows x 64 bytes, K-contiguous
  __shared__ signed char Bs[8192];
  const int t = threadIdx.x;
  const int m0 = blockIdx.y * 128, n0 = blockIdx.x * 128;
  const int w = t >> 6, lane = t & 63;
  const int fr = lane & 15, quad = lane >> 4;
  const int r0 = t >> 2;            // staging row 0..63
  const int c0 = (t & 3) * 16;      // staging byte col
  const int a_off0 = (w * 32 + fr) * 64 + quad * 16;
  const int b_off0 = fr * 64 + quad * 16;

  int4v acc[2][8];
#pragma unroll
  for (int r = 0; r < 2; r++)
#pragma unroll
    for (int c = 0; c < 8; c++) acc[r][c] = (int4v){0, 0, 0, 0};

  for (int k0 = 0; k0 < K; k0 += 64) {
    __syncthreads();
    gl2lds16(A + (long)(m0 + r0) * K + k0 + c0, As + t * 16);
    gl2lds16(A + (long)(m0 + r0 + 64) * K + k0 + c0, As + t * 16 + 4096);
    gl2lds16(Bw + (long)(n0 + r0) * K + k0 + c0, Bs + t * 16);
    gl2lds16(Bw + (long)(n0 + r0 + 64) * K + k0 + c0, Bs + t * 16 + 4096);
    __syncthreads();
    int4v af[2], bf[8];
#pragma unroll
    for (int r = 0; r < 2; r++) af[r] = *(const int4v*)(As + a_off0 + r * 1024);
#pragma unroll
    for (int c = 0; c < 8; c++) bf[c] = *(const int4v*)(Bs + b_off0 + c * 1024);
#pragma unroll
    for (int r = 0; r < 2; r++)
#pragma unroll
      for (int c = 0; c < 8; c++)
        acc[r][c] = __builtin_amdgcn_mfma_i32_16x16x64_i8(af[r], bf[c], acc[r][c], 0, 0, 0);
  }

  const float s_a = fmaxf(amax_a[0] / div_a, 1e-8f);
  const float s_b = fmaxf(amax_b[0] / 127.f, 1e-8f);
  const float s = s_a * s_b;
  float lmax = 0.f;
#pragma unroll
  for (int r = 0; r < 2; r++) {
    int rbase = m0 + w * 32 + r * 16 + quad * 4;
#pragma unroll
    for (int c = 0; c < 8; c++) {
      int col = n0 + c * 16 + fr;
      int corr = rowsum ? (rowsum[col] << 7) : 0;
      float bi = biasq[col];
#pragma unroll
      for (int g = 0; g < 4; g++) {
        float o = (float)(acc[r][c][g] + corr) * s + bi;
        lmax = fmaxf(lmax, relu_amax ? fmaxf(o, 0.f) : fabsf(o));
        C[(long)(rbase + g) * N + col] = o;
      }
    }
  }
#pragma unroll
  for (int o = 32; o; o >>= 1) lmax = fmaxf(lmax, __shfl_down(lmax, o, 64));
  __shared__ float redm[4];
  if (!lane) redm[w] = lmax;
  __syncthreads();
  if (t == 0) atomicMaxF(amax_out, fmaxf(fmaxf(redm[0], redm[1]), fmaxf(redm[2], redm[3])));
}

// ---------------------------------------------------------------------------
// q/k quant + permute: fp32 [B,S,H*D] -> i8 [B,H,S,D]  (coalesced attn loads)
// ---------------------------------------------------------------------------
__global__ __launch_bounds__(256) void quant8_qk_kernel(const float* __restrict__ in,
                                                        signed char* __restrict__ out8,
                                                        const float* __restrict__ amax_p,
                                                        float pre) {
  const float scale = fmaxf(amax_p[0] * pre / 127.f, 1e-8f);
  const long n4 = (long)TB_ROWS * TB_E / 16;   // 16-byte units: 1M
  long stride = (long)gridDim.x * 256;
  for (long o4 = (long)blockIdx.x * 256 + threadIdx.x; o4 < n4; o4 += stride) {
    int dq = (int)(o4 & 3);
    int s  = (int)((o4 >> 2) & 1023);
    int bh = (int)(o4 >> 12);
    int b = bh >> 4, h = bh & 15;
    const float* src = in + ((long)(b * TB_S + s)) * TB_E + h * 64 + dq * 16;
    char4 oc[4];
#pragma unroll
    for (int j = 0; j < 4; j++) {
      float4 v = *(const float4*)(src + j * 4);
      oc[j].x = (signed char)(int)fminf(fmaxf(rintf(v.x * pre / scale), -128.f), 127.f);
      oc[j].y = (signed char)(int)fminf(fmaxf(rintf(v.y * pre / scale), -128.f), 127.f);
      oc[j].z = (signed char)(int)fminf(fmaxf(rintf(v.z * pre / scale), -128.f), 127.f);
      oc[j].w = (signed char)(int)fminf(fmaxf(rintf(v.w * pre / scale), -128.f), 127.f);
    }
    *(int4v*)(out8 + o4 * 16) = *(int4v*)oc;
  }
}

// ---------------------------------------------------------------------------
// v quant + transpose: fp32 [B,S,H,D] -> i8 blocked [BH][jb][D][64]
// ---------------------------------------------------------------------------
__global__ __launch_bounds__(256) void quant8_vb_kernel(const float* __restrict__ v,
                                                        const float* __restrict__ amax_p,
                                                        signed char* __restrict__ v8b) {
  __shared__ signed char tile[64][80];  // [d][s], stride 80
  const int bh = blockIdx.x, b = bh >> 4, h = bh & 15;
  const int jb = blockIdx.y;
  const int s0 = jb * 64;
  const int t = threadIdx.x;
  const float scale = fmaxf(amax_p[0] / 127.f, 1e-8f);
#pragma unroll
  for (int it = 0; it < 4; it++) {
    int idx = t + it * 256;           // 0..1023 float4 slots
    int r = idx >> 4, c4 = (idx & 15) * 4;
    float4 vv = *(const float4*)(v + (((long)(b * TB_S + s0 + r)) * TB_H + h) * TB_D + c4);
    tile[c4 + 0][r] = (signed char)(int)fminf(fmaxf(rintf(vv.x / scale), -128.f), 127.f);
    tile[c4 + 1][r] = (signed char)(int)fminf(fmaxf(rintf(vv.y / scale), -128.f), 127.f);
    tile[c4 + 2][r] = (signed char)(int)fminf(fmaxf(rintf(vv.z / scale), -128.f), 127.f);
    tile[c4 + 3][r] = (signed char)(int)fminf(fmaxf(rintf(vv.w / scale), -128.f), 127.f);
  }
  __syncthreads();
  int d = t >> 2, sb = (t & 3) * 16;
  int4v o = *(const int4v*)&tile[d][sb];
  *(int4v*)(v8b + (((long)bh * 16 + jb) * 64 + d) * 64 + sb) = o;
}

// ---------------------------------------------------------------------------
// Attention pass A: per-row signed int max of scores -> irowmax; global int
// absmax -> imax_out. q8/k8 in [B,H,S,D]; wave loads are 1KB contiguous.
// D[m=j][n=i]: lane (fr,quad) holds i = i0+fr, j = j0 + quad*4 + g.
// ---------------------------------------------------------------------------
__global__ __launch_bounds__(256) void attn_rowmax_kernel(const signed char* __restrict__ q8,
                                                          const signed char* __restrict__ k8,
                                                          int* __restrict__ irowmax,
                                                          int* __restrict__ imax_out) {
  const int bh = blockIdx.x;
  const int t = threadIdx.x, w = t >> 6, lane = t & 63;
  const int fr = lane & 15, quad = lane >> 4;
  const int i0 = blockIdx.y * 64 + w * 16;
  const long base = (long)bh * TB_S;
  int4v qf = *(const int4v*)(q8 + (base + i0 + fr) * 64 + quad * 16);
  int mx = -2147483647, mn = 2147483647;
  for (int j0 = 0; j0 < TB_S; j0 += 16) {
    int4v kf = *(const int4v*)(k8 + (base + j0 + fr) * 64 + quad * 16);
    int4v sc = __builtin_amdgcn_mfma_i32_16x16x64_i8(kf, qf, (int4v){0, 0, 0, 0}, 0, 0, 0);
    mx = max(mx, max(max(sc[0], sc[1]), max(sc[2], sc[3])));
    mn = min(mn, min(min(sc[0], sc[1]), min(sc[2], sc[3])));
  }
  mx = max(mx, __shfl_xor(mx, 16, 64));
  mx = max(mx, __shfl_xor(mx, 32, 64));
  mn = min(mn, __shfl_xor(mn, 16, 64));
  mn = min(mn, __shfl_xor(mn, 32, 64));
  if (quad == 0) irowmax[(long)bh * TB_S + i0 + fr] = mx;
  int gm = max(mx, -mn);
#pragma unroll
  for (int o = 32; o; o >>= 1) gm = max(gm, __shfl_down(gm, o, 64));
  __shared__ int sm[4];
  if (!lane) sm[w] = gm;
  __syncthreads();
  if (t == 0) atomicMax(imax_out, max(max(sm[0], sm[1]), max(sm[2], sm[3])));
}

// ---------------------------------------------------------------------------
// Attention pass B: l = sum exp2((qv - qmax)*aa) per row (single loop; row max
// code derived from irowmax). rowl <- l; amax_attn <- max(1/l).
// ---------------------------------------------------------------------------
__global__ __launch_bounds__(256) void attn_rowsum_kernel(
    const signed char* __restrict__ q8, const signed char* __restrict__ k8,
    const int* __restrict__ irowmax, const int* __restrict__ imax_p,
    const float* __restrict__ amax_q, const float* __restrict__ amax_k,
    float* __restrict__ rowl, float* __restrict__ amax_attn) {
  const int bh = blockIdx.x;
  const int t = threadIdx.x, w = t >> 6, lane = t & 63;
  const int fr = lane & 15, quad = lane >> 4;
  const int i0 = blockIdx.y * 64 + w * 16;
  const float s_q = fmaxf(amax_q[0] * 0.125f / 127.f, 1e-8f);
  const float s_k = fmaxf(amax_k[0] / 127.f, 1e-8f);
  const float sqk = s_q * s_k;
  const float s_sc = fmaxf((float)imax_p[0] * sqk / 127.f, 1e-8f);
  const float c1 = sqk / s_sc;
  const float aa = s_sc * 1.44269504088896340736f;
  const long base = (long)bh * TB_S;
  int4v qf = *(const int4v*)(q8 + (base + i0 + fr) * 64 + quad * 16);
  const int imr = irowmax[base + i0 + fr];
  const float qmax = fminf(fmaxf(rintf((float)imr * c1), -128.f), 127.f);
  const float qa = qmax * aa;
  float l = 0.f;
  for (int j0 = 0; j0 < TB_S; j0 += 16) {
    int4v kf = *(const int4v*)(k8 + (base + j0 + fr) * 64 + quad * 16);
    int4v sc = __builtin_amdgcn_mfma_i32_16x16x64_i8(kf, qf, (int4v){0, 0, 0, 0}, 0, 0, 0);
#pragma unroll
    for (int g = 0; g < 4; g++) {
      float qv = fminf(fmaxf(rintf((float)sc[g] * c1), -128.f), 127.f);
      l += fast_exp2(fmaf(qv, aa, -qa));
    }
  }
  l += __shfl_xor(l, 16, 64);
  l += __shfl_xor(l, 32, 64);
  if (quad == 0) rowl[base + i0 + fr] = l;
  float inv = 1.f / l;                        // row max of softmax = 1/l
#pragma unroll
  for (int o = 32; o; o >>= 1) inv = fmaxf(inv, __shfl_down(inv, o, 64));
  __shared__ float smf[4];
  if (!lane) smf[w] = inv;
  __syncthreads();
  if (t == 0) atomicMaxF(amax_attn, fmaxf(fmaxf(smf[0], smf[1]), fmaxf(smf[2], smf[3])));
}

// ---------------------------------------------------------------------------
// Attention pass C: recompute scores (identical expr -> identical codes),
// attn code = rint(exp2(qv*aa - bexp) * invls); per-wave LDS transpose (NO
// block barriers - latt[w] is wave-private, lgkmcnt(0) suffices); PV MFMA on
// blocked v8b (coalesced). ctx fp32 [B,S,H,D] + fused absmax.
// ---------------------------------------------------------------------------
__global__ __launch_bounds__(256) void attn_pv_kernel(
    const signed char* __restrict__ q8, const signed char* __restrict__ k8,
    const signed char* __restrict__ v8b,
    const int* __restrict__ irowmax, const int* __restrict__ imax_p,
    const float* __restrict__ amax_q, const float* __restrict__ amax_k,
    const float* __restrict__ amax_v, const float* __restrict__ amax_attn,
    const float* __restrict__ rowl,
    float* __restrict__ ctx, float* __restrict__ amax_ctx) {
  __shared__ signed char latt[4][16][80];  // [wave][i-rel][j-byte], stride 80
  const int bh = blockIdx.x, b = bh >> 4, h = bh & 15;
  const int t = threadIdx.x, w = t >> 6, lane = t & 63;
  const int fr = lane & 15, quad = lane >> 4;
  const int i0 = blockIdx.y * 64 + w * 16;
  const float s_q = fmaxf(amax_q[0] * 0.125f / 127.f, 1e-8f);
  const float s_k = fmaxf(amax_k[0] / 127.f, 1e-8f);
  const float sqk = s_q * s_k;
  const float s_sc = fmaxf((float)imax_p[0] * sqk / 127.f, 1e-8f);
  const float c1 = sqk / s_sc;                       // identical to pass B
  const float aa = s_sc * 1.44269504088896340736f;   // identical to pass B
  const float s_v = fmaxf(amax_v[0] / 127.f, 1e-8f);
  const float s_at = fmaxf(amax_attn[0] / 127.f, 1e-8f);
  const long base = (long)bh * TB_S;
  int4v qf = *(const int4v*)(q8 + (base + i0 + fr) * 64 + quad * 16);
  const int imr = irowmax[base + i0 + fr];
  const float qmax = fminf(fmaxf(rintf((float)imr * c1), -128.f), 127.f);
  const float bexp = qmax * aa;
  const float li = rowl[base + i0 + fr];
  const float invls = 1.f / (li * s_at);             // one exact div per row
  int4v accv[4];
#pragma unroll
  for (int dtile = 0; dtile < 4; dtile++) accv[dtile] = (int4v){0, 0, 0, 0};

  for (int j0 = 0; j0 < TB_S; j0 += 64) {
#pragma unroll
    for (int tt = 0; tt < 4; tt++) {
      int4v kf = *(const int4v*)(k8 + (base + j0 + tt * 16 + fr) * 64 + quad * 16);
      int4v sc = __builtin_amdgcn_mfma_i32_16x16x64_i8(kf, qf, (int4v){0, 0, 0, 0}, 0, 0, 0);
      int packed = 0;
#pragma unroll
      for (int g = 0; g < 4; g++) {
        float qv = fminf(fmaxf(rintf((float)sc[g] * c1), -128.f), 127.f);
        float e = fast_exp2(fmaf(qv, aa, -bexp));
        int code = (int)fminf(fmaxf(rintf(e * invls), -128.f), 127.f);
        packed |= (code & 255) << (g * 8);
      }
      *(int*)&latt[w][fr][tt * 16 + quad * 4] = packed;
    }
    LGKM0();   // wave-private LDS: ds in-order per wave, no block barrier needed
    int4v af = *(const int4v*)&latt[w][fr][quad * 16];
    const signed char* vbase = v8b + (((long)bh * 16 + (j0 >> 6)) * 64) * 64;
#pragma unroll
    for (int dtile = 0; dtile < 4; dtile++) {
      int4v vf = *(const int4v*)(vbase + (dtile * 16 + fr) * 64 + quad * 16);
      accv[dtile] = __builtin_amdgcn_mfma_i32_16x16x64_i8(af, vf, accv[dtile], 0, 0, 0);
    }
    CMEMBAR(); // keep next iteration's ds_writes after this read (in-order DS)
  }
  const float sav = s_at * s_v;
  float cmax = 0.f;
#pragma unroll
  for (int dtile = 0; dtile < 4; dtile++) {
#pragma unroll
    for (int g = 0; g < 4; g++) {
      float val = (float)accv[dtile][g] * sav;
      cmax = fmaxf(cmax, fabsf(val));
      int irow = i0 + quad * 4 + g;
      ctx[(((long)(b * TB_S + irow)) * TB_H + h) * TB_D + dtile * 16 + fr] = val;
    }
  }
#pragma unroll
  for (int o = 32; o; o >>= 1) cmax = fmaxf(cmax, __shfl_down(cmax, o, 64));
  __shared__ float smf[4];
  if (!lane) smf[w] = cmax;
  __syncthreads();
  if (t == 0) atomicMaxF(amax_ctx, fmaxf(fmaxf(smf[0], smf[1]), fmaxf(smf[2], smf[3])));
}

// ---------------------------------------------------------------------------
// h = LayerNorm(dequant(a8) + fakequant(braw)); fused output absmax.
// ---------------------------------------------------------------------------
__global__ __launch_bounds__(256) void resid_ln_kernel(const signed char* __restrict__ a8,
                                                       const float* __restrict__ amax_a,
                                                       const float* __restrict__ braw,
                                                       const float* __restrict__ amax_b,
                                                       float* __restrict__ outp,
                                                       float* __restrict__ amax_out) {
  __shared__ float red[4];
  __shared__ float redm[4];
  const int row = blockIdx.x, t = threadIdx.x;
  const float sa = fmaxf(amax_a[0] / 127.f, 1e-8f);
  const float sb = fmaxf(amax_b[0] / 127.f, 1e-8f);
  const long base = (long)row * TB_E + t * 4;
  char4 a = ((const char4*)a8)[(long)row * 256 + t];
  float4 bv = *(const float4*)(braw + base);
  float v0 = (float)a.x * sa + fminf(fmaxf(rintf(bv.x / sb), -128.f), 127.f) * sb;
  float v1 = (float)a.y * sa + fminf(fmaxf(rintf(bv.y / sb), -128.f), 127.f) * sb;
  float v2 = (float)a.z * sa + fminf(fmaxf(rintf(bv.z / sb), -128.f), 127.f) * sb;
  float v3 = (float)a.w * sa + fminf(fmaxf(rintf(bv.w / sb), -128.f), 127.f) * sb;
  float s = v0 + v1 + v2 + v3;
#pragma unroll
  for (int o = 32; o; o >>= 1) s += __shfl_down(s, o, 64);
  if (!(t & 63)) red[t >> 6] = s;
  __syncthreads();
  float mu = ((red[0] + red[1]) + (red[2] + red[3])) * (1.f / TB_E);
  float d0 = v0 - mu, d1 = v1 - mu, d2 = v2 - mu, d3 = v3 - mu;
  float sq = d0 * d0 + d1 * d1 + d2 * d2 + d3 * d3;
#pragma unroll
  for (int o = 32; o; o >>= 1) sq += __shfl_down(sq, o, 64);
  __syncthreads();
  if (!(t & 63)) red[t >> 6] = sq;
  __syncthreads();
  float var = ((red[0] + red[1]) + (red[2] + red[3])) * (1.f / TB_E);
  float rs = 1.f / sqrtf(var + 1e-5f);
  float4 o4;
  o4.x = d0 * rs; o4.y = d1 * rs; o4.z = d2 * rs; o4.w = d3 * rs;
  *(float4*)(outp + base) = o4;
  float lm = fmaxf(fmaxf(fabsf(o4.x), fabsf(o4.y)), fmaxf(fabsf(o4.z), fabsf(o4.w)));
#pragma unroll
  for (int o = 32; o; o >>= 1) lm = fmaxf(lm, __shfl_down(lm, o, 64));
  if (!(t & 63)) redm[t >> 6] = lm;
  __syncthreads();
  if (t == 0) atomicMaxF(amax_out, fmaxf(fmaxf(redm[0], redm[1]), fmaxf(redm[2], redm[3])));
}

// ---------------------------------------------------------------------------
// Host side
// ---------------------------------------------------------------------------
#define SL_X 0
#define SL_WQ 1
#define SL_WK 2
#define SL_WV 3
#define SL_WO 4
#define SL_W1 5
#define SL_W2 6
#define SL_BQ 7
#define SL_BK 8
#define SL_BV 9
#define SL_BO 10
#define SL_B1 11
#define SL_B2 12
#define SL_Q 13
#define SL_K 14
#define SL_V 15
#define SL_SCI 16     // int imax of scores
#define SL_ATTN 17
#define SL_CTX 18
#define SL_AO 19
#define SL_H 20
#define SL_RELU 21
#define SL_M2 22
#define SL_DUMMY 23

static inline int nblocks(long n) {
  long b = (n + 255) / 256;
  return (int)(b > 2048 ? 2048 : b);
}

extern "C" void kernel_launch(void* const* d_in, const int* in_sizes, int n_in,
                              void* d_out, int out_size, void* d_ws, size_t ws_size,
                              hipStream_t stream) {
  const float* x  = (const float*)d_in[0];
  const float* Wq = (const float*)d_in[1];
  const float* bq = (const float*)d_in[2];
  const float* Wk = (const float*)d_in[3];
  const float* bk = (const float*)d_in[4];
  const float* Wv = (const float*)d_in[5];
  const float* bv = (const float*)d_in[6];
  const float* Wo = (const float*)d_in[7];
  const float* bo = (const float*)d_in[8];
  const float* W1 = (const float*)d_in[9];
  const float* b1 = (const float*)d_in[10];
  const float* W2 = (const float*)d_in[11];
  const float* b2 = (const float*)d_in[12];
  float* ws = (float*)d_ws;
  float* out = (float*)d_out;

  const long SZ_XE = (long)TB_ROWS * TB_E;      // 4,194,304
  const long SZ_W  = (long)TB_E * TB_E;         // 1,048,576
  const long SZ_M1 = (long)TB_ROWS * TB_MLP;    // 16,777,216

  // float-offset layout
  const long OFF_QBQ = 1024, OFF_QBK = 2048, OFF_QBV = 3072, OFF_QBO = 4096;
  const long OFF_QB1 = 5120, OFF_QB2 = 9216;
  const long OFF_RSUM = 10240;                  // int32[1024]
  const long OFF_Q  = 65536;                    // fp32 q, later ctx
  const long OFF_K  = OFF_Q + SZ_XE;            // fp32 k, later attn_out
  const long OFF_V  = OFF_K + SZ_XE;            // fp32 v, later h
  const long OFF_M2 = OFF_V + SZ_XE;            // fp32 m2
  const long OFF_IRM = OFF_M2 + SZ_XE;          // int irowmax [65536]
  const long OFF_ROWL = OFF_IRM + 65536;
  const long OFF_M1 = OFF_ROWL + 65536;         // fp32 m1 (64MB)
  const long OFF_I8 = OFF_M1 + SZ_M1;           // i8 region start (float offset)

  float* qbuf = ws + OFF_Q;  float* kbuf = ws + OFF_K;  float* vbuf = ws + OFF_V;
  float* m2   = ws + OFF_M2;
  int*   irowmax = (int*)(ws + OFF_IRM);
  float* rowl = ws + OFF_ROWL;
  float* m1 = ws + OFF_M1;
  float* ctx = qbuf;        // reuse q (q8 codes already extracted)
  float* attn_out = kbuf;   // reuse k
  float* hbuf = vbuf;       // reuse v
  float* qbq_ = ws + OFF_QBQ; float* qbk_ = ws + OFF_QBK;
  float* qbv_ = ws + OFF_QBV; float* qbo_ = ws + OFF_QBO;
  float* qb1_ = ws + OFF_QB1; float* qb2_ = ws + OFF_QB2;
  int* rsum = (int*)(ws + OFF_RSUM);
  int* imax = (int*)(ws + SL_SCI);

  // i8 code buffers (byte pointers)
  signed char* i8base = (signed char*)(ws + OFF_I8);
  signed char* qx8  = i8base;                   // 4096x1024 [rows,E]
  signed char* wq8  = qx8 + SZ_XE;              // 1024x1024
  signed char* wk8  = wq8 + SZ_W;
  signed char* wv8  = wk8 + SZ_W;
  signed char* wo8  = wv8 + SZ_W;
  signed char* w18  = wo8 + SZ_W;               // 4096x1024
  signed char* w28  = w18 + SZ_XE;              // 1024x4096
  signed char* ctx8 = w28 + SZ_XE;              // 4096x1024
  signed char* m08  = ctx8 + SZ_XE;             // 4096x1024
  signed char* m18  = m08 + SZ_XE;              // 4096x4096 (relu codes - 128)
  signed char* q8   = m18 + SZ_M1;              // [B,H,S,D]
  signed char* k8   = q8 + SZ_XE;               // [B,H,S,D]
  signed char* v8b  = k8 + SZ_XE;               // [BH][16][64][64]

  hipMemsetAsync(ws, 0, 4096, stream);  // zero scalar slots

  // --- absmax of all 13 inputs (1 dispatch) ---
  AMBatch am;
  am.d[0]  = {x,  SZ_XE/4, SL_X};
  am.d[1]  = {Wq, SZ_W/4,  SL_WQ};
  am.d[2]  = {Wk, SZ_W/4,  SL_WK};
  am.d[3]  = {Wv, SZ_W/4,  SL_WV};
  am.d[4]  = {Wo, SZ_W/4,  SL_WO};
  am.d[5]  = {W1, SZ_XE/4, SL_W1};
  am.d[6]  = {W2, SZ_XE/4, SL_W2};
  am.d[7]  = {bq, 256,     SL_BQ};
  am.d[8]  = {bk, 256,     SL_BK};
  am.d[9]  = {bv, 256,     SL_BV};
  am.d[10] = {bo, 256,     SL_BO};
  am.d[11] = {b1, 1024,    SL_B1};
  am.d[12] = {b2, 256,     SL_B2};
  absmax_multi_kernel<<<dim3(64, 13), 256, 0, stream>>>(am, ws);

  // --- quantize x + 6 weights to i8 codes (1 dispatch); biases (1 dispatch) ---
  QMBatch qm;
  qm.d[0] = {x,  qx8, SZ_XE/4, SL_X,  -128.f};
  qm.d[1] = {Wq, wq8, SZ_W/4,  SL_WQ, -127.f};
  qm.d[2] = {Wk, wk8, SZ_W/4,  SL_WK, -127.f};
  qm.d[3] = {Wv, wv8, SZ_W/4,  SL_WV, -127.f};
  qm.d[4] = {W1, w18, SZ_XE/4, SL_W1, -127.f};
  qm.d[5] = {W2, w28, SZ_XE/4, SL_W2, -127.f};
  qm.d[6] = {Wo, wo8, SZ_W/4,  SL_WO, -127.f};
  quant8_multi_kernel<<<dim3(64, 7), 256, 0, stream>>>(qm, ws);
  rowsum_i8_kernel<<<TB_E, 256, 0, stream>>>(w28, rsum, TB_MLP);
  BBatch bb;
  bb.d[0] = {bq, qbq_, 256,  SL_BQ};
  bb.d[1] = {bk, qbk_, 256,  SL_BK};
  bb.d[2] = {bv, qbv_, 256,  SL_BV};
  bb.d[3] = {bo, qbo_, 256,  SL_BO};
  bb.d[4] = {b1, qb1_, 1024, SL_B1};
  bb.d[5] = {b2, qb2_, 256,  SL_B2};
  bias_quant_multi_kernel<<<dim3(4, 6), 256, 0, stream>>>(bb, ws);

  // --- in-projections (int8 MFMA, exact) with fused output absmax ---
  gemm_i8_kernel<<<dim3(TB_E/128, TB_ROWS/128), 256, 0, stream>>>(
      qx8, wq8, qbq_, ws + SL_X, 127.f, ws + SL_WQ, nullptr, qbuf, TB_ROWS, TB_E, TB_E, ws + SL_Q, 0);
  gemm_i8_kernel<<<dim3(TB_E/128, TB_ROWS/128), 256, 0, stream>>>(
      qx8, wk8, qbk_, ws + SL_X, 127.f, ws + SL_WK, nullptr, kbuf, TB_ROWS, TB_E, TB_E, ws + SL_K, 0);
  gemm_i8_kernel<<<dim3(TB_E/128, TB_ROWS/128), 256, 0, stream>>>(
      qx8, wv8, qbv_, ws + SL_X, 127.f, ws + SL_WV, nullptr, vbuf, TB_ROWS, TB_E, TB_E, ws + SL_V, 0);

  // --- quantize q (pre=1/8), k -> [B,H,S,D]; v -> blocked [BH][jb][D][64] ---
  quant8_qk_kernel<<<2048, 256, 0, stream>>>(qbuf, q8, ws + SL_Q, 0.125f);
  quant8_qk_kernel<<<2048, 256, 0, stream>>>(kbuf, k8, ws + SL_K, 1.f);
  quant8_vb_kernel<<<dim3(TB_B*TB_H, TB_S/64), 256, 0, stream>>>(vbuf, ws + SL_V, v8b);

  // --- attention (i8 MFMA, 3 passes) ---
  attn_rowmax_kernel<<<dim3(TB_B*TB_H, TB_S/64), 256, 0, stream>>>(q8, k8, irowmax, imax);
  attn_rowsum_kernel<<<dim3(TB_B*TB_H, TB_S/64), 256, 0, stream>>>(
      q8, k8, irowmax, imax, ws + SL_Q, ws + SL_K, rowl, ws + SL_ATTN);
  attn_pv_kernel<<<dim3(TB_B*TB_H, TB_S/64), 256, 0, stream>>>(
      q8, k8, v8b, irowmax, imax, ws + SL_Q, ws + SL_K, ws + SL_V, ws + SL_ATTN,
      rowl, ctx, ws + SL_CTX);

  // --- out projection ---
  quant8_kernel<<<nblocks(SZ_XE/4), 256, 0, stream>>>(ctx, ctx8, SZ_XE/4, ws + SL_CTX, 1.f, -128.f);
  gemm_i8_kernel<<<dim3(TB_E/128, TB_ROWS/128), 256, 0, stream>>>(
      ctx8, wo8, qbo_, ws + SL_CTX, 127.f, ws + SL_WO, nullptr, attn_out, TB_ROWS, TB_E, TB_E, ws + SL_AO, 0);

  // --- residual + LN (fused h absmax) ---
  resid_ln_kernel<<<TB_ROWS, 256, 0, stream>>>(qx8, ws + SL_X, attn_out, ws + SL_AO, hbuf, ws + SL_H);

  // --- MLP ---
  quant8_kernel<<<nblocks(SZ_XE/4), 256, 0, stream>>>(hbuf, m08, SZ_XE/4, ws + SL_H, 1.f, -128.f);
  gemm_i8_kernel<<<dim3(TB_MLP/128, TB_ROWS/128), 256, 0, stream>>>(
      m08, w18, qb1_, ws + SL_H, 127.f, ws + SL_W1, nullptr, m1, TB_ROWS, TB_MLP, TB_E, ws + SL_RELU, 1);
  relu_quant8_kernel<<<nblocks(SZ_M1/4), 256, 0, stream>>>(m1, m18, SZ_M1/4, ws + SL_RELU);
  gemm_i8_kernel<<<dim3(TB_E/128, TB_ROWS/128), 256, 0, stream>>>(
      m18, w28, qb2_, ws + SL_RELU, 255.f, ws + SL_W2, rsum, m2, TB_ROWS, TB_E, TB_MLP, ws + SL_M2, 0);

  // --- final residual + LN ---
  resid_ln_kernel<<<TB_ROWS, 256, 0, stream>>>(m08, ws + SL_H, m2, ws + SL_M2, out, ws + SL_DUMMY);
}

// Round 6
// 553.656 us; speedup vs baseline: 5.1661x; 1.0475x over previous
//
#include <hip/hip_runtime.h>
#include <cstdint>
#include <cstddef>

// Problem constants
#define TB_B 4
#define TB_S 1024
#define TB_E 1024
#define TB_H 16
#define TB_D 64
#define TB_MLP 4096
#define TB_ROWS (TB_B * TB_S)   // 4096

typedef int int4v __attribute__((ext_vector_type(4)));

#define LGKM0() __asm__ volatile("s_waitcnt lgkmcnt(0)" ::: "memory")
#define CMEMBAR() __asm__ volatile("" ::: "memory")

static __device__ __forceinline__ void atomicMaxF(float* addr, float v) {
  // valid for non-negative floats: IEEE bit pattern is monotonic
  atomicMax(reinterpret_cast<unsigned int*>(addr), __float_as_uint(v));
}

static __device__ __forceinline__ float fast_exp2(float x) {
#if __has_builtin(__builtin_amdgcn_exp2f)
  return __builtin_amdgcn_exp2f(x);
#else
  return exp2f(x);
#endif
}

// async global->LDS, 16 bytes per lane. LDS dest must be wave-uniform base + lane*16.
static __device__ __forceinline__ void gl2lds16(const void* g, void* l) {
  __builtin_amdgcn_global_load_lds(
      (const __attribute__((address_space(1))) void*)g,
      (__attribute__((address_space(3))) void*)l, 16, 0, 0);
}

// ---------------------------------------------------------------------------
// multi-tensor absmax: one dispatch for all 13 input tensors
// ---------------------------------------------------------------------------
struct AMDesc { const float* p; long n4; int slot; };
struct AMBatch { AMDesc d[13]; };
__global__ __launch_bounds__(256) void absmax_multi_kernel(AMBatch bt, float* ws) {
  AMDesc d = bt.d[blockIdx.y];
  float m = 0.f;
  long stride = (long)gridDim.x * 256;
  for (long i = (long)blockIdx.x * 256 + threadIdx.x; i < d.n4; i += stride) {
    float4 v = ((const float4*)d.p)[i];
    m = fmaxf(m, fmaxf(fmaxf(fabsf(v.x), fabsf(v.y)), fmaxf(fabsf(v.z), fabsf(v.w))));
  }
#pragma unroll
  for (int o = 32; o; o >>= 1) m = fmaxf(m, __shfl_down(m, o, 64));
  __shared__ float sm[4];
  if (!(threadIdx.x & 63)) sm[threadIdx.x >> 6] = m;
  __syncthreads();
  if (threadIdx.x == 0)
    atomicMaxF(ws + d.slot, fmaxf(fmaxf(sm[0], sm[1]), fmaxf(sm[2], sm[3])));
}

// multi-tensor fake-quant -> i8 codes (x + 6 weights)
struct QMDesc { const float* in; signed char* out; long n4; int slot; float qmin; };
struct QMBatch { QMDesc d[7]; };
__global__ __launch_bounds__(256) void quant8_multi_kernel(QMBatch bt, const float* ws) {
  QMDesc d = bt.d[blockIdx.y];
  float scale = fmaxf(ws[d.slot] / 127.f, 1e-8f);
  long stride = (long)gridDim.x * 256;
  for (long i = (long)blockIdx.x * 256 + threadIdx.x; i < d.n4; i += stride) {
    float4 v = ((const float4*)d.in)[i];
    char4 o;
    o.x = (signed char)(int)fminf(fmaxf(rintf(v.x / scale), d.qmin), 127.f);
    o.y = (signed char)(int)fminf(fmaxf(rintf(v.y / scale), d.qmin), 127.f);
    o.z = (signed char)(int)fminf(fmaxf(rintf(v.z / scale), d.qmin), 127.f);
    o.w = (signed char)(int)fminf(fmaxf(rintf(v.w / scale), d.qmin), 127.f);
    ((char4*)d.out)[i] = o;
  }
}

// multi-tensor bias fake-quant -> fp32
struct BDesc { const float* in; float* out; int n4; int slot; };
struct BBatch { BDesc d[6]; };
__global__ __launch_bounds__(256) void bias_quant_multi_kernel(BBatch bt, const float* ws) {
  BDesc d = bt.d[blockIdx.y];
  float scale = fmaxf(ws[d.slot] / 127.f, 1e-8f);
  int i = blockIdx.x * 256 + threadIdx.x;
  if (i < d.n4) {
    float4 v = ((const float4*)d.in)[i];
    float4 o;
    o.x = fminf(fmaxf(rintf(v.x / scale), -128.f), 127.f) * scale;
    o.y = fminf(fmaxf(rintf(v.y / scale), -128.f), 127.f) * scale;
    o.z = fminf(fmaxf(rintf(v.z / scale), -128.f), 127.f) * scale;
    o.w = fminf(fmaxf(rintf(v.w / scale), -128.f), 127.f) * scale;
    ((float4*)d.out)[i] = o;
  }
}

// generic fake-quant -> i8 (same layout)
__global__ __launch_bounds__(256) void quant8_kernel(const float* __restrict__ in,
                                                     signed char* __restrict__ out8, long n4,
                                                     const float* __restrict__ amax_p,
                                                     float pre, float qmin) {
  float scale = fmaxf(amax_p[0] * pre / 127.f, 1e-8f);
  long stride = (long)gridDim.x * 256;
  for (long i = (long)blockIdx.x * 256 + threadIdx.x; i < n4; i += stride) {
    float4 v = ((const float4*)in)[i];
    char4 o;
    o.x = (signed char)(int)fminf(fmaxf(rintf(v.x * pre / scale), qmin), 127.f);
    o.y = (signed char)(int)fminf(fmaxf(rintf(v.y * pre / scale), qmin), 127.f);
    o.z = (signed char)(int)fminf(fmaxf(rintf(v.z * pre / scale), qmin), 127.f);
    o.w = (signed char)(int)fminf(fmaxf(rintf(v.w * pre / scale), qmin), 127.f);
    ((char4*)out8)[i] = o;
  }
}

// relu + unsigned 8-bit quant -> codes stored as (c - 128) in signed i8
__global__ __launch_bounds__(256) void relu_quant8_kernel(const float* __restrict__ in,
                                                          signed char* __restrict__ out8, long n4,
                                                          const float* __restrict__ amax_p) {
  float scale = fmaxf(amax_p[0] / 255.f, 1e-8f);
  long stride = (long)gridDim.x * 256;
  for (long i = (long)blockIdx.x * 256 + threadIdx.x; i < n4; i += stride) {
    float4 v = ((const float4*)in)[i];
    char4 o;
    o.x = (signed char)((int)fminf(fmaxf(rintf(fmaxf(v.x, 0.f) / scale), 0.f), 255.f) - 128);
    o.y = (signed char)((int)fminf(fmaxf(rintf(fmaxf(v.y, 0.f) / scale), 0.f), 255.f) - 128);
    o.z = (signed char)((int)fminf(fmaxf(rintf(fmaxf(v.z, 0.f) / scale), 0.f), 255.f) - 128);
    o.w = (signed char)((int)fminf(fmaxf(rintf(fmaxf(v.w, 0.f) / scale), 0.f), 255.f) - 128);
    ((char4*)out8)[i] = o;
  }
}

// per-row sum of int8 codes (for unsigned-offset correction); one block per row
__global__ __launch_bounds__(256) void rowsum_i8_kernel(const signed char* __restrict__ w8,
                                                        int* __restrict__ out, int Kdim) {
  const int row = blockIdx.x, t = threadIdx.x;
  const signed char* p = w8 + (long)row * Kdim;
  int s = 0;
  for (int i = t * 16; i < Kdim; i += 4096) {
    int4v v = *(const int4v*)(p + i);
    const signed char* b = (const signed char*)&v;
#pragma unroll
    for (int j = 0; j < 16; j++) s += b[j];
  }
#pragma unroll
  for (int o = 32; o; o >>= 1) s += __shfl_down(s, o, 64);
  __shared__ int sm[4];
  if (!(t & 63)) sm[t >> 6] = s;
  __syncthreads();
  if (t == 0) out[row] = sm[0] + sm[1] + sm[2] + sm[3];
}

// ---------------------------------------------------------------------------
// int8 MFMA NT GEMM (exact): C[M,N] = (sum_k A8[m,k]*B8[n,k] + corr) * s_a*s_b + bias[n]
// XCD-aware swizzle: M-row bands partitioned per XCD so co-resident blocks
// share the B matrix in that XCD's L2.
// mode 0: row-major C, single amax slot. mode 1 (QKV): N=3*1024 segments,
// per-segment scale/amax, C written fp32 in [B,H,S,D] per segment.
// ---------------------------------------------------------------------------
__global__ __launch_bounds__(256) void gemm_i8_kernel(
    const signed char* __restrict__ A, const signed char* __restrict__ Bw,
    const float* __restrict__ biasq,
    const float* __restrict__ amax_a, float div_a,
    const float* __restrict__ amax_b,
    const int* __restrict__ rowsum,           // nullable: adds 128*rowsum[n]
    float* __restrict__ C, int M, int N, int K,
    float* __restrict__ amax_out, int relu_amax, int mode) {
  __shared__ signed char As[8192];  // 128 rows x 64 bytes, K-contiguous
  __shared__ signed char Bs[8192];
  const int t = threadIdx.x;
  // XCD-aware swizzle (gridDim.y % 8 == 0): xcd gets M-band [xcd*gy/8 .. )
  int bx, by;
  {
    int lin = blockIdx.y * gridDim.x + blockIdx.x;
    if ((gridDim.y & 7) == 0) {
      int xcd = lin & 7, j = lin >> 3;
      bx = j % gridDim.x;
      by = (gridDim.y >> 3) * xcd + j / gridDim.x;
    } else { bx = blockIdx.x; by = blockIdx.y; }
  }
  const int m0 = by * 128, n0 = bx * 128;
  const int w = t >> 6, lane = t & 63;
  const int fr = lane & 15, quad = lane >> 4;
  const int r0 = t >> 2;            // staging row 0..63
  const int c0 = (t & 3) * 16;      // staging byte col
  const int a_off0 = (w * 32 + fr) * 64 + quad * 16;
  const int b_off0 = fr * 64 + quad * 16;

  int4v acc[2][8];
#pragma unroll
  for (int r = 0; r < 2; r++)
#pragma unroll
    for (int c = 0; c < 8; c++) acc[r][c] = (int4v){0, 0, 0, 0};

  for (int k0 = 0; k0 < K; k0 += 64) {
    __syncthreads();
    gl2lds16(A + (long)(m0 + r0) * K + k0 + c0, As + t * 16);
    gl2lds16(A + (long)(m0 + r0 + 64) * K + k0 + c0, As + t * 16 + 4096);
    gl2lds16(Bw + (long)(n0 + r0) * K + k0 + c0, Bs + t * 16);
    gl2lds16(Bw + (long)(n0 + r0 + 64) * K + k0 + c0, Bs + t * 16 + 4096);
    __syncthreads();
    int4v af[2], bf[8];
#pragma unroll
    for (int r = 0; r < 2; r++) af[r] = *(const int4v*)(As + a_off0 + r * 1024);
#pragma unroll
    for (int c = 0; c < 8; c++) bf[c] = *(const int4v*)(Bs + b_off0 + c * 1024);
#pragma unroll
    for (int r = 0; r < 2; r++)
#pragma unroll
      for (int c = 0; c < 8; c++)
        acc[r][c] = __builtin_amdgcn_mfma_i32_16x16x64_i8(af[r], bf[c], acc[r][c], 0, 0, 0);
  }

  const int seg = (mode == 1) ? (n0 >> 10) : 0;
  const float s_a = fmaxf(amax_a[0] / div_a, 1e-8f);
  const float s_b = fmaxf(amax_b[seg] / 127.f, 1e-8f);
  const float s = s_a * s_b;
  float lmax = 0.f;
#pragma unroll
  for (int r = 0; r < 2; r++) {
    int rbase = m0 + w * 32 + r * 16 + quad * 4;
#pragma unroll
    for (int c = 0; c < 8; c++) {
      int col = n0 + c * 16 + fr;
      int corr = rowsum ? (rowsum[col] << 7) : 0;
      float bi = biasq[col];
      if (mode == 1) {
        // segment-local fp32 [B,H,S,D] write
        int h = (col >> 6) & 15, dd = col & 63;
        float* cbase = C + (long)seg * ((long)TB_ROWS * TB_E);
#pragma unroll
        for (int g = 0; g < 4; g++) {
          int m = rbase + g;
          int b = m >> 10, sdx = m & 1023;
          float o = (float)acc[r][c][g] * s + bi;
          lmax = fmaxf(lmax, fabsf(o));
          cbase[((((long)b * TB_H + h) * TB_S) + sdx) * TB_D + dd] = o;
        }
      } else {
#pragma unroll
        for (int g = 0; g < 4; g++) {
          float o = (float)(acc[r][c][g] + corr) * s + bi;
          lmax = fmaxf(lmax, relu_amax ? fmaxf(o, 0.f) : fabsf(o));
          C[(long)(rbase + g) * N + col] = o;
        }
      }
    }
  }
#pragma unroll
  for (int o = 32; o; o >>= 1) lmax = fmaxf(lmax, __shfl_down(lmax, o, 64));
  __shared__ float redm[4];
  if (!lane) redm[w] = lmax;
  __syncthreads();
  if (t == 0) atomicMaxF(amax_out + seg, fmaxf(fmaxf(redm[0], redm[1]), fmaxf(redm[2], redm[3])));
}

// ---------------------------------------------------------------------------
// v quant + transpose: fp32 [B,H,S,D] -> i8 blocked [BH][jb][D][64]
// ---------------------------------------------------------------------------
__global__ __launch_bounds__(256) void quant8_vb_kernel(const float* __restrict__ v,
                                                        const float* __restrict__ amax_p,
                                                        signed char* __restrict__ v8b) {
  __shared__ signed char tile[64][80];  // [d][s], stride 80
  const int bh = blockIdx.x;
  const int jb = blockIdx.y;
  const int s0 = jb * 64;
  const int t = threadIdx.x;
  const float scale = fmaxf(amax_p[0] / 127.f, 1e-8f);
#pragma unroll
  for (int it = 0; it < 4; it++) {
    int idx = t + it * 256;           // 0..1023 float4 slots
    int r = idx >> 4, c4 = (idx & 15) * 4;
    float4 vv = *(const float4*)(v + ((long)bh * TB_S + s0 + r) * TB_D + c4);
    tile[c4 + 0][r] = (signed char)(int)fminf(fmaxf(rintf(vv.x / scale), -128.f), 127.f);
    tile[c4 + 1][r] = (signed char)(int)fminf(fmaxf(rintf(vv.y / scale), -128.f), 127.f);
    tile[c4 + 2][r] = (signed char)(int)fminf(fmaxf(rintf(vv.z / scale), -128.f), 127.f);
    tile[c4 + 3][r] = (signed char)(int)fminf(fmaxf(rintf(vv.w / scale), -128.f), 127.f);
  }
  __syncthreads();
  int d = t >> 2, sb = (t & 3) * 16;
  int4v o = *(const int4v*)&tile[d][sb];
  *(int4v*)(v8b + (((long)bh * 16 + jb) * 64 + d) * 64 + sb) = o;
}

// ---------------------------------------------------------------------------
// Attention pass A: per-row signed int max of scores -> irowmax; global int
// absmax -> imax_out. q8/k8 in [B,H,S,D]; wave loads are 1KB contiguous.
// D[m=j][n=i]: lane (fr,quad) holds i = i0+fr, j = j0 + quad*4 + g.
// ---------------------------------------------------------------------------
__global__ __launch_bounds__(256) void attn_rowmax_kernel(const signed char* __restrict__ q8,
                                                          const signed char* __restrict__ k8,
                                                          int* __restrict__ irowmax,
                                                          int* __restrict__ imax_out) {
  const int bh = blockIdx.x;
  const int t = threadIdx.x, w = t >> 6, lane = t & 63;
  const int fr = lane & 15, quad = lane >> 4;
  const int i0 = blockIdx.y * 64 + w * 16;
  const long base = (long)bh * TB_S;
  int4v qf = *(const int4v*)(q8 + (base + i0 + fr) * 64 + quad * 16);
  int mx = -2147483647, mn = 2147483647;
  for (int j0 = 0; j0 < TB_S; j0 += 16) {
    int4v kf = *(const int4v*)(k8 + (base + j0 + fr) * 64 + quad * 16);
    int4v sc = __builtin_amdgcn_mfma_i32_16x16x64_i8(kf, qf, (int4v){0, 0, 0, 0}, 0, 0, 0);
    mx = max(mx, max(max(sc[0], sc[1]), max(sc[2], sc[3])));
    mn = min(mn, min(min(sc[0], sc[1]), min(sc[2], sc[3])));
  }
  mx = max(mx, __shfl_xor(mx, 16, 64));
  mx = max(mx, __shfl_xor(mx, 32, 64));
  mn = min(mn, __shfl_xor(mn, 16, 64));
  mn = min(mn, __shfl_xor(mn, 32, 64));
  if (quad == 0) irowmax[(long)bh * TB_S + i0 + fr] = mx;
  int gm = max(mx, -mn);
#pragma unroll
  for (int o = 32; o; o >>= 1) gm = max(gm, __shfl_down(gm, o, 64));
  __shared__ int sm[4];
  if (!lane) sm[w] = gm;
  __syncthreads();
  if (t == 0) atomicMax(imax_out, max(max(sm[0], sm[1]), max(sm[2], sm[3])));
}

// ---------------------------------------------------------------------------
// Attention pass B: l = sum exp2((qv - qmax)*aa) per row (single loop; row max
// code derived from irowmax). rowl <- l; amax_attn <- max(1/l).
// ---------------------------------------------------------------------------
__global__ __launch_bounds__(256) void attn_rowsum_kernel(
    const signed char* __restrict__ q8, const signed char* __restrict__ k8,
    const int* __restrict__ irowmax, const int* __restrict__ imax_p,
    const float* __restrict__ amax_q, const float* __restrict__ amax_k,
    float* __restrict__ rowl, float* __restrict__ amax_attn) {
  const int bh = blockIdx.x;
  const int t = threadIdx.x, w = t >> 6, lane = t & 63;
  const int fr = lane & 15, quad = lane >> 4;
  const int i0 = blockIdx.y * 64 + w * 16;
  const float s_q = fmaxf(amax_q[0] * 0.125f / 127.f, 1e-8f);
  const float s_k = fmaxf(amax_k[0] / 127.f, 1e-8f);
  const float sqk = s_q * s_k;
  const float s_sc = fmaxf((float)imax_p[0] * sqk / 127.f, 1e-8f);
  const float c1 = sqk / s_sc;
  const float aa = s_sc * 1.44269504088896340736f;
  const long base = (long)bh * TB_S;
  int4v qf = *(const int4v*)(q8 + (base + i0 + fr) * 64 + quad * 16);
  const int imr = irowmax[base + i0 + fr];
  const float qmax = fminf(fmaxf(rintf((float)imr * c1), -128.f), 127.f);
  const float qa = qmax * aa;
  float l = 0.f;
  for (int j0 = 0; j0 < TB_S; j0 += 16) {
    int4v kf = *(const int4v*)(k8 + (base + j0 + fr) * 64 + quad * 16);
    int4v sc = __builtin_amdgcn_mfma_i32_16x16x64_i8(kf, qf, (int4v){0, 0, 0, 0}, 0, 0, 0);
#pragma unroll
    for (int g = 0; g < 4; g++) {
      float qv = fminf(fmaxf(rintf((float)sc[g] * c1), -128.f), 127.f);
      l += fast_exp2(fmaf(qv, aa, -qa));
    }
  }
  l += __shfl_xor(l, 16, 64);
  l += __shfl_xor(l, 32, 64);
  if (quad == 0) rowl[base + i0 + fr] = l;
  float inv = 1.f / l;                        // row max of softmax = 1/l
#pragma unroll
  for (int o = 32; o; o >>= 1) inv = fmaxf(inv, __shfl_down(inv, o, 64));
  __shared__ float smf[4];
  if (!lane) smf[w] = inv;
  __syncthreads();
  if (t == 0) atomicMaxF(amax_attn, fmaxf(fmaxf(smf[0], smf[1]), fmaxf(smf[2], smf[3])));
}

// ---------------------------------------------------------------------------
// Attention pass C: recompute scores (identical expr -> identical codes),
// attn code = rint(exp2(qv*aa - bexp) * invls); per-wave LDS transpose (no
// block barriers); PV MFMA on blocked v8b. ctx fp32 [B,S,H,D] + fused absmax.
// ---------------------------------------------------------------------------
__global__ __launch_bounds__(256) void attn_pv_kernel(
    const signed char* __restrict__ q8, const signed char* __restrict__ k8,
    const signed char* __restrict__ v8b,
    const int* __restrict__ irowmax, const int* __restrict__ imax_p,
    const float* __restrict__ amax_q, const float* __restrict__ amax_k,
    const float* __restrict__ amax_v, const float* __restrict__ amax_attn,
    const float* __restrict__ rowl,
    float* __restrict__ ctx, float* __restrict__ amax_ctx) {
  __shared__ signed char latt[4][16][80];  // [wave][i-rel][j-byte], stride 80
  const int bh = blockIdx.x, b = bh >> 4, h = bh & 15;
  const int t = threadIdx.x, w = t >> 6, lane = t & 63;
  const int fr = lane & 15, quad = lane >> 4;
  const int i0 = blockIdx.y * 64 + w * 16;
  const float s_q = fmaxf(amax_q[0] * 0.125f / 127.f, 1e-8f);
  const float s_k = fmaxf(amax_k[0] / 127.f, 1e-8f);
  const float sqk = s_q * s_k;
  const float s_sc = fmaxf((float)imax_p[0] * sqk / 127.f, 1e-8f);
  const float c1 = sqk / s_sc;
  const float aa = s_sc * 1.44269504088896340736f;
  const float s_v = fmaxf(amax_v[0] / 127.f, 1e-8f);
  const float s_at = fmaxf(amax_attn[0] / 127.f, 1e-8f);
  const long base = (long)bh * TB_S;
  int4v qf = *(const int4v*)(q8 + (base + i0 + fr) * 64 + quad * 16);
  const int imr = irowmax[base + i0 + fr];
  const float qmax = fminf(fmaxf(rintf((float)imr * c1), -128.f), 127.f);
  const float bexp = qmax * aa;
  const float li = rowl[base + i0 + fr];
  const float invls = 1.f / (li * s_at);             // one exact div per row
  int4v accv[4];
#pragma unroll
  for (int dtile = 0; dtile < 4; dtile++) accv[dtile] = (int4v){0, 0, 0, 0};

  for (int j0 = 0; j0 < TB_S; j0 += 64) {
#pragma unroll
    for (int tt = 0; tt < 4; tt++) {
      int4v kf = *(const int4v*)(k8 + (base + j0 + tt * 16 + fr) * 64 + quad * 16);
      int4v sc = __builtin_amdgcn_mfma_i32_16x16x64_i8(kf, qf, (int4v){0, 0, 0, 0}, 0, 0, 0);
      int packed = 0;
#pragma unroll
      for (int g = 0; g < 4; g++) {
        float qv = fminf(fmaxf(rintf((float)sc[g] * c1), -128.f), 127.f);
        float e = fast_exp2(fmaf(qv, aa, -bexp));
        int code = (int)fminf(fmaxf(rintf(e * invls), -128.f), 127.f);
        packed |= (code & 255) << (g * 8);
      }
      *(int*)&latt[w][fr][tt * 16 + quad * 4] = packed;
    }
    LGKM0();   // wave-private LDS: ds in-order per wave, no block barrier needed
    int4v af = *(const int4v*)&latt[w][fr][quad * 16];
    const signed char* vbase = v8b + (((long)bh * 16 + (j0 >> 6)) * 64) * 64;
#pragma unroll
    for (int dtile = 0; dtile < 4; dtile++) {
      int4v vf = *(const int4v*)(vbase + (dtile * 16 + fr) * 64 + quad * 16);
      accv[dtile] = __builtin_amdgcn_mfma_i32_16x16x64_i8(af, vf, accv[dtile], 0, 0, 0);
    }
    CMEMBAR(); // keep next iteration's ds_writes after this read (in-order DS)
  }
  const float sav = s_at * s_v;
  float cmax = 0.f;
#pragma unroll
  for (int dtile = 0; dtile < 4; dtile++) {
#pragma unroll
    for (int g = 0; g < 4; g++) {
      float val = (float)accv[dtile][g] * sav;
      cmax = fmaxf(cmax, fabsf(val));
      int irow = i0 + quad * 4 + g;
      ctx[(((long)(b * TB_S + irow)) * TB_H + h) * TB_D + dtile * 16 + fr] = val;
    }
  }
#pragma unroll
  for (int o = 32; o; o >>= 1) cmax = fmaxf(cmax, __shfl_down(cmax, o, 64));
  __shared__ float smf[4];
  if (!lane) smf[w] = cmax;
  __syncthreads();
  if (t == 0) atomicMaxF(amax_ctx, fmaxf(fmaxf(smf[0], smf[1]), fmaxf(smf[2], smf[3])));
}

// ---------------------------------------------------------------------------
// h = LayerNorm(dequant(a8) + fakequant(braw)); fused output absmax.
// ---------------------------------------------------------------------------
__global__ __launch_bounds__(256) void resid_ln_kernel(const signed char* __restrict__ a8,
                                                       const float* __restrict__ amax_a,
                                                       const float* __restrict__ braw,
                                                       const float* __restrict__ amax_b,
                                                       float* __restrict__ outp,
                                                       float* __restrict__ amax_out) {
  __shared__ float red[4];
  __shared__ float redm[4];
  const int row = blockIdx.x, t = threadIdx.x;
  const float sa = fmaxf(amax_a[0] / 127.f, 1e-8f);
  const float sb = fmaxf(amax_b[0] / 127.f, 1e-8f);
  const long base = (long)row * TB_E + t * 4;
  char4 a = ((const char4*)a8)[(long)row * 256 + t];
  float4 bv = *(const float4*)(braw + base);
  float v0 = (float)a.x * sa + fminf(fmaxf(rintf(bv.x / sb), -128.f), 127.f) * sb;
  float v1 = (float)a.y * sa + fminf(fmaxf(rintf(bv.y / sb), -128.f), 127.f) * sb;
  float v2 = (float)a.z * sa + fminf(fmaxf(rintf(bv.z / sb), -128.f), 127.f) * sb;
  float v3 = (float)a.w * sa + fminf(fmaxf(rintf(bv.w / sb), -128.f), 127.f) * sb;
  float s = v0 + v1 + v2 + v3;
#pragma unroll
  for (int o = 32; o; o >>= 1) s += __shfl_down(s, o, 64);
  if (!(t & 63)) red[t >> 6] = s;
  __syncthreads();
  float mu = ((red[0] + red[1]) + (red[2] + red[3])) * (1.f / TB_E);
  float d0 = v0 - mu, d1 = v1 - mu, d2 = v2 - mu, d3 = v3 - mu;
  float sq = d0 * d0 + d1 * d1 + d2 * d2 + d3 * d3;
#pragma unroll
  for (int o = 32; o; o >>= 1) sq += __shfl_down(sq, o, 64);
  __syncthreads();
  if (!(t & 63)) red[t >> 6] = sq;
  __syncthreads();
  float var = ((red[0] + red[1]) + (red[2] + red[3])) * (1.f / TB_E);
  float rs = 1.f / sqrtf(var + 1e-5f);
  float4 o4;
  o4.x = d0 * rs; o4.y = d1 * rs; o4.z = d2 * rs; o4.w = d3 * rs;
  *(float4*)(outp + base) = o4;
  float lm = fmaxf(fmaxf(fabsf(o4.x), fabsf(o4.y)), fmaxf(fabsf(o4.z), fabsf(o4.w)));
#pragma unroll
  for (int o = 32; o; o >>= 1) lm = fmaxf(lm, __shfl_down(lm, o, 64));
  if (!(t & 63)) redm[t >> 6] = lm;
  __syncthreads();
  if (t == 0) atomicMaxF(amax_out, fmaxf(fmaxf(redm[0], redm[1]), fmaxf(redm[2], redm[3])));
}

// ---------------------------------------------------------------------------
// Host side
// ---------------------------------------------------------------------------
#define SL_X 0
#define SL_WQ 1
#define SL_WK 2
#define SL_WV 3
#define SL_WO 4
#define SL_W1 5
#define SL_W2 6
#define SL_BQ 7
#define SL_BK 8
#define SL_BV 9
#define SL_BO 10
#define SL_B1 11
#define SL_B2 12
#define SL_Q 13   // SL_K = 14, SL_V = 15 must stay consecutive (QKV epilogue)
#define SL_K 14
#define SL_V 15
#define SL_SCI 16     // int imax of scores
#define SL_ATTN 17
#define SL_CTX 18
#define SL_AO 19
#define SL_H 20
#define SL_RELU 21
#define SL_M2 22
#define SL_DUMMY 23

static inline int nblocks(long n) {
  long b = (n + 255) / 256;
  return (int)(b > 2048 ? 2048 : b);
}

extern "C" void kernel_launch(void* const* d_in, const int* in_sizes, int n_in,
                              void* d_out, int out_size, void* d_ws, size_t ws_size,
                              hipStream_t stream) {
  const float* x  = (const float*)d_in[0];
  const float* Wq = (const float*)d_in[1];
  const float* bq = (const float*)d_in[2];
  const float* Wk = (const float*)d_in[3];
  const float* bk = (const float*)d_in[4];
  const float* Wv = (const float*)d_in[5];
  const float* bv = (const float*)d_in[6];
  const float* Wo = (const float*)d_in[7];
  const float* bo = (const float*)d_in[8];
  const float* W1 = (const float*)d_in[9];
  const float* b1 = (const float*)d_in[10];
  const float* W2 = (const float*)d_in[11];
  const float* b2 = (const float*)d_in[12];
  float* ws = (float*)d_ws;
  float* out = (float*)d_out;

  const long SZ_XE = (long)TB_ROWS * TB_E;      // 4,194,304
  const long SZ_W  = (long)TB_E * TB_E;         // 1,048,576
  const long SZ_M1 = (long)TB_ROWS * TB_MLP;    // 16,777,216

  // float-offset layout
  const long OFF_QBQ = 1024, OFF_QBK = 2048, OFF_QBV = 3072, OFF_QBO = 4096;
  const long OFF_QB1 = 5120, OFF_QB2 = 9216;
  const long OFF_RSUM = 10240;                  // int32[1024]
  const long OFF_Q  = 65536;                    // fp32 q [B,H,S,D], later ctx
  const long OFF_K  = OFF_Q + SZ_XE;            // fp32 k [B,H,S,D], later attn_out
  const long OFF_V  = OFF_K + SZ_XE;            // fp32 v [B,H,S,D], later h
  const long OFF_M2 = OFF_V + SZ_XE;            // fp32 m2
  const long OFF_IRM = OFF_M2 + SZ_XE;          // int irowmax [65536]
  const long OFF_ROWL = OFF_IRM + 65536;
  const long OFF_M1 = OFF_ROWL + 65536;         // fp32 m1 (64MB)
  const long OFF_I8 = OFF_M1 + SZ_M1;           // i8 region start (float offset)

  float* qbuf = ws + OFF_Q;  float* kbuf = ws + OFF_K;  float* vbuf = ws + OFF_V;
  float* m2   = ws + OFF_M2;
  int*   irowmax = (int*)(ws + OFF_IRM);
  float* rowl = ws + OFF_ROWL;
  float* m1 = ws + OFF_M1;
  float* ctx = qbuf;        // reuse q (q8 codes already extracted)
  float* attn_out = kbuf;   // reuse k
  float* hbuf = vbuf;       // reuse v
  float* qbq_ = ws + OFF_QBQ; float* qbk_ = ws + OFF_QBK;
  float* qbv_ = ws + OFF_QBV; float* qbo_ = ws + OFF_QBO;
  float* qb1_ = ws + OFF_QB1; float* qb2_ = ws + OFF_QB2;
  int* rsum = (int*)(ws + OFF_RSUM);
  int* imax = (int*)(ws + SL_SCI);

  // i8 code buffers (byte pointers)
  signed char* i8base = (signed char*)(ws + OFF_I8);
  signed char* qx8  = i8base;                   // 4096x1024 [rows,E]
  signed char* wq8  = qx8 + SZ_XE;              // 1024x1024  (wq8,wk8,wv8 contiguous for QKV fusion)
  signed char* wk8  = wq8 + SZ_W;
  signed char* wv8  = wk8 + SZ_W;
  signed char* wo8  = wv8 + SZ_W;
  signed char* w18  = wo8 + SZ_W;               // 4096x1024
  signed char* w28  = w18 + SZ_XE;              // 1024x4096
  signed char* ctx8 = w28 + SZ_XE;              // 4096x1024
  signed char* m08  = ctx8 + SZ_XE;             // 4096x1024
  signed char* m18  = m08 + SZ_XE;              // 4096x4096 (relu codes - 128)
  signed char* q8   = m18 + SZ_M1;              // [B,H,S,D]
  signed char* k8   = q8 + SZ_XE;               // [B,H,S,D]
  signed char* v8b  = k8 + SZ_XE;               // [BH][16][64][64]

  hipMemsetAsync(ws, 0, 4096, stream);  // zero scalar slots

  // --- absmax of all 13 inputs (1 dispatch) ---
  AMBatch am;
  am.d[0]  = {x,  SZ_XE/4, SL_X};
  am.d[1]  = {Wq, SZ_W/4,  SL_WQ};
  am.d[2]  = {Wk, SZ_W/4,  SL_WK};
  am.d[3]  = {Wv, SZ_W/4,  SL_WV};
  am.d[4]  = {Wo, SZ_W/4,  SL_WO};
  am.d[5]  = {W1, SZ_XE/4, SL_W1};
  am.d[6]  = {W2, SZ_XE/4, SL_W2};
  am.d[7]  = {bq, 256,     SL_BQ};
  am.d[8]  = {bk, 256,     SL_BK};
  am.d[9]  = {bv, 256,     SL_BV};
  am.d[10] = {bo, 256,     SL_BO};
  am.d[11] = {b1, 1024,    SL_B1};
  am.d[12] = {b2, 256,     SL_B2};
  absmax_multi_kernel<<<dim3(64, 13), 256, 0, stream>>>(am, ws);

  // --- quantize x + 6 weights to i8 codes (1 dispatch); biases (1 dispatch) ---
  QMBatch qm;
  qm.d[0] = {x,  qx8, SZ_XE/4, SL_X,  -128.f};
  qm.d[1] = {Wq, wq8, SZ_W/4,  SL_WQ, -127.f};
  qm.d[2] = {Wk, wk8, SZ_W/4,  SL_WK, -127.f};
  qm.d[3] = {Wv, wv8, SZ_W/4,  SL_WV, -127.f};
  qm.d[4] = {W1, w18, SZ_XE/4, SL_W1, -127.f};
  qm.d[5] = {W2, w28, SZ_XE/4, SL_W2, -127.f};
  qm.d[6] = {Wo, wo8, SZ_W/4,  SL_WO, -127.f};
  quant8_multi_kernel<<<dim3(64, 7), 256, 0, stream>>>(qm, ws);
  rowsum_i8_kernel<<<TB_E, 256, 0, stream>>>(w28, rsum, TB_MLP);
  BBatch bb;
  bb.d[0] = {bq, qbq_, 256,  SL_BQ};
  bb.d[1] = {bk, qbk_, 256,  SL_BK};
  bb.d[2] = {bv, qbv_, 256,  SL_BV};
  bb.d[3] = {bo, qbo_, 256,  SL_BO};
  bb.d[4] = {b1, qb1_, 1024, SL_B1};
  bb.d[5] = {b2, qb2_, 256,  SL_B2};
  bias_quant_multi_kernel<<<dim3(4, 6), 256, 0, stream>>>(bb, ws);

  // --- fused QKV in-projection (int8 MFMA, exact): N=3072, writes [B,H,S,D] fp32 ---
  gemm_i8_kernel<<<dim3(3*TB_E/128, TB_ROWS/128), 256, 0, stream>>>(
      qx8, wq8, qbq_, ws + SL_X, 127.f, ws + SL_WQ, nullptr, qbuf,
      TB_ROWS, 3*TB_E, TB_E, ws + SL_Q, 0, 1);

  // --- quantize q (pre=1/8), k (linear, layouts already [B,H,S,D]); v blocked ---
  quant8_kernel<<<2048, 256, 0, stream>>>(qbuf, q8, SZ_XE/4, ws + SL_Q, 0.125f, -128.f);
  quant8_kernel<<<2048, 256, 0, stream>>>(kbuf, k8, SZ_XE/4, ws + SL_K, 1.f, -128.f);
  quant8_vb_kernel<<<dim3(TB_B*TB_H, TB_S/64), 256, 0, stream>>>(vbuf, ws + SL_V, v8b);

  // --- attention (i8 MFMA, 3 passes) ---
  attn_rowmax_kernel<<<dim3(TB_B*TB_H, TB_S/64), 256, 0, stream>>>(q8, k8, irowmax, imax);
  attn_rowsum_kernel<<<dim3(TB_B*TB_H, TB_S/64), 256, 0, stream>>>(
      q8, k8, irowmax, imax, ws + SL_Q, ws + SL_K, rowl, ws + SL_ATTN);
  attn_pv_kernel<<<dim3(TB_B*TB_H, TB_S/64), 256, 0, stream>>>(
      q8, k8, v8b, irowmax, imax, ws + SL_Q, ws + SL_K, ws + SL_V, ws + SL_ATTN,
      rowl, ctx, ws + SL_CTX);

  // --- out projection ---
  quant8_kernel<<<2048, 256, 0, stream>>>(ctx, ctx8, SZ_XE/4, ws + SL_CTX, 1.f, -128.f);
  gemm_i8_kernel<<<dim3(TB_E/128, TB_ROWS/128), 256, 0, stream>>>(
      ctx8, wo8, qbo_, ws + SL_CTX, 127.f, ws + SL_WO, nullptr, attn_out,
      TB_ROWS, TB_E, TB_E, ws + SL_AO, 0, 0);

  // --- residual + LN (fused h absmax) ---
  resid_ln_kernel<<<TB_ROWS, 256, 0, stream>>>(qx8, ws + SL_X, attn_out, ws + SL_AO, hbuf, ws + SL_H);

  // --- MLP ---
  quant8_kernel<<<2048, 256, 0, stream>>>(hbuf, m08, SZ_XE/4, ws + SL_H, 1.f, -128.f);
  gemm_i8_kernel<<<dim3(TB_MLP/128, TB_ROWS/128), 256, 0, stream>>>(
      m08, w18, qb1_, ws + SL_H, 127.f, ws + SL_W1, nullptr, m1,
      TB_ROWS, TB_MLP, TB_E, ws + SL_RELU, 1, 0);
  relu_quant8_kernel<<<nblocks(SZ_M1/4), 256, 0, stream>>>(m1, m18, SZ_M1/4, ws + SL_RELU);
  gemm_i8_kernel<<<dim3(TB_E/128, TB_ROWS/128), 256, 0, stream>>>(
      m18, w28, qb2_, ws + SL_RELU, 255.f, ws + SL_W2, rsum, m2,
      TB_ROWS, TB_E, TB_MLP, ws + SL_M2, 0, 0);

  // --- final residual + LN ---
  resid_ln_kernel<<<TB_ROWS, 256, 0, stream>>>(m08, ws + SL_H, m2, ws + SL_M2, out, ws + SL_DUMMY);
}